// Round 1
// 1644.586 us; speedup vs baseline: 1.2734x; 1.2734x over previous
//
#include <hip/hip_runtime.h>

// ---------------------------------------------------------------------------
// FocalAtt (CA mode): B=8, Lq=512, Lk=1024, qd=kd=768, hid=1024, mid=4096,
// H=16, dh=64. Inputs f32, outputs f32. bf16 MFMA GEMMs (16x16x32), fp32 acc.
// R1: score + att@V moved from scalar-FMA to MFMA. V produced pre-transposed
// ([v1T;v0T] = [WvT;Wv0T] @ kp^T) so the PV GEMM is contraction-contiguous.
// Workspace peak 58,241,024 B (< known-good 58,490,880).
// ---------------------------------------------------------------------------

typedef unsigned short bfr;  // raw bf16 bits
using short8 = __attribute__((ext_vector_type(8))) short;
using f32x4  = __attribute__((ext_vector_type(4))) float;

__device__ __forceinline__ float b2f(bfr s) {
  return __uint_as_float(((unsigned int)s) << 16);
}
__device__ __forceinline__ bfr f2b(float f) {
  unsigned int u = __float_as_uint(f);
  u += 0x7fffu + ((u >> 16) & 1u);  // RNE
  return (bfr)(u >> 16);
}

struct __align__(8) us4 { bfr x, y, z, w; };

__device__ __forceinline__ float4 load4f(const float* p) { return *(const float4*)p; }
__device__ __forceinline__ float4 load4f(const bfr* p) {
  us4 u = *(const us4*)p;
  return make_float4(b2f(u.x), b2f(u.y), b2f(u.z), b2f(u.w));
}
__device__ __forceinline__ void store4(float* p, float a, float b, float c, float d) {
  *(float4*)p = make_float4(a, b, c, d);
}
__device__ __forceinline__ void store4(bfr* p, float a, float b, float c, float d) {
  us4 v; v.x = f2b(a); v.y = f2b(b); v.z = f2b(c); v.w = f2b(d);
  *(us4*)p = v;
}

// ---------------------------------------------------------------------------
// Positional encoding
// ---------------------------------------------------------------------------
__device__ __forceinline__ float pe_val(int l, int d) {
  float ang = (float)l * expf((float)(d & ~1) * (-9.210340371976184f / 768.0f));
  return (d & 1) ? cosf(ang) : sinf(ang);
}

// k + PE -> f32 kp (d_out; also K/V projection A/B-input). total = 8*1024*768
__global__ __launch_bounds__(256) void posenc_k(const float* __restrict__ in,
                                                float* __restrict__ outf, int total) {
  int idx = blockIdx.x * 256 + threadIdx.x;
  if (idx >= total) return;
  outf[idx] = in[idx] + pe_val((idx / 768) % 1024, idx % 768);
}

// q + PE -> bf16 qp_all [4096,768]
__global__ __launch_bounds__(256) void posenc_q_all(const float* __restrict__ in,
                                                    bfr* __restrict__ out, int total) {
  int idx = blockIdx.x * 256 + threadIdx.x;
  if (idx >= total) return;
  out[idx] = f2b(in[idx] + pe_val((idx / 768) % 512, idx % 768));
}

// ---------------------------------------------------------------------------
// Weight transpose: src f32 [rows, cols] (row stride ld) -> dst bf16 [cols, rows]
// grid (cols/32, rows/32), 256 threads.
// ---------------------------------------------------------------------------
__global__ __launch_bounds__(256) void transpose_w(const float* __restrict__ src,
                                                   bfr* __restrict__ dst,
                                                   int rows, int cols, int ld) {
  __shared__ float t[32][33];
  const int bc = blockIdx.x * 32, br = blockIdx.y * 32;
  const int tx = threadIdx.x & 31, ty = threadIdx.x >> 5;  // ty 0..7
#pragma unroll
  for (int i = 0; i < 4; i++)
    t[ty + i * 8][tx] = src[(size_t)(br + ty + i * 8) * ld + bc + tx];
  __syncthreads();
#pragma unroll
  for (int i = 0; i < 4; i++)
    dst[(size_t)(bc + ty + i * 8) * rows + br + tx] = f2b(t[tx][ty + i * 8]);
}

// ---------------------------------------------------------------------------
// MFMA GEMM: C[M,N] = A[M,K] @ B[K,N] (+bias, relu, accum). B passed as
// BT[N,K] (pre-transposed). 128x128 block, 256 thr = 4 waves, each wave
// 64x64 via 4x4 of v_mfma_f32_16x16x32_bf16. BK=32. All dims %128==0, K%32==0.
// A-frag: lane holds A[m=lane&15][k=(lane>>4)*8+j]; D: row=(lane>>4)*4+r,
// col=lane&15 (measured m89/m91 layouts).
// ---------------------------------------------------------------------------
__device__ __forceinline__ void stage16(const bfr* __restrict__ s, bfr* d) {
  *(short8*)d = *(const short8*)s;
  *(short8*)(d + 8) = *(const short8*)(s + 8);
}
__device__ __forceinline__ void stage16(const float* __restrict__ s, bfr* d) {
  bfr tmp[16];
#pragma unroll
  for (int i = 0; i < 16; i += 4) {
    float4 v = *(const float4*)(s + i);
    tmp[i] = f2b(v.x); tmp[i + 1] = f2b(v.y);
    tmp[i + 2] = f2b(v.z); tmp[i + 3] = f2b(v.w);
  }
  *(short8*)d = *(short8*)&tmp[0];
  *(short8*)(d + 8) = *(short8*)&tmp[8];
}

template <typename TA, typename TB, typename TC>
__global__ __launch_bounds__(256) void mgemm(const TA* __restrict__ A,
                                             const TB* __restrict__ BT,
                                             const float* __restrict__ bias,
                                             TC* __restrict__ C,
                                             int K, int ldc, int relu, int accum) {
  __shared__ bfr As[128][40];  // row stride 80 B = 20 banks (2-way max, free)
  __shared__ bfr Bs[128][40];
  const int tid = threadIdx.x;
  const int n0 = blockIdx.x * 128, m0 = blockIdx.y * 128;
  const int lane = tid & 63;
  const int wm = ((tid >> 6) & 1) * 64, wn = (tid >> 7) * 64;
  const int sr = tid >> 1, sc16 = (tid & 1) * 16;
  const int fr = lane & 15, fc = (lane >> 4) * 8;
  f32x4 acc[4][4];
#pragma unroll
  for (int i = 0; i < 4; i++)
#pragma unroll
    for (int j = 0; j < 4; j++) acc[i][j] = (f32x4){0.f, 0.f, 0.f, 0.f};
  for (int k0 = 0; k0 < K; k0 += 32) {
    stage16(A + (size_t)(m0 + sr) * K + k0 + sc16, &As[sr][sc16]);
    stage16(BT + (size_t)(n0 + sr) * K + k0 + sc16, &Bs[sr][sc16]);
    __syncthreads();
    short8 af[4], bf[4];
#pragma unroll
    for (int t = 0; t < 4; t++) af[t] = *(const short8*)&As[wm + t * 16 + fr][fc];
#pragma unroll
    for (int t = 0; t < 4; t++) bf[t] = *(const short8*)&Bs[wn + t * 16 + fr][fc];
#pragma unroll
    for (int i = 0; i < 4; i++)
#pragma unroll
      for (int j = 0; j < 4; j++)
        acc[i][j] = __builtin_amdgcn_mfma_f32_16x16x32_bf16(af[i], bf[j], acc[i][j], 0, 0, 0);
    __syncthreads();
  }
  const int col0 = n0 + wn + fr;
  const int row0 = m0 + wm + (lane >> 4) * 4;
  float bsv[4];
#pragma unroll
  for (int j = 0; j < 4; j++) bsv[j] = bias ? bias[col0 + j * 16] : 0.f;
#pragma unroll
  for (int i = 0; i < 4; i++) {
#pragma unroll
    for (int j = 0; j < 4; j++) {
      const int col = col0 + j * 16;
#pragma unroll
      for (int r = 0; r < 4; r++) {
        const int row = row0 + i * 16 + r;
        float v = acc[i][j][r] + bsv[j];
        if (relu) v = fmaxf(v, 0.f);
        size_t idx = (size_t)row * ldc + col;
        if constexpr (sizeof(TC) == 2) {
          C[idx] = f2b(v);
        } else {
          if (accum) C[idx] += v; else C[idx] = v;
        }
      }
    }
  }
}

// ---------------------------------------------------------------------------
// MFMA scores (one batch): sc[h,q,k] = dot_64(qh[q,h*64+:], kh[k,h*64+:]) / 8
// 128x128 tile, K=64 (two 32-steps, staged once). grid (8 kb, 4 qb, 16 h).
// ---------------------------------------------------------------------------
__global__ __launch_bounds__(256) void score_mfma(const bfr* __restrict__ qh,
                                                  const bfr* __restrict__ kh,
                                                  bfr* __restrict__ sc) {
  __shared__ __align__(16) bfr Qs[128][72];  // stride 144 B: 2-way max, free
  __shared__ __align__(16) bfr Ks[128][72];
  const int h = blockIdx.z, q0 = blockIdx.y * 128, k0 = blockIdx.x * 128;
  const int tid = threadIdx.x, lane = tid & 63;
  const int wm = ((tid >> 6) & 1) * 64, wn = (tid >> 7) * 64;
  const int fr = lane & 15, fc = (lane >> 4) * 8;
  {
    const int r = tid >> 1, c = (tid & 1) * 32;
    const bfr* qsrc = qh + (size_t)(q0 + r) * 1024 + h * 64 + c;
    const bfr* ksrc = kh + (size_t)(k0 + r) * 1024 + h * 64 + c;
#pragma unroll
    for (int i = 0; i < 4; i++) {
      *(short8*)&Qs[r][c + i * 8] = *(const short8*)(qsrc + i * 8);
      *(short8*)&Ks[r][c + i * 8] = *(const short8*)(ksrc + i * 8);
    }
  }
  __syncthreads();
  f32x4 acc[4][4];
#pragma unroll
  for (int i = 0; i < 4; i++)
#pragma unroll
    for (int j = 0; j < 4; j++) acc[i][j] = (f32x4){0.f, 0.f, 0.f, 0.f};
#pragma unroll
  for (int ks = 0; ks < 2; ks++) {
    short8 af[4], bf[4];
#pragma unroll
    for (int t = 0; t < 4; t++) af[t] = *(const short8*)&Qs[wm + t * 16 + fr][ks * 32 + fc];
#pragma unroll
    for (int t = 0; t < 4; t++) bf[t] = *(const short8*)&Ks[wn + t * 16 + fr][ks * 32 + fc];
#pragma unroll
    for (int i = 0; i < 4; i++)
#pragma unroll
      for (int j = 0; j < 4; j++)
        acc[i][j] = __builtin_amdgcn_mfma_f32_16x16x32_bf16(af[i], bf[j], acc[i][j], 0, 0, 0);
  }
  const int col0 = k0 + wn + fr;
  const int row0 = q0 + wm + (lane >> 4) * 4;
#pragma unroll
  for (int i = 0; i < 4; i++)
#pragma unroll
    for (int j = 0; j < 4; j++)
#pragma unroll
      for (int r = 0; r < 4; r++)
        sc[((size_t)h * 512 + row0 + i * 16 + r) * 1024 + col0 + j * 16] =
            f2b(acc[i][j][r] * 0.125f);
}

// att_out_b[q,k] = sum_h relu(sc[h,q,k]) / 16 (pre-softmax), f32 out
__global__ __launch_bounds__(256) void attout_kernel(const bfr* __restrict__ sc,
                                                     float* __restrict__ out) {
  int idx = blockIdx.x * 256 + threadIdx.x;  // < 512*1024
  float s = 0.f;
#pragma unroll
  for (int h = 0; h < 16; h++) s += fmaxf(b2f(sc[(size_t)h * 524288 + idx]), 0.f);
  out[idx] = s * (1.0f / 16.0f);
}

// in-place row softmax over 1024 bf16 (rows = 8192 per batch)
__global__ __launch_bounds__(256) void softmax_kernel(bfr* __restrict__ sc) {
  __shared__ float sm[4];
  const size_t row = blockIdx.x;
  us4* p = (us4*)(sc + row * 1024);
  const int tid = threadIdx.x;
  us4 raw = p[tid];
  float v0 = b2f(raw.x), v1 = b2f(raw.y), v2 = b2f(raw.z), v3 = b2f(raw.w);
  float m = fmaxf(fmaxf(v0, v1), fmaxf(v2, v3));
  for (int o = 32; o; o >>= 1) m = fmaxf(m, __shfl_down(m, o, 64));
  if ((tid & 63) == 0) sm[tid >> 6] = m;
  __syncthreads();
  m = fmaxf(fmaxf(sm[0], sm[1]), fmaxf(sm[2], sm[3]));
  v0 = expf(v0 - m); v1 = expf(v1 - m); v2 = expf(v2 - m); v3 = expf(v3 - m);
  float s = v0 + v1 + v2 + v3;
  __syncthreads();
  for (int o = 32; o; o >>= 1) s += __shfl_down(s, o, 64);
  if ((tid & 63) == 0) sm[tid >> 6] = s;
  __syncthreads();
  s = sm[0] + sm[1] + sm[2] + sm[3];
  float inv = 1.0f / s;
  raw.x = f2b(v0 * inv); raw.y = f2b(v1 * inv);
  raw.z = f2b(v2 * inv); raw.w = f2b(v3 * inv);
  p[tid] = raw;
}

// ---------------------------------------------------------------------------
// MFMA att@V (one batch): atp[q,h*64+d] = sum_k att[h,q,k]*v1T[h*64+d,k] + bv;
// u same with v0T/bv0. Bias is exact via softmax row-sum == 1.
// grid (16 qb of 32 rows, 16 h), 256 thr = 4 waves:
//   waves 0,1 -> atp rows 0-15/16-31; waves 2,3 -> u rows 0-15/16-31.
// ---------------------------------------------------------------------------
__global__ __launch_bounds__(256) void attv_mfma(const bfr* __restrict__ att,
                                                 const bfr* __restrict__ v1T,
                                                 const bfr* __restrict__ v0T,
                                                 const float* __restrict__ bv,
                                                 const float* __restrict__ bv0,
                                                 bfr* __restrict__ atp,
                                                 bfr* __restrict__ u) {
  __shared__ __align__(16) bfr As[32][40];
  __shared__ __align__(16) bfr B1s[64][40];
  __shared__ __align__(16) bfr B2s[64][40];
  const int h = blockIdx.y, q0 = blockIdx.x * 32;
  const int tid = threadIdx.x, lane = tid & 63, wave = tid >> 6;
  const int fr = lane & 15, fc = (lane >> 4) * 8;
  const bfr* attb = att + ((size_t)h * 512 + q0) * 1024;
  const bfr* v1b = v1T + (size_t)h * 64 * 1024;
  const bfr* v0b = v0T + (size_t)h * 64 * 1024;
  const int sra = tid >> 2, sc8 = (tid & 3) * 8;  // staging coords
  f32x4 acc[4];
#pragma unroll
  for (int j = 0; j < 4; j++) acc[j] = (f32x4){0.f, 0.f, 0.f, 0.f};
  const bfr(*Bsel)[40] = (wave < 2) ? B1s : B2s;
  const int wr = (wave & 1) * 16;
  for (int k0 = 0; k0 < 1024; k0 += 32) {
    if (tid < 128)  // As: 32 rows x 32 k
      *(short8*)&As[tid >> 2][sc8] =
          *(const short8*)(attb + (size_t)(tid >> 2) * 1024 + k0 + sc8);
    // B tiles: 64 rows (d) x 32 k each
    *(short8*)&B1s[sra][sc8] = *(const short8*)(v1b + (size_t)sra * 1024 + k0 + sc8);
    *(short8*)&B2s[sra][sc8] = *(const short8*)(v0b + (size_t)sra * 1024 + k0 + sc8);
    __syncthreads();
    short8 af = *(const short8*)&As[wr + fr][fc];
#pragma unroll
    for (int j = 0; j < 4; j++) {
      short8 bf = *(const short8*)&Bsel[j * 16 + fr][fc];
      acc[j] = __builtin_amdgcn_mfma_f32_16x16x32_bf16(af, bf, acc[j], 0, 0, 0);
    }
    __syncthreads();
  }
  bfr* o = (wave < 2) ? atp : u;
  const float* bias = (wave < 2) ? bv : bv0;
  const int row0 = q0 + wr + (lane >> 4) * 4;
#pragma unroll
  for (int j = 0; j < 4; j++) {
    const int col = h * 64 + j * 16 + fr;
    const float bb = bias[col];
#pragma unroll
    for (int r = 0; r < 4; r++)
      o[(size_t)(row0 + r) * 1024 + col] = f2b(acc[j][r] + bb);
  }
}

// xpre_b[c] += sum over 64 rows of q0p_b[v,c]*u_b[v,c] (per batch), grid (4,8)
__global__ __launch_bounds__(256) void xpre_kernel(const bfr* __restrict__ q0p,
                                                   const bfr* __restrict__ u,
                                                   float* __restrict__ xpre) {
  const int c = blockIdx.x * 256 + threadIdx.x;
  const int r0 = blockIdx.y * 64;
  const bfr* qp = q0p + (size_t)r0 * 1024 + c;
  const bfr* up = u + (size_t)r0 * 1024 + c;
  float s = 0.f;
#pragma unroll 8
  for (int r = 0; r < 64; r++)
    s = fmaf(b2f(qp[(size_t)r * 1024]), b2f(up[(size_t)r * 1024]), s);
  atomicAdd(&xpre[c], s);
}

// torch_ln over rows of 1024: a*(x-mean)/(sqrt(var_unbiased)+1e-6)+b, X (+Y)
template <typename TX, typename TY, typename OT>
__global__ __launch_bounds__(256) void ln_kernel(const TX* __restrict__ X,
                                                 const TY* __restrict__ Y,
                                                 const float* __restrict__ ga,
                                                 const float* __restrict__ be,
                                                 OT* __restrict__ out) {
  __shared__ float sm[4];
  const size_t row = blockIdx.x;
  const int tid = threadIdx.x;
  float4 v = load4f(X + row * 1024 + tid * 4);
  if (Y) {
    float4 w = load4f(Y + row * 1024 + tid * 4);
    v.x += w.x; v.y += w.y; v.z += w.z; v.w += w.w;
  }
  float s = v.x + v.y + v.z + v.w;
  for (int o = 32; o; o >>= 1) s += __shfl_down(s, o, 64);
  if ((tid & 63) == 0) sm[tid >> 6] = s;
  __syncthreads();
  s = sm[0] + sm[1] + sm[2] + sm[3];
  float mean = s * (1.0f / 1024.0f);
  float d0 = v.x - mean, d1 = v.y - mean, d2 = v.z - mean, d3 = v.w - mean;
  float q = d0 * d0 + d1 * d1 + d2 * d2 + d3 * d3;
  __syncthreads();
  for (int o = 32; o; o >>= 1) q += __shfl_down(q, o, 64);
  if ((tid & 63) == 0) sm[tid >> 6] = q;
  __syncthreads();
  q = sm[0] + sm[1] + sm[2] + sm[3];
  float rs = 1.0f / (sqrtf(q * (1.0f / 1023.0f)) + 1e-6f);
  float4 g = *(const float4*)(ga + tid * 4);
  float4 bb = *(const float4*)(be + tid * 4);
  store4(out + row * 1024 + tid * 4,
         g.x * d0 * rs + bb.x, g.y * d1 * rs + bb.y,
         g.z * d2 * rs + bb.z, g.w * d3 * rs + bb.w);
}

// ---------------------------------------------------------------------------
extern "C" void kernel_launch(void* const* d_in, const int* in_sizes, int n_in,
                              void* d_out, int out_size, void* d_ws, size_t ws_size,
                              hipStream_t stream) {
  (void)in_sizes; (void)n_in; (void)out_size; (void)ws_size;
  const float* q   = (const float*)d_in[0];
  const float* k   = (const float*)d_in[1];
  const float* Wq  = (const float*)d_in[2];
  const float* bq  = (const float*)d_in[3];
  const float* Wk  = (const float*)d_in[4];
  const float* bk  = (const float*)d_in[5];
  const float* Wv  = (const float*)d_in[6];
  const float* bv  = (const float*)d_in[7];
  const float* Wv0 = (const float*)d_in[8];
  const float* bv0 = (const float*)d_in[9];
  const float* Wq0 = (const float*)d_in[10];
  const float* bq0 = (const float*)d_in[11];
  const float* nqa = (const float*)d_in[12];
  const float* nqb = (const float*)d_in[13];
  const float* nxa = (const float*)d_in[14];
  const float* nxb = (const float*)d_in[15];
  const float* W1  = (const float*)d_in[16];
  const float* b1  = (const float*)d_in[17];
  const float* W2  = (const float*)d_in[18];
  const float* b2  = (const float*)d_in[19];
  const float* nsa = (const float*)d_in[20];
  const float* nsb = (const float*)d_in[21];

  float* out = (float*)d_out;
  float* x_out  = out;                       // 8,192
  float* qq_out = out + 8192;                // 4,194,304
  float* kp_out = out + 4202496;             // 6,291,456
  float* ao_out = out + 10493952;            // 4,194,304

  char* base = (char*)d_ws;
  // persistent
  bfr* q0p   = (bfr*)(base + 0);            // 8,388,608  [4096,1024]
  bfr* qh    = (bfr*)(base + 8388608);      // 8,388,608  [4096,1024]
  bfr* atl   = (bfr*)(base + 16777216);     // 8,388,608  [4096,1024]
  bfr* WqT   = (bfr*)(base + 25165824);     // 1,572,864  [1024,768]
  bfr* Wq0T  = (bfr*)(base + 26738688);     // 1,572,864
  bfr* WTkv  = (bfr*)(base + 28311552);     // 4,718,592  [WkT;WvT;Wv0T][3072,768]
  float* xpre = (float*)(base + 33042432);  //    32,768  [8,1024]
  char* S = base + 33075200;                // scratch region, 25,165,824 B
  // attention-loop overlay
  bfr* sc    = (bfr*)(S + 0);               // 16,777,216 [16,512,1024]
  bfr* kh    = (bfr*)(S + 16777216);        //  2,097,152 [1024,1024]
  bfr* v1T   = (bfr*)(S + 18874368);        //  2,097,152 [1024,1024] (d',k)
  bfr* v0T   = (bfr*)(S + 20971520);        //  2,097,152 [1024,1024] (d',k)
  bfr* atpb  = (bfr*)(S + 23068672);        //  1,048,576 [512,1024]
  bfr* ub    = (bfr*)(S + 24117248);        //  1,048,576
  // pre-loop overlay (dead before sc/kh first written)
  bfr* qp_all = (bfr*)(S + 0);              //  6,291,456 [4096,768]
  // FFN-phase overlay (attention buffers dead)
  bfr* W1Tn  = (bfr*)(S + 0);               //  1,048,576 [512,1024]
  bfr* W2Tn  = (bfr*)(S + 1048576);         //  1,048,576 [1024,512]
  bfr* ff1n  = (bfr*)(S + 2097152);         //  4,194,304 [4096,512]
  float* ff2a = (float*)(S + 6291456);      // 16,777,216 [4096,1024] f32
  // peak footprint: 58,241,024 B

  // --- setup ---
  posenc_k<<<24576, 256, 0, stream>>>(k, kp_out, 6291456);
  posenc_q_all<<<12288, 256, 0, stream>>>(q, qp_all, 3145728);
  transpose_w<<<dim3(32, 24), 256, 0, stream>>>(Wq, WqT, 768, 1024, 1024);
  transpose_w<<<dim3(32, 24), 256, 0, stream>>>(Wq0, Wq0T, 768, 1024, 1024);
  transpose_w<<<dim3(32, 24), 256, 0, stream>>>(Wk, WTkv, 768, 1024, 1024);
  transpose_w<<<dim3(32, 24), 256, 0, stream>>>(Wv, WTkv + 786432, 768, 1024, 1024);
  transpose_w<<<dim3(32, 24), 256, 0, stream>>>(Wv0, WTkv + 1572864, 768, 1024, 1024);

  // full-batch projections (MFMA)
  mgemm<float, bfr, bfr><<<dim3(8, 32), 256, 0, stream>>>(q, Wq0T, bq0, q0p, 768, 1024, 0, 0);
  mgemm<bfr, bfr, bfr><<<dim3(8, 32), 256, 0, stream>>>(qp_all, WqT, bq, qh, 768, 1024, 0, 0);
  hipMemsetAsync(xpre, 0, 32768, stream);

  // --- per-batch attention ---
  for (int b = 0; b < 8; b++) {
    const float* kp_b = kp_out + (size_t)b * 786432;
    // kh = kp @ Wk + bk  [1024,1024]
    mgemm<float, bfr, bfr><<<dim3(8, 8), 256, 0, stream>>>(
        kp_b, WTkv, bk, kh, 768, 1024, 0, 0);
    // [v1T; v0T] = [WvT; Wv0T] @ kp^T  [2048,1024], contiguous in ws
    mgemm<bfr, float, bfr><<<dim3(8, 16), 256, 0, stream>>>(
        WTkv + 786432, kp_b, nullptr, v1T, 768, 1024, 0, 0);
    score_mfma<<<dim3(8, 4, 16), 256, 0, stream>>>(qh + (size_t)b * 524288, kh, sc);
    attout_kernel<<<2048, 256, 0, stream>>>(sc, ao_out + (size_t)b * 524288);
    softmax_kernel<<<8192, 256, 0, stream>>>(sc);
    attv_mfma<<<dim3(16, 16), 256, 0, stream>>>(sc, v1T, v0T, bv, bv0, atpb, ub);
    xpre_kernel<<<dim3(4, 8), 256, 0, stream>>>(q0p + (size_t)b * 524288, ub,
                                                xpre + b * 1024);
    ln_kernel<bfr, bfr, bfr><<<512, 256, 0, stream>>>(
        q0p + (size_t)b * 524288, atpb, nqa, nqb, atl + (size_t)b * 524288);
  }

  // x = LN(bilinear)
  ln_kernel<float, float, float><<<8, 256, 0, stream>>>(xpre, (const float*)nullptr,
                                                        nxa, nxb, x_out);

  // --- FFN, K-split into 8 chunks of 512, f32 accumulation ---
  for (int nc = 0; nc < 8; nc++) {
    transpose_w<<<dim3(16, 32), 256, 0, stream>>>(W1 + nc * 512, W1Tn, 1024, 512, 4096);
    transpose_w<<<dim3(32, 16), 256, 0, stream>>>(W2 + (size_t)nc * 512 * 1024, W2Tn,
                                                  512, 1024, 1024);
    mgemm<bfr, bfr, bfr><<<dim3(4, 32), 256, 0, stream>>>(atl, W1Tn, b1 + nc * 512, ff1n,
                                                          1024, 512, 1, 0);
    mgemm<bfr, bfr, float><<<dim3(8, 32), 256, 0, stream>>>(ff1n, W2Tn,
                                                            nc == 0 ? b2 : nullptr, ff2a,
                                                            512, 1024, 0, nc > 0);
  }
  ln_kernel<bfr, float, float><<<4096, 256, 0, stream>>>(atl, ff2a, nsa, nsb, qq_out);
}

// Round 2
// 1232.946 us; speedup vs baseline: 1.6985x; 1.3339x over previous
//
#include <hip/hip_runtime.h>

// ---------------------------------------------------------------------------
// FocalAtt (CA mode): B=8, Lq=512, Lk=1024, qd=kd=768, hid=1024, mid=4096,
// H=16, dh=64. Inputs f32, outputs f32. bf16 MFMA GEMMs (16x16x32), fp32 acc.
// R2: attv -> mgemm-structured attv2 (interleaved v1|v0 B-tile, K-step 64);
// attout+softmax fused into smax_ao (single sc pass); FFN re-chunked to 2
// K=2048 chunks using freed q0p/qh region for f32 accumulator.
// Workspace peak 58,228,736 B (< known-good 58,490,880).
// ---------------------------------------------------------------------------

typedef unsigned short bfr;  // raw bf16 bits
using short8 = __attribute__((ext_vector_type(8))) short;
using f32x4  = __attribute__((ext_vector_type(4))) float;

__device__ __forceinline__ float b2f(bfr s) {
  return __uint_as_float(((unsigned int)s) << 16);
}
__device__ __forceinline__ bfr f2b(float f) {
  unsigned int u = __float_as_uint(f);
  u += 0x7fffu + ((u >> 16) & 1u);  // RNE
  return (bfr)(u >> 16);
}

struct __align__(8) us4 { bfr x, y, z, w; };

__device__ __forceinline__ float4 load4f(const float* p) { return *(const float4*)p; }
__device__ __forceinline__ float4 load4f(const bfr* p) {
  us4 u = *(const us4*)p;
  return make_float4(b2f(u.x), b2f(u.y), b2f(u.z), b2f(u.w));
}
__device__ __forceinline__ void store4(float* p, float a, float b, float c, float d) {
  *(float4*)p = make_float4(a, b, c, d);
}
__device__ __forceinline__ void store4(bfr* p, float a, float b, float c, float d) {
  us4 v; v.x = f2b(a); v.y = f2b(b); v.z = f2b(c); v.w = f2b(d);
  *(us4*)p = v;
}

// ---------------------------------------------------------------------------
// Positional encoding
// ---------------------------------------------------------------------------
__device__ __forceinline__ float pe_val(int l, int d) {
  float ang = (float)l * expf((float)(d & ~1) * (-9.210340371976184f / 768.0f));
  return (d & 1) ? cosf(ang) : sinf(ang);
}

// k + PE -> f32 kp (d_out; also K/V projection A/B-input). total = 8*1024*768
__global__ __launch_bounds__(256) void posenc_k(const float* __restrict__ in,
                                                float* __restrict__ outf, int total) {
  int idx = blockIdx.x * 256 + threadIdx.x;
  if (idx >= total) return;
  outf[idx] = in[idx] + pe_val((idx / 768) % 1024, idx % 768);
}

// q + PE -> bf16 qp_all [4096,768]
__global__ __launch_bounds__(256) void posenc_q_all(const float* __restrict__ in,
                                                    bfr* __restrict__ out, int total) {
  int idx = blockIdx.x * 256 + threadIdx.x;
  if (idx >= total) return;
  out[idx] = f2b(in[idx] + pe_val((idx / 768) % 512, idx % 768));
}

// ---------------------------------------------------------------------------
// Weight transpose: src f32 [rows, cols] (row stride ld) -> dst bf16 [cols, rows]
// grid (cols/32, rows/32), 256 threads. mode: dst-row remap for interleaved
// v1|v0 stacking. 0: r=c; 1: r=(c>>6)*128+(c&63); 2: r=(c>>6)*128+64+(c&63).
// ---------------------------------------------------------------------------
__global__ __launch_bounds__(256) void transpose_w(const float* __restrict__ src,
                                                   bfr* __restrict__ dst,
                                                   int rows, int cols, int ld,
                                                   int mode) {
  __shared__ float t[32][33];
  const int bc = blockIdx.x * 32, br = blockIdx.y * 32;
  const int tx = threadIdx.x & 31, ty = threadIdx.x >> 5;  // ty 0..7
#pragma unroll
  for (int i = 0; i < 4; i++)
    t[ty + i * 8][tx] = src[(size_t)(br + ty + i * 8) * ld + bc + tx];
  __syncthreads();
#pragma unroll
  for (int i = 0; i < 4; i++) {
    int c = bc + ty + i * 8;
    int r = (mode == 0) ? c : ((c >> 6) * 128 + (c & 63) + (mode == 2 ? 64 : 0));
    dst[(size_t)r * rows + br + tx] = f2b(t[tx][ty + i * 8]);
  }
}

// ---------------------------------------------------------------------------
// MFMA GEMM: C[M,N] = A[M,K] @ B[K,N] (+bias, relu, accum). B passed as
// BT[N,K] (pre-transposed). 128x128 block, 256 thr = 4 waves, each wave
// 64x64 via 4x4 of v_mfma_f32_16x16x32_bf16. BK=32. All dims %128==0, K%32==0.
// A-frag: lane holds A[m=lane&15][k=(lane>>4)*8+j]; D: row=(lane>>4)*4+r,
// col=lane&15 (measured m89/m91 layouts).
// ---------------------------------------------------------------------------
__device__ __forceinline__ void stage16(const bfr* __restrict__ s, bfr* d) {
  *(short8*)d = *(const short8*)s;
  *(short8*)(d + 8) = *(const short8*)(s + 8);
}
__device__ __forceinline__ void stage16(const float* __restrict__ s, bfr* d) {
  bfr tmp[16];
#pragma unroll
  for (int i = 0; i < 16; i += 4) {
    float4 v = *(const float4*)(s + i);
    tmp[i] = f2b(v.x); tmp[i + 1] = f2b(v.y);
    tmp[i + 2] = f2b(v.z); tmp[i + 3] = f2b(v.w);
  }
  *(short8*)d = *(short8*)&tmp[0];
  *(short8*)(d + 8) = *(short8*)&tmp[8];
}

template <typename TA, typename TB, typename TC>
__global__ __launch_bounds__(256) void mgemm(const TA* __restrict__ A,
                                             const TB* __restrict__ BT,
                                             const float* __restrict__ bias,
                                             TC* __restrict__ C,
                                             int K, int ldc, int relu, int accum) {
  __shared__ bfr As[128][40];  // row stride 80 B = 20 banks (2-way max, free)
  __shared__ bfr Bs[128][40];
  const int tid = threadIdx.x;
  const int n0 = blockIdx.x * 128, m0 = blockIdx.y * 128;
  const int lane = tid & 63;
  const int wm = ((tid >> 6) & 1) * 64, wn = (tid >> 7) * 64;
  const int sr = tid >> 1, sc16 = (tid & 1) * 16;
  const int fr = lane & 15, fc = (lane >> 4) * 8;
  f32x4 acc[4][4];
#pragma unroll
  for (int i = 0; i < 4; i++)
#pragma unroll
    for (int j = 0; j < 4; j++) acc[i][j] = (f32x4){0.f, 0.f, 0.f, 0.f};
  for (int k0 = 0; k0 < K; k0 += 32) {
    stage16(A + (size_t)(m0 + sr) * K + k0 + sc16, &As[sr][sc16]);
    stage16(BT + (size_t)(n0 + sr) * K + k0 + sc16, &Bs[sr][sc16]);
    __syncthreads();
    short8 af[4], bf[4];
#pragma unroll
    for (int t = 0; t < 4; t++) af[t] = *(const short8*)&As[wm + t * 16 + fr][fc];
#pragma unroll
    for (int t = 0; t < 4; t++) bf[t] = *(const short8*)&Bs[wn + t * 16 + fr][fc];
#pragma unroll
    for (int i = 0; i < 4; i++)
#pragma unroll
      for (int j = 0; j < 4; j++)
        acc[i][j] = __builtin_amdgcn_mfma_f32_16x16x32_bf16(af[i], bf[j], acc[i][j], 0, 0, 0);
    __syncthreads();
  }
  const int col0 = n0 + wn + fr;
  const int row0 = m0 + wm + (lane >> 4) * 4;
  float bsv[4];
#pragma unroll
  for (int j = 0; j < 4; j++) bsv[j] = bias ? bias[col0 + j * 16] : 0.f;
#pragma unroll
  for (int i = 0; i < 4; i++) {
#pragma unroll
    for (int j = 0; j < 4; j++) {
      const int col = col0 + j * 16;
#pragma unroll
      for (int r = 0; r < 4; r++) {
        const int row = row0 + i * 16 + r;
        float v = acc[i][j][r] + bsv[j];
        if (relu) v = fmaxf(v, 0.f);
        size_t idx = (size_t)row * ldc + col;
        if constexpr (sizeof(TC) == 2) {
          C[idx] = f2b(v);
        } else {
          if (accum) C[idx] += v; else C[idx] = v;
        }
      }
    }
  }
}

// ---------------------------------------------------------------------------
// MFMA scores (one batch): sc[h,q,k] = dot_64(qh[q,h*64+:], kh[k,h*64+:]) / 8
// 128x128 tile, K=64 (two 32-steps, staged once). grid (8 kb, 4 qb, 16 h).
// ---------------------------------------------------------------------------
__global__ __launch_bounds__(256) void score_mfma(const bfr* __restrict__ qh,
                                                  const bfr* __restrict__ kh,
                                                  bfr* __restrict__ sc) {
  __shared__ __align__(16) bfr Qs[128][72];  // stride 144 B: 2-way max, free
  __shared__ __align__(16) bfr Ks[128][72];
  const int h = blockIdx.z, q0 = blockIdx.y * 128, k0 = blockIdx.x * 128;
  const int tid = threadIdx.x, lane = tid & 63;
  const int wm = ((tid >> 6) & 1) * 64, wn = (tid >> 7) * 64;
  const int fr = lane & 15, fc = (lane >> 4) * 8;
  {
    const int r = tid >> 1, c = (tid & 1) * 32;
    const bfr* qsrc = qh + (size_t)(q0 + r) * 1024 + h * 64 + c;
    const bfr* ksrc = kh + (size_t)(k0 + r) * 1024 + h * 64 + c;
#pragma unroll
    for (int i = 0; i < 4; i++) {
      *(short8*)&Qs[r][c + i * 8] = *(const short8*)(qsrc + i * 8);
      *(short8*)&Ks[r][c + i * 8] = *(const short8*)(ksrc + i * 8);
    }
  }
  __syncthreads();
  f32x4 acc[4][4];
#pragma unroll
  for (int i = 0; i < 4; i++)
#pragma unroll
    for (int j = 0; j < 4; j++) acc[i][j] = (f32x4){0.f, 0.f, 0.f, 0.f};
#pragma unroll
  for (int ks = 0; ks < 2; ks++) {
    short8 af[4], bf[4];
#pragma unroll
    for (int t = 0; t < 4; t++) af[t] = *(const short8*)&Qs[wm + t * 16 + fr][ks * 32 + fc];
#pragma unroll
    for (int t = 0; t < 4; t++) bf[t] = *(const short8*)&Ks[wn + t * 16 + fr][ks * 32 + fc];
#pragma unroll
    for (int i = 0; i < 4; i++)
#pragma unroll
      for (int j = 0; j < 4; j++)
        acc[i][j] = __builtin_amdgcn_mfma_f32_16x16x32_bf16(af[i], bf[j], acc[i][j], 0, 0, 0);
  }
  const int col0 = k0 + wn + fr;
  const int row0 = q0 + wm + (lane >> 4) * 4;
#pragma unroll
  for (int i = 0; i < 4; i++)
#pragma unroll
    for (int j = 0; j < 4; j++)
#pragma unroll
      for (int r = 0; r < 4; r++)
        sc[((size_t)h * 512 + row0 + i * 16 + r) * 1024 + col0 + j * 16] =
            f2b(acc[i][j][r] * 0.125f);
}

// ---------------------------------------------------------------------------
// Fused attout + softmax (one batch): block per q (512 blocks). 4 waves x 4 h
// each. Per (h,q)-row of 1024: relu-sum partial (pre-softmax) + in-place
// softmax, wave-level shfl reductions only. Cross-wave relu-sum via LDS ->
// ao[q,k] = sum_h relu(sc)/16 (f32).
// ---------------------------------------------------------------------------
__global__ __launch_bounds__(256) void smax_ao(bfr* __restrict__ sc,
                                               float* __restrict__ ao) {
  __shared__ float part[4][1024];
  const int q = blockIdx.x;
  const int tid = threadIdx.x, lane = tid & 63, w = tid >> 6;
  float aos[16];
#pragma unroll
  for (int i = 0; i < 16; i++) aos[i] = 0.f;
#pragma unroll
  for (int i = 0; i < 4; i++) {
    const int h = w * 4 + i;
    bfr* row = sc + ((size_t)h * 512 + q) * 1024 + lane * 16;
    us4 raw[4];
    float v[16];
#pragma unroll
    for (int j = 0; j < 4; j++) raw[j] = ((const us4*)row)[j];
#pragma unroll
    for (int j = 0; j < 4; j++) {
      v[j * 4 + 0] = b2f(raw[j].x); v[j * 4 + 1] = b2f(raw[j].y);
      v[j * 4 + 2] = b2f(raw[j].z); v[j * 4 + 3] = b2f(raw[j].w);
    }
    float m = v[0];
#pragma unroll
    for (int j = 1; j < 16; j++) m = fmaxf(m, v[j]);
#pragma unroll
    for (int j = 0; j < 16; j++) aos[j] += fmaxf(v[j], 0.f);
    for (int o = 32; o; o >>= 1) m = fmaxf(m, __shfl_xor(m, o, 64));
    float s = 0.f;
#pragma unroll
    for (int j = 0; j < 16; j++) { v[j] = expf(v[j] - m); s += v[j]; }
    for (int o = 32; o; o >>= 1) s += __shfl_xor(s, o, 64);
    const float inv = 1.0f / s;
#pragma unroll
    for (int j = 0; j < 4; j++) {
      raw[j].x = f2b(v[j * 4 + 0] * inv); raw[j].y = f2b(v[j * 4 + 1] * inv);
      raw[j].z = f2b(v[j * 4 + 2] * inv); raw[j].w = f2b(v[j * 4 + 3] * inv);
      ((us4*)row)[j] = raw[j];
    }
  }
#pragma unroll
  for (int j = 0; j < 4; j++)
    *(float4*)&part[w][lane * 16 + j * 4] =
        make_float4(aos[j * 4], aos[j * 4 + 1], aos[j * 4 + 2], aos[j * 4 + 3]);
  __syncthreads();
  const int k4 = tid * 4;
  float4 a0 = *(const float4*)&part[0][k4];
  float4 a1 = *(const float4*)&part[1][k4];
  float4 a2 = *(const float4*)&part[2][k4];
  float4 a3 = *(const float4*)&part[3][k4];
  store4(ao + (size_t)q * 1024 + k4,
         (a0.x + a1.x + a2.x + a3.x) * 0.0625f, (a0.y + a1.y + a2.y + a3.y) * 0.0625f,
         (a0.z + a1.z + a2.z + a3.z) * 0.0625f, (a0.w + a1.w + a2.w + a3.w) * 0.0625f);
}

// ---------------------------------------------------------------------------
// MFMA att@V (one batch): vT is [h][128 d'][1024 k] with d'<64 = v1 rows,
// d'>=64 = v0 rows (interleaved at weight-transpose time). Output tile
// 32q x 128d' per block, grid (16 qb, 16 h), 4 waves (2 row x 2 col halves),
// K-step 64: 8 MFMA per wave per barrier pair. Bias exact (softmax rows sum
// to 1). Waves 0-1 -> atp (+bv), waves 2-3 -> u (+bv0): wave-uniform.
// ---------------------------------------------------------------------------
__global__ __launch_bounds__(256) void attv2(const bfr* __restrict__ att,
                                             const bfr* __restrict__ vT,
                                             const float* __restrict__ bv,
                                             const float* __restrict__ bv0,
                                             bfr* __restrict__ atp,
                                             bfr* __restrict__ u) {
  __shared__ __align__(16) bfr As[32][72];
  __shared__ __align__(16) bfr Bs[128][72];
  const int h = blockIdx.y, q0 = blockIdx.x * 32;
  const int tid = threadIdx.x, lane = tid & 63, w = tid >> 6;
  const int fr = lane & 15, fc = (lane >> 4) * 8;
  const int wm = (w & 1) * 16, wn = (w >> 1) * 64;
  const bfr* attb = att + ((size_t)h * 512 + q0) * 1024;
  const bfr* vb = vT + (size_t)h * 128 * 1024;
  const int ar = tid >> 3, ac = (tid & 7) * 8;
  const int br = tid >> 2, bc = (tid & 3) * 16;
  f32x4 acc[4];
#pragma unroll
  for (int t = 0; t < 4; t++) acc[t] = (f32x4){0.f, 0.f, 0.f, 0.f};
  for (int k0 = 0; k0 < 1024; k0 += 64) {
    *(short8*)&As[ar][ac] = *(const short8*)(attb + (size_t)ar * 1024 + k0 + ac);
    stage16(vb + (size_t)br * 1024 + k0 + bc, &Bs[br][bc]);
    stage16(vb + (size_t)(br + 64) * 1024 + k0 + bc, &Bs[br + 64][bc]);
    __syncthreads();
#pragma unroll
    for (int ks = 0; ks < 2; ks++) {
      short8 af = *(const short8*)&As[wm + fr][ks * 32 + fc];
#pragma unroll
      for (int t = 0; t < 4; t++) {
        short8 bf = *(const short8*)&Bs[wn + t * 16 + fr][ks * 32 + fc];
        acc[t] = __builtin_amdgcn_mfma_f32_16x16x32_bf16(af, bf, acc[t], 0, 0, 0);
      }
    }
    __syncthreads();
  }
  const int row0 = q0 + wm + (lane >> 4) * 4;
  bfr* o = (wn == 0) ? atp : u;
  const float* bias = (wn == 0) ? bv : bv0;
#pragma unroll
  for (int t = 0; t < 4; t++) {
    const int cm = t * 16 + fr;  // 0..63 within the selected half
    const float bb = bias[h * 64 + cm];
#pragma unroll
    for (int r = 0; r < 4; r++)
      o[(size_t)(row0 + r) * 1024 + h * 64 + cm] = f2b(acc[t][r] + bb);
  }
}

// xpre_b[c] += sum over 64 rows of q0p_b[v,c]*u_b[v,c] (per batch), grid (4,8)
__global__ __launch_bounds__(256) void xpre_kernel(const bfr* __restrict__ q0p,
                                                   const bfr* __restrict__ u,
                                                   float* __restrict__ xpre) {
  const int c = blockIdx.x * 256 + threadIdx.x;
  const int r0 = blockIdx.y * 64;
  const bfr* qp = q0p + (size_t)r0 * 1024 + c;
  const bfr* up = u + (size_t)r0 * 1024 + c;
  float s = 0.f;
#pragma unroll 8
  for (int r = 0; r < 64; r++)
    s = fmaf(b2f(qp[(size_t)r * 1024]), b2f(up[(size_t)r * 1024]), s);
  atomicAdd(&xpre[c], s);
}

// torch_ln over rows of 1024: a*(x-mean)/(sqrt(var_unbiased)+1e-6)+b, X (+Y)
template <typename TX, typename TY, typename OT>
__global__ __launch_bounds__(256) void ln_kernel(const TX* __restrict__ X,
                                                 const TY* __restrict__ Y,
                                                 const float* __restrict__ ga,
                                                 const float* __restrict__ be,
                                                 OT* __restrict__ out) {
  __shared__ float sm[4];
  const size_t row = blockIdx.x;
  const int tid = threadIdx.x;
  float4 v = load4f(X + row * 1024 + tid * 4);
  if (Y) {
    float4 w = load4f(Y + row * 1024 + tid * 4);
    v.x += w.x; v.y += w.y; v.z += w.z; v.w += w.w;
  }
  float s = v.x + v.y + v.z + v.w;
  for (int o = 32; o; o >>= 1) s += __shfl_down(s, o, 64);
  if ((tid & 63) == 0) sm[tid >> 6] = s;
  __syncthreads();
  s = sm[0] + sm[1] + sm[2] + sm[3];
  float mean = s * (1.0f / 1024.0f);
  float d0 = v.x - mean, d1 = v.y - mean, d2 = v.z - mean, d3 = v.w - mean;
  float q = d0 * d0 + d1 * d1 + d2 * d2 + d3 * d3;
  __syncthreads();
  for (int o = 32; o; o >>= 1) q += __shfl_down(q, o, 64);
  if ((tid & 63) == 0) sm[tid >> 6] = q;
  __syncthreads();
  q = sm[0] + sm[1] + sm[2] + sm[3];
  float rs = 1.0f / (sqrtf(q * (1.0f / 1023.0f)) + 1e-6f);
  float4 g = *(const float4*)(ga + tid * 4);
  float4 bb = *(const float4*)(be + tid * 4);
  store4(out + row * 1024 + tid * 4,
         g.x * d0 * rs + bb.x, g.y * d1 * rs + bb.y,
         g.z * d2 * rs + bb.z, g.w * d3 * rs + bb.w);
}

// ---------------------------------------------------------------------------
extern "C" void kernel_launch(void* const* d_in, const int* in_sizes, int n_in,
                              void* d_out, int out_size, void* d_ws, size_t ws_size,
                              hipStream_t stream) {
  (void)in_sizes; (void)n_in; (void)out_size; (void)ws_size;
  const float* q   = (const float*)d_in[0];
  const float* k   = (const float*)d_in[1];
  const float* Wq  = (const float*)d_in[2];
  const float* bq  = (const float*)d_in[3];
  const float* Wk  = (const float*)d_in[4];
  const float* bk  = (const float*)d_in[5];
  const float* Wv  = (const float*)d_in[6];
  const float* bv  = (const float*)d_in[7];
  const float* Wv0 = (const float*)d_in[8];
  const float* bv0 = (const float*)d_in[9];
  const float* Wq0 = (const float*)d_in[10];
  const float* bq0 = (const float*)d_in[11];
  const float* nqa = (const float*)d_in[12];
  const float* nqb = (const float*)d_in[13];
  const float* nxa = (const float*)d_in[14];
  const float* nxb = (const float*)d_in[15];
  const float* W1  = (const float*)d_in[16];
  const float* b1  = (const float*)d_in[17];
  const float* W2  = (const float*)d_in[18];
  const float* b2  = (const float*)d_in[19];
  const float* nsa = (const float*)d_in[20];
  const float* nsb = (const float*)d_in[21];

  float* out = (float*)d_out;
  float* x_out  = out;                       // 8,192
  float* qq_out = out + 8192;                // 4,194,304
  float* kp_out = out + 4202496;             // 6,291,456
  float* ao_out = out + 10493952;            // 4,194,304

  char* base = (char*)d_ws;
  // persistent (attention phase)
  bfr* q0p   = (bfr*)(base + 0);            // 8,388,608  [4096,1024]
  bfr* qh    = (bfr*)(base + 8388608);      // 8,388,608  [4096,1024]
  bfr* atl   = (bfr*)(base + 16777216);     // 8,388,608  [4096,1024] (to end)
  bfr* WqT   = (bfr*)(base + 25165824);     // 1,572,864  [1024,768]
  bfr* Wq0T  = (bfr*)(base + 26738688);     // 1,572,864
  bfr* WTkv  = (bfr*)(base + 28311552);     // 4,718,592  [WkT 1024; vv-interleaved 2048][768]
  float* xpre = (float*)(base + 33030144);  //    32,768  [8,1024]
  char* S = base + 33062912;                // scratch region
  // attention-loop overlay (23,068,672 B)
  bfr* sc    = (bfr*)(S + 0);               // 16,777,216 [16,512,1024]
  bfr* vT    = (bfr*)(S + 16777216);        //  4,194,304 [16][128][1024] v1|v0
  bfr* atpb  = (bfr*)(S + 20971520);        //  1,048,576 [512,1024]
  bfr* ub    = (bfr*)(S + 22020096);        //  1,048,576
  bfr* kh    = qh;                          // reuse? no -- kh needs own space
  // kh lives after ub would exceed scratch; reuse sc region is unsafe (score
  // writes sc while reading kh). Place kh in the FFN ff1n slot region:
  kh = (bfr*)(S + 0);                       // NOTE: overlaps sc! fixed below.
  // pre-loop overlay (dead before attention buffers first written)
  bfr* qp_all = (bfr*)(S + 0);              //  6,291,456 [4096,768]
  // FFN-phase overlay (attention buffers dead; q0p/qh dead)
  bfr* W1Tn  = (bfr*)(S + 0);               //  4,194,304 [2048,1024]
  bfr* W2Tn  = (bfr*)(S + 4194304);         //  4,194,304 [1024,2048]
  bfr* ff1n  = (bfr*)(S + 8388608);         // 16,777,216 [4096,2048]
  float* ff2a = (float*)(base + 0);         // 16,777,216 [4096,1024] f32 (over q0p/qh)
  // kh: needs 2 MiB live from its GEMM until score completes, per batch.
  // sc(16M)+vT(4M)+atpb+ub(2M) = 22 MiB; scratch has 25,165,824 -> kh fits at tail.
  kh = (bfr*)(S + 23068672);                //  2,097,152 [1024,1024]
  // peak footprint: 33,062,912 + 25,165,824 = 58,228,736 B

  // --- setup ---
  posenc_k<<<24576, 256, 0, stream>>>(k, kp_out, 6291456);
  posenc_q_all<<<12288, 256, 0, stream>>>(q, qp_all, 3145728);
  transpose_w<<<dim3(32, 24), 256, 0, stream>>>(Wq, WqT, 768, 1024, 1024, 0);
  transpose_w<<<dim3(32, 24), 256, 0, stream>>>(Wq0, Wq0T, 768, 1024, 1024, 0);
  transpose_w<<<dim3(32, 24), 256, 0, stream>>>(Wk, WTkv, 768, 1024, 1024, 0);
  transpose_w<<<dim3(32, 24), 256, 0, stream>>>(Wv, WTkv + 786432, 768, 1024, 1024, 1);
  transpose_w<<<dim3(32, 24), 256, 0, stream>>>(Wv0, WTkv + 786432, 768, 1024, 1024, 2);

  // full-batch projections (MFMA)
  mgemm<float, bfr, bfr><<<dim3(8, 32), 256, 0, stream>>>(q, Wq0T, bq0, q0p, 768, 1024, 0, 0);
  mgemm<bfr, bfr, bfr><<<dim3(8, 32), 256, 0, stream>>>(qp_all, WqT, bq, qh, 768, 1024, 0, 0);
  hipMemsetAsync(xpre, 0, 32768, stream);

  // --- per-batch attention ---
  for (int b = 0; b < 8; b++) {
    const float* kp_b = kp_out + (size_t)b * 786432;
    // kh = kp @ Wk + bk  [1024,1024]
    mgemm<float, bfr, bfr><<<dim3(8, 8), 256, 0, stream>>>(
        kp_b, WTkv, bk, kh, 768, 1024, 0, 0);
    // vT (interleaved v1|v0 per h) = WTvv @ kp^T  [2048,1024]
    mgemm<bfr, float, bfr><<<dim3(8, 16), 256, 0, stream>>>(
        WTkv + 786432, kp_b, nullptr, vT, 768, 1024, 0, 0);
    score_mfma<<<dim3(8, 4, 16), 256, 0, stream>>>(qh + (size_t)b * 524288, kh, sc);
    smax_ao<<<512, 256, 0, stream>>>(sc, ao_out + (size_t)b * 524288);
    attv2<<<dim3(16, 16), 256, 0, stream>>>(sc, vT, bv, bv0, atpb, ub);
    xpre_kernel<<<dim3(4, 8), 256, 0, stream>>>(q0p + (size_t)b * 524288, ub,
                                                xpre + b * 1024);
    ln_kernel<bfr, bfr, bfr><<<512, 256, 0, stream>>>(
        q0p + (size_t)b * 524288, atpb, nqa, nqb, atl + (size_t)b * 524288);
  }

  // x = LN(bilinear)
  ln_kernel<float, float, float><<<8, 256, 0, stream>>>(xpre, (const float*)nullptr,
                                                        nxa, nxb, x_out);

  // --- FFN, K-split into 2 chunks of 2048, f32 accumulation in ff2a ---
  for (int nc = 0; nc < 2; nc++) {
    transpose_w<<<dim3(64, 32), 256, 0, stream>>>(W1 + nc * 2048, W1Tn,
                                                  1024, 2048, 4096, 0);
    transpose_w<<<dim3(32, 64), 256, 0, stream>>>(W2 + (size_t)nc * 2048 * 1024, W2Tn,
                                                  2048, 1024, 1024, 0);
    mgemm<bfr, bfr, bfr><<<dim3(16, 32), 256, 0, stream>>>(
        atl, W1Tn, b1 + nc * 2048, ff1n, 1024, 2048, 1, 0);
    mgemm<bfr, bfr, float><<<dim3(8, 32), 256, 0, stream>>>(
        ff1n, W2Tn, nc == 0 ? b2 : nullptr, ff2a, 2048, 1024, 0, nc);
  }
  ln_kernel<bfr, float, float><<<4096, 256, 0, stream>>>(atl, ff2a, nsa, nsb, qq_out);
}

// Round 3
// 1222.365 us; speedup vs baseline: 1.7132x; 1.0087x over previous
//
#include <hip/hip_runtime.h>

// ---------------------------------------------------------------------------
// FocalAtt (CA mode): B=8, Lq=512, Lk=1024, qd=kd=768, hid=1024, mid=4096,
// H=16, dh=64. Inputs f32, outputs f32. bf16 MFMA GEMMs (16x16x32), fp32 acc.
// R3: mgemm staged via __builtin_amdgcn_global_load_lds (width 16) for bf16
// operands, linear LDS [128][32] (m97 recipe); XCD-aware bijective block
// swizzle (m204). f32 operands keep reg-stage+convert.
// Workspace peak 58,228,736 B (< known-good 58,490,880).
// ---------------------------------------------------------------------------

typedef unsigned short bfr;  // raw bf16 bits
using short8 = __attribute__((ext_vector_type(8))) short;
using f32x4  = __attribute__((ext_vector_type(4))) float;

__device__ __forceinline__ float b2f(bfr s) {
  return __uint_as_float(((unsigned int)s) << 16);
}
__device__ __forceinline__ bfr f2b(float f) {
  unsigned int u = __float_as_uint(f);
  u += 0x7fffu + ((u >> 16) & 1u);  // RNE
  return (bfr)(u >> 16);
}

struct __align__(8) us4 { bfr x, y, z, w; };

__device__ __forceinline__ float4 load4f(const float* p) { return *(const float4*)p; }
__device__ __forceinline__ float4 load4f(const bfr* p) {
  us4 u = *(const us4*)p;
  return make_float4(b2f(u.x), b2f(u.y), b2f(u.z), b2f(u.w));
}
__device__ __forceinline__ void store4(float* p, float a, float b, float c, float d) {
  *(float4*)p = make_float4(a, b, c, d);
}
__device__ __forceinline__ void store4(bfr* p, float a, float b, float c, float d) {
  us4 v; v.x = f2b(a); v.y = f2b(b); v.z = f2b(c); v.w = f2b(d);
  *(us4*)p = v;
}

// async global(bf16 x8, 16B) -> LDS at wave-uniform base + lane*16B
__device__ __forceinline__ void gll16(const bfr* g, bfr* l) {
  __builtin_amdgcn_global_load_lds(
      (const __attribute__((address_space(1))) unsigned int*)g,
      (__attribute__((address_space(3))) unsigned int*)l, 16, 0, 0);
}

// ---------------------------------------------------------------------------
// Positional encoding
// ---------------------------------------------------------------------------
__device__ __forceinline__ float pe_val(int l, int d) {
  float ang = (float)l * expf((float)(d & ~1) * (-9.210340371976184f / 768.0f));
  return (d & 1) ? cosf(ang) : sinf(ang);
}

// k + PE -> f32 kp (d_out; also K/V projection A/B-input). total = 8*1024*768
__global__ __launch_bounds__(256) void posenc_k(const float* __restrict__ in,
                                                float* __restrict__ outf, int total) {
  int idx = blockIdx.x * 256 + threadIdx.x;
  if (idx >= total) return;
  outf[idx] = in[idx] + pe_val((idx / 768) % 1024, idx % 768);
}

// q + PE -> bf16 qp_all [4096,768]
__global__ __launch_bounds__(256) void posenc_q_all(const float* __restrict__ in,
                                                    bfr* __restrict__ out, int total) {
  int idx = blockIdx.x * 256 + threadIdx.x;
  if (idx >= total) return;
  out[idx] = f2b(in[idx] + pe_val((idx / 768) % 512, idx % 768));
}

// ---------------------------------------------------------------------------
// Weight transpose: src f32 [rows, cols] (row stride ld) -> dst bf16 [cols, rows]
// grid (cols/32, rows/32), 256 threads. mode: dst-row remap for interleaved
// v1|v0 stacking. 0: r=c; 1: r=(c>>6)*128+(c&63); 2: r=(c>>6)*128+64+(c&63).
// ---------------------------------------------------------------------------
__global__ __launch_bounds__(256) void transpose_w(const float* __restrict__ src,
                                                   bfr* __restrict__ dst,
                                                   int rows, int cols, int ld,
                                                   int mode) {
  __shared__ float t[32][33];
  const int bc = blockIdx.x * 32, br = blockIdx.y * 32;
  const int tx = threadIdx.x & 31, ty = threadIdx.x >> 5;  // ty 0..7
#pragma unroll
  for (int i = 0; i < 4; i++)
    t[ty + i * 8][tx] = src[(size_t)(br + ty + i * 8) * ld + bc + tx];
  __syncthreads();
#pragma unroll
  for (int i = 0; i < 4; i++) {
    int c = bc + ty + i * 8;
    int r = (mode == 0) ? c : ((c >> 6) * 128 + (c & 63) + (mode == 2 ? 64 : 0));
    dst[(size_t)r * rows + br + tx] = f2b(t[tx][ty + i * 8]);
  }
}

// ---------------------------------------------------------------------------
// MFMA GEMM: C[M,N] = A[M,K] @ B[K,N] (+bias, relu, accum). B passed as
// BT[N,K] (pre-transposed). 128x128 block, 256 thr = 4 waves, each wave
// 64x64 via 4x4 of v_mfma_f32_16x16x32_bf16. BK=32. All dims %128==0, K%32==0.
// bf16 operands staged async via global_load_lds (LDS linear [128][32], m97);
// f32 operands reg-staged + converted. XCD-bijective block swizzle (m204).
// A-frag: lane holds A[m=lane&15][k=(lane>>4)*8+j]; D: row=(lane>>4)*4+r,
// col=lane&15 (measured m89/m91 layouts).
// ---------------------------------------------------------------------------
__device__ __forceinline__ void stage16f(const float* __restrict__ s, bfr* d) {
  bfr tmp[16];
#pragma unroll
  for (int i = 0; i < 16; i += 4) {
    float4 v = *(const float4*)(s + i);
    tmp[i] = f2b(v.x); tmp[i + 1] = f2b(v.y);
    tmp[i + 2] = f2b(v.z); tmp[i + 3] = f2b(v.w);
  }
  *(short8*)d = *(short8*)&tmp[0];
  *(short8*)(d + 8) = *(short8*)&tmp[8];
}

template <typename TA, typename TB, typename TC>
__global__ __launch_bounds__(256) void mgemm(const TA* __restrict__ A,
                                             const TB* __restrict__ BT,
                                             const float* __restrict__ bias,
                                             TC* __restrict__ C,
                                             int K, int ldc, int relu, int accum) {
  __shared__ bfr As[128 * 32];  // linear, row stride 64 B
  __shared__ bfr Bs[128 * 32];
  const int tid = threadIdx.x;
  // XCD-bijective swizzle of linear block id (all grids are %8 == 0 anyway)
  const int nwg = gridDim.x * gridDim.y;
  const int bid = blockIdx.y * gridDim.x + blockIdx.x;
  const int q8 = nwg >> 3, r8 = nwg & 7;
  const int xcd = bid & 7, off = bid >> 3;
  const int swz = (xcd < r8 ? xcd * (q8 + 1) : r8 * (q8 + 1) + (xcd - r8) * q8) + off;
  const int n0 = (swz % gridDim.x) * 128, m0 = (swz / gridDim.x) * 128;
  const int lane = tid & 63, w = tid >> 6;
  const int wm = (w & 1) * 64, wn = (w >> 1) * 64;
  const int sr = tid >> 1, sc16 = (tid & 1) * 16;      // f32 staging coords
  const int grow = w * 32 + (lane >> 2), gkc = (lane & 3) * 8;  // gll coords
  const int fr = lane & 15, fc = (lane >> 4) * 8;
  f32x4 acc[4][4];
#pragma unroll
  for (int i = 0; i < 4; i++)
#pragma unroll
    for (int j = 0; j < 4; j++) acc[i][j] = (f32x4){0.f, 0.f, 0.f, 0.f};
  for (int k0 = 0; k0 < K; k0 += 32) {
    if constexpr (sizeof(TA) == 2) {
      gll16(A + (size_t)(m0 + grow) * K + k0 + gkc, &As[(w * 32) * 32]);
      gll16(A + (size_t)(m0 + grow + 16) * K + k0 + gkc, &As[(w * 32 + 16) * 32]);
    } else {
      stage16f(A + (size_t)(m0 + sr) * K + k0 + sc16, &As[sr * 32 + sc16]);
    }
    if constexpr (sizeof(TB) == 2) {
      gll16(BT + (size_t)(n0 + grow) * K + k0 + gkc, &Bs[(w * 32) * 32]);
      gll16(BT + (size_t)(n0 + grow + 16) * K + k0 + gkc, &Bs[(w * 32 + 16) * 32]);
    } else {
      stage16f(BT + (size_t)(n0 + sr) * K + k0 + sc16, &Bs[sr * 32 + sc16]);
    }
    __syncthreads();
    short8 af[4], bf[4];
#pragma unroll
    for (int t = 0; t < 4; t++) af[t] = *(const short8*)&As[(wm + t * 16 + fr) * 32 + fc];
#pragma unroll
    for (int t = 0; t < 4; t++) bf[t] = *(const short8*)&Bs[(wn + t * 16 + fr) * 32 + fc];
#pragma unroll
    for (int i = 0; i < 4; i++)
#pragma unroll
      for (int j = 0; j < 4; j++)
        acc[i][j] = __builtin_amdgcn_mfma_f32_16x16x32_bf16(af[i], bf[j], acc[i][j], 0, 0, 0);
    __syncthreads();
  }
  const int col0 = n0 + wn + fr;
  const int row0 = m0 + wm + (lane >> 4) * 4;
  float bsv[4];
#pragma unroll
  for (int j = 0; j < 4; j++) bsv[j] = bias ? bias[col0 + j * 16] : 0.f;
#pragma unroll
  for (int i = 0; i < 4; i++) {
#pragma unroll
    for (int j = 0; j < 4; j++) {
      const int col = col0 + j * 16;
#pragma unroll
      for (int r = 0; r < 4; r++) {
        const int row = row0 + i * 16 + r;
        float v = acc[i][j][r] + bsv[j];
        if (relu) v = fmaxf(v, 0.f);
        size_t idx = (size_t)row * ldc + col;
        if constexpr (sizeof(TC) == 2) {
          C[idx] = f2b(v);
        } else {
          if (accum) C[idx] += v; else C[idx] = v;
        }
      }
    }
  }
}

// ---------------------------------------------------------------------------
// MFMA scores (one batch): sc[h,q,k] = dot_64(qh[q,h*64+:], kh[k,h*64+:]) / 8
// 128x128 tile, K=64 (two 32-steps, staged once). grid (8 kb, 4 qb, 16 h).
// ---------------------------------------------------------------------------
__global__ __launch_bounds__(256) void score_mfma(const bfr* __restrict__ qh,
                                                  const bfr* __restrict__ kh,
                                                  bfr* __restrict__ sc) {
  __shared__ __align__(16) bfr Qs[128][72];  // stride 144 B: 2-way max, free
  __shared__ __align__(16) bfr Ks[128][72];
  const int h = blockIdx.z, q0 = blockIdx.y * 128, k0 = blockIdx.x * 128;
  const int tid = threadIdx.x, lane = tid & 63;
  const int wm = ((tid >> 6) & 1) * 64, wn = (tid >> 7) * 64;
  const int fr = lane & 15, fc = (lane >> 4) * 8;
  {
    const int r = tid >> 1, c = (tid & 1) * 32;
    const bfr* qsrc = qh + (size_t)(q0 + r) * 1024 + h * 64 + c;
    const bfr* ksrc = kh + (size_t)(k0 + r) * 1024 + h * 64 + c;
#pragma unroll
    for (int i = 0; i < 4; i++) {
      *(short8*)&Qs[r][c + i * 8] = *(const short8*)(qsrc + i * 8);
      *(short8*)&Ks[r][c + i * 8] = *(const short8*)(ksrc + i * 8);
    }
  }
  __syncthreads();
  f32x4 acc[4][4];
#pragma unroll
  for (int i = 0; i < 4; i++)
#pragma unroll
    for (int j = 0; j < 4; j++) acc[i][j] = (f32x4){0.f, 0.f, 0.f, 0.f};
#pragma unroll
  for (int ks = 0; ks < 2; ks++) {
    short8 af[4], bf[4];
#pragma unroll
    for (int t = 0; t < 4; t++) af[t] = *(const short8*)&Qs[wm + t * 16 + fr][ks * 32 + fc];
#pragma unroll
    for (int t = 0; t < 4; t++) bf[t] = *(const short8*)&Ks[wn + t * 16 + fr][ks * 32 + fc];
#pragma unroll
    for (int i = 0; i < 4; i++)
#pragma unroll
      for (int j = 0; j < 4; j++)
        acc[i][j] = __builtin_amdgcn_mfma_f32_16x16x32_bf16(af[i], bf[j], acc[i][j], 0, 0, 0);
  }
  const int col0 = k0 + wn + fr;
  const int row0 = q0 + wm + (lane >> 4) * 4;
#pragma unroll
  for (int i = 0; i < 4; i++)
#pragma unroll
    for (int j = 0; j < 4; j++)
#pragma unroll
      for (int r = 0; r < 4; r++)
        sc[((size_t)h * 512 + row0 + i * 16 + r) * 1024 + col0 + j * 16] =
            f2b(acc[i][j][r] * 0.125f);
}

// ---------------------------------------------------------------------------
// Fused attout + softmax (one batch): block per q (512 blocks). 4 waves x 4 h
// each. Per (h,q)-row of 1024: relu-sum partial (pre-softmax) + in-place
// softmax, wave-level shfl reductions only. Cross-wave relu-sum via LDS ->
// ao[q,k] = sum_h relu(sc)/16 (f32).
// ---------------------------------------------------------------------------
__global__ __launch_bounds__(256) void smax_ao(bfr* __restrict__ sc,
                                               float* __restrict__ ao) {
  __shared__ float part[4][1024];
  const int q = blockIdx.x;
  const int tid = threadIdx.x, lane = tid & 63, w = tid >> 6;
  float aos[16];
#pragma unroll
  for (int i = 0; i < 16; i++) aos[i] = 0.f;
#pragma unroll
  for (int i = 0; i < 4; i++) {
    const int h = w * 4 + i;
    bfr* row = sc + ((size_t)h * 512 + q) * 1024 + lane * 16;
    us4 raw[4];
    float v[16];
#pragma unroll
    for (int j = 0; j < 4; j++) raw[j] = ((const us4*)row)[j];
#pragma unroll
    for (int j = 0; j < 4; j++) {
      v[j * 4 + 0] = b2f(raw[j].x); v[j * 4 + 1] = b2f(raw[j].y);
      v[j * 4 + 2] = b2f(raw[j].z); v[j * 4 + 3] = b2f(raw[j].w);
    }
    float m = v[0];
#pragma unroll
    for (int j = 1; j < 16; j++) m = fmaxf(m, v[j]);
#pragma unroll
    for (int j = 0; j < 16; j++) aos[j] += fmaxf(v[j], 0.f);
    for (int o = 32; o; o >>= 1) m = fmaxf(m, __shfl_xor(m, o, 64));
    float s = 0.f;
#pragma unroll
    for (int j = 0; j < 16; j++) { v[j] = expf(v[j] - m); s += v[j]; }
    for (int o = 32; o; o >>= 1) s += __shfl_xor(s, o, 64);
    const float inv = 1.0f / s;
#pragma unroll
    for (int j = 0; j < 4; j++) {
      raw[j].x = f2b(v[j * 4 + 0] * inv); raw[j].y = f2b(v[j * 4 + 1] * inv);
      raw[j].z = f2b(v[j * 4 + 2] * inv); raw[j].w = f2b(v[j * 4 + 3] * inv);
      ((us4*)row)[j] = raw[j];
    }
  }
#pragma unroll
  for (int j = 0; j < 4; j++)
    *(float4*)&part[w][lane * 16 + j * 4] =
        make_float4(aos[j * 4], aos[j * 4 + 1], aos[j * 4 + 2], aos[j * 4 + 3]);
  __syncthreads();
  const int k4 = tid * 4;
  float4 a0 = *(const float4*)&part[0][k4];
  float4 a1 = *(const float4*)&part[1][k4];
  float4 a2 = *(const float4*)&part[2][k4];
  float4 a3 = *(const float4*)&part[3][k4];
  store4(ao + (size_t)q * 1024 + k4,
         (a0.x + a1.x + a2.x + a3.x) * 0.0625f, (a0.y + a1.y + a2.y + a3.y) * 0.0625f,
         (a0.z + a1.z + a2.z + a3.z) * 0.0625f, (a0.w + a1.w + a2.w + a3.w) * 0.0625f);
}

// ---------------------------------------------------------------------------
// MFMA att@V (one batch): vT is [h][128 d'][1024 k] with d'<64 = v1 rows,
// d'>=64 = v0 rows (interleaved at weight-transpose time). Output tile
// 32q x 128d' per block, grid (16 qb, 16 h), 4 waves (2 row x 2 col halves),
// K-step 64: 8 MFMA per wave per barrier pair. Bias exact (softmax rows sum
// to 1). Waves 0-1 -> atp (+bv), waves 2-3 -> u (+bv0): wave-uniform.
// ---------------------------------------------------------------------------
__global__ __launch_bounds__(256) void attv2(const bfr* __restrict__ att,
                                             const bfr* __restrict__ vT,
                                             const float* __restrict__ bv,
                                             const float* __restrict__ bv0,
                                             bfr* __restrict__ atp,
                                             bfr* __restrict__ u) {
  __shared__ __align__(16) bfr As[32][72];
  __shared__ __align__(16) bfr Bs[128][72];
  const int h = blockIdx.y, q0 = blockIdx.x * 32;
  const int tid = threadIdx.x, lane = tid & 63, w = tid >> 6;
  const int fr = lane & 15, fc = (lane >> 4) * 8;
  const int wm = (w & 1) * 16, wn = (w >> 1) * 64;
  const bfr* attb = att + ((size_t)h * 512 + q0) * 1024;
  const bfr* vb = vT + (size_t)h * 128 * 1024;
  const int ar = tid >> 3, ac = (tid & 7) * 8;
  const int br = tid >> 2, bc = (tid & 3) * 16;
  f32x4 acc[4];
#pragma unroll
  for (int t = 0; t < 4; t++) acc[t] = (f32x4){0.f, 0.f, 0.f, 0.f};
  for (int k0 = 0; k0 < 1024; k0 += 64) {
    *(short8*)&As[ar][ac] = *(const short8*)(attb + (size_t)ar * 1024 + k0 + ac);
    *(short8*)&Bs[br][bc] = *(const short8*)(vb + (size_t)br * 1024 + k0 + bc);
    *(short8*)&Bs[br][bc + 8] = *(const short8*)(vb + (size_t)br * 1024 + k0 + bc + 8);
    *(short8*)&Bs[br + 64][bc] = *(const short8*)(vb + (size_t)(br + 64) * 1024 + k0 + bc);
    *(short8*)&Bs[br + 64][bc + 8] =
        *(const short8*)(vb + (size_t)(br + 64) * 1024 + k0 + bc + 8);
    __syncthreads();
#pragma unroll
    for (int ks = 0; ks < 2; ks++) {
      short8 af = *(const short8*)&As[wm + fr][ks * 32 + fc];
#pragma unroll
      for (int t = 0; t < 4; t++) {
        short8 bf = *(const short8*)&Bs[wn + t * 16 + fr][ks * 32 + fc];
        acc[t] = __builtin_amdgcn_mfma_f32_16x16x32_bf16(af, bf, acc[t], 0, 0, 0);
      }
    }
    __syncthreads();
  }
  const int row0 = q0 + wm + (lane >> 4) * 4;
  bfr* o = (wn == 0) ? atp : u;
  const float* bias = (wn == 0) ? bv : bv0;
#pragma unroll
  for (int t = 0; t < 4; t++) {
    const int cm = t * 16 + fr;  // 0..63 within the selected half
    const float bb = bias[h * 64 + cm];
#pragma unroll
    for (int r = 0; r < 4; r++)
      o[(size_t)(row0 + r) * 1024 + h * 64 + cm] = f2b(acc[t][r] + bb);
  }
}

// xpre_b[c] += sum over 64 rows of q0p_b[v,c]*u_b[v,c] (per batch), grid (4,8)
__global__ __launch_bounds__(256) void xpre_kernel(const bfr* __restrict__ q0p,
                                                   const bfr* __restrict__ u,
                                                   float* __restrict__ xpre) {
  const int c = blockIdx.x * 256 + threadIdx.x;
  const int r0 = blockIdx.y * 64;
  const bfr* qp = q0p + (size_t)r0 * 1024 + c;
  const bfr* up = u + (size_t)r0 * 1024 + c;
  float s = 0.f;
#pragma unroll 8
  for (int r = 0; r < 64; r++)
    s = fmaf(b2f(qp[(size_t)r * 1024]), b2f(up[(size_t)r * 1024]), s);
  atomicAdd(&xpre[c], s);
}

// torch_ln over rows of 1024: a*(x-mean)/(sqrt(var_unbiased)+1e-6)+b, X (+Y)
template <typename TX, typename TY, typename OT>
__global__ __launch_bounds__(256) void ln_kernel(const TX* __restrict__ X,
                                                 const TY* __restrict__ Y,
                                                 const float* __restrict__ ga,
                                                 const float* __restrict__ be,
                                                 OT* __restrict__ out) {
  __shared__ float sm[4];
  const size_t row = blockIdx.x;
  const int tid = threadIdx.x;
  float4 v = load4f(X + row * 1024 + tid * 4);
  if (Y) {
    float4 w = load4f(Y + row * 1024 + tid * 4);
    v.x += w.x; v.y += w.y; v.z += w.z; v.w += w.w;
  }
  float s = v.x + v.y + v.z + v.w;
  for (int o = 32; o; o >>= 1) s += __shfl_down(s, o, 64);
  if ((tid & 63) == 0) sm[tid >> 6] = s;
  __syncthreads();
  s = sm[0] + sm[1] + sm[2] + sm[3];
  float mean = s * (1.0f / 1024.0f);
  float d0 = v.x - mean, d1 = v.y - mean, d2 = v.z - mean, d3 = v.w - mean;
  float q = d0 * d0 + d1 * d1 + d2 * d2 + d3 * d3;
  __syncthreads();
  for (int o = 32; o; o >>= 1) q += __shfl_down(q, o, 64);
  if ((tid & 63) == 0) sm[tid >> 6] = q;
  __syncthreads();
  q = sm[0] + sm[1] + sm[2] + sm[3];
  float rs = 1.0f / (sqrtf(q * (1.0f / 1023.0f)) + 1e-6f);
  float4 g = *(const float4*)(ga + tid * 4);
  float4 bb = *(const float4*)(be + tid * 4);
  store4(out + row * 1024 + tid * 4,
         g.x * d0 * rs + bb.x, g.y * d1 * rs + bb.y,
         g.z * d2 * rs + bb.z, g.w * d3 * rs + bb.w);
}

// ---------------------------------------------------------------------------
extern "C" void kernel_launch(void* const* d_in, const int* in_sizes, int n_in,
                              void* d_out, int out_size, void* d_ws, size_t ws_size,
                              hipStream_t stream) {
  (void)in_sizes; (void)n_in; (void)out_size; (void)ws_size;
  const float* q   = (const float*)d_in[0];
  const float* k   = (const float*)d_in[1];
  const float* Wq  = (const float*)d_in[2];
  const float* bq  = (const float*)d_in[3];
  const float* Wk  = (const float*)d_in[4];
  const float* bk  = (const float*)d_in[5];
  const float* Wv  = (const float*)d_in[6];
  const float* bv  = (const float*)d_in[7];
  const float* Wv0 = (const float*)d_in[8];
  const float* bv0 = (const float*)d_in[9];
  const float* Wq0 = (const float*)d_in[10];
  const float* bq0 = (const float*)d_in[11];
  const float* nqa = (const float*)d_in[12];
  const float* nqb = (const float*)d_in[13];
  const float* nxa = (const float*)d_in[14];
  const float* nxb = (const float*)d_in[15];
  const float* W1  = (const float*)d_in[16];
  const float* b1  = (const float*)d_in[17];
  const float* W2  = (const float*)d_in[18];
  const float* b2  = (const float*)d_in[19];
  const float* nsa = (const float*)d_in[20];
  const float* nsb = (const float*)d_in[21];

  float* out = (float*)d_out;
  float* x_out  = out;                       // 8,192
  float* qq_out = out + 8192;                // 4,194,304
  float* kp_out = out + 4202496;             // 6,291,456
  float* ao_out = out + 10493952;            // 4,194,304

  char* base = (char*)d_ws;
  // persistent (attention phase)
  bfr* q0p   = (bfr*)(base + 0);            // 8,388,608  [4096,1024]
  bfr* qh    = (bfr*)(base + 8388608);      // 8,388,608  [4096,1024]
  bfr* atl   = (bfr*)(base + 16777216);     // 8,388,608  [4096,1024]
  bfr* WqT   = (bfr*)(base + 25165824);     // 1,572,864  [1024,768]
  bfr* Wq0T  = (bfr*)(base + 26738688);     // 1,572,864
  bfr* WTkv  = (bfr*)(base + 28311552);     // 4,718,592  [WkT 1024; vv-interleaved 2048][768]
  float* xpre = (float*)(base + 33030144);  //    32,768  [8,1024]
  char* S = base + 33062912;                // scratch region (25,165,824 B)
  // attention-loop overlay
  bfr* sc    = (bfr*)(S + 0);               // 16,777,216 [16,512,1024]
  bfr* vT    = (bfr*)(S + 16777216);        //  4,194,304 [16][128][1024] v1|v0
  bfr* atpb  = (bfr*)(S + 20971520);        //  1,048,576 [512,1024]
  bfr* ub    = (bfr*)(S + 22020096);        //  1,048,576
  bfr* kh    = (bfr*)(S + 23068672);        //  2,097,152 [1024,1024]
  // pre-loop overlay (dead before attention buffers first written)
  bfr* qp_all = (bfr*)(S + 0);              //  6,291,456 [4096,768]
  // FFN-phase overlay (attention buffers dead; q0p/qh dead)
  bfr* W1Tn  = (bfr*)(S + 0);               //  4,194,304 [2048,1024]
  bfr* W2Tn  = (bfr*)(S + 4194304);         //  4,194,304 [1024,2048]
  bfr* ff1n  = (bfr*)(S + 8388608);         // 16,777,216 [4096,2048]
  float* ff2a = (float*)(base + 0);         // 16,777,216 [4096,1024] f32 (over q0p/qh)
  // peak footprint: 33,062,912 + 25,165,824 = 58,228,736 B

  // --- setup ---
  posenc_k<<<24576, 256, 0, stream>>>(k, kp_out, 6291456);
  posenc_q_all<<<12288, 256, 0, stream>>>(q, qp_all, 3145728);
  transpose_w<<<dim3(32, 24), 256, 0, stream>>>(Wq, WqT, 768, 1024, 1024, 0);
  transpose_w<<<dim3(32, 24), 256, 0, stream>>>(Wq0, Wq0T, 768, 1024, 1024, 0);
  transpose_w<<<dim3(32, 24), 256, 0, stream>>>(Wk, WTkv, 768, 1024, 1024, 0);
  transpose_w<<<dim3(32, 24), 256, 0, stream>>>(Wv, WTkv + 786432, 768, 1024, 1024, 1);
  transpose_w<<<dim3(32, 24), 256, 0, stream>>>(Wv0, WTkv + 786432, 768, 1024, 1024, 2);

  // full-batch projections (MFMA)
  mgemm<float, bfr, bfr><<<dim3(8, 32), 256, 0, stream>>>(q, Wq0T, bq0, q0p, 768, 1024, 0, 0);
  mgemm<bfr, bfr, bfr><<<dim3(8, 32), 256, 0, stream>>>(qp_all, WqT, bq, qh, 768, 1024, 0, 0);
  hipMemsetAsync(xpre, 0, 32768, stream);

  // --- per-batch attention ---
  for (int b = 0; b < 8; b++) {
    const float* kp_b = kp_out + (size_t)b * 786432;
    // kh = kp @ Wk + bk  [1024,1024]
    mgemm<float, bfr, bfr><<<dim3(8, 8), 256, 0, stream>>>(
        kp_b, WTkv, bk, kh, 768, 1024, 0, 0);
    // vT (interleaved v1|v0 per h) = WTvv @ kp^T  [2048,1024]
    mgemm<bfr, float, bfr><<<dim3(8, 16), 256, 0, stream>>>(
        WTkv + 786432, kp_b, nullptr, vT, 768, 1024, 0, 0);
    score_mfma<<<dim3(8, 4, 16), 256, 0, stream>>>(qh + (size_t)b * 524288, kh, sc);
    smax_ao<<<512, 256, 0, stream>>>(sc, ao_out + (size_t)b * 524288);
    attv2<<<dim3(16, 16), 256, 0, stream>>>(sc, vT, bv, bv0, atpb, ub);
    xpre_kernel<<<dim3(4, 8), 256, 0, stream>>>(q0p + (size_t)b * 524288, ub,
                                                xpre + b * 1024);
    ln_kernel<bfr, bfr, bfr><<<512, 256, 0, stream>>>(
        q0p + (size_t)b * 524288, atpb, nqa, nqb, atl + (size_t)b * 524288);
  }

  // x = LN(bilinear)
  ln_kernel<float, float, float><<<8, 256, 0, stream>>>(xpre, (const float*)nullptr,
                                                        nxa, nxb, x_out);

  // --- FFN, K-split into 2 chunks of 2048, f32 accumulation in ff2a ---
  for (int nc = 0; nc < 2; nc++) {
    transpose_w<<<dim3(64, 32), 256, 0, stream>>>(W1 + nc * 2048, W1Tn,
                                                  1024, 2048, 4096, 0);
    transpose_w<<<dim3(32, 64), 256, 0, stream>>>(W2 + (size_t)nc * 2048 * 1024, W2Tn,
                                                  2048, 1024, 1024, 0);
    mgemm<bfr, bfr, bfr><<<dim3(16, 32), 256, 0, stream>>>(
        atl, W1Tn, b1 + nc * 2048, ff1n, 1024, 2048, 1, 0);
    mgemm<bfr, bfr, float><<<dim3(8, 32), 256, 0, stream>>>(
        ff1n, W2Tn, nc == 0 ? b2 : nullptr, ff2a, 2048, 1024, 0, nc);
  }
  ln_kernel<bfr, float, float><<<4096, 256, 0, stream>>>(atl, ff2a, nsa, nsb, qq_out);
}

// Round 4
// 918.912 us; speedup vs baseline: 2.2790x; 1.3302x over previous
//
#include <hip/hip_runtime.h>

// ---------------------------------------------------------------------------
// FocalAtt (CA mode): B=8, Lq=512, Lk=1024, qd=kd=768, hid=1024, mid=4096,
// H=16, dh=64. Inputs f32, outputs f32. bf16 MFMA GEMMs (16x16x32), fp32 acc.
// R4: mgemm -> 2-phase double-buffered pipeline (issue next-tile stage before
// MFMA, one barrier per K-step) -- targets the 0.25-2 blocks/CU regime where
// the single-buffer barrier drain is fully exposed. kh+vT fused into one
// 192-block launch; the two q-projections fused into one 512-block launch.
// Workspace peak 58,228,736 B (< known-good 58,490,880).
// ---------------------------------------------------------------------------

typedef unsigned short bfr;  // raw bf16 bits
using short8 = __attribute__((ext_vector_type(8))) short;
using f32x4  = __attribute__((ext_vector_type(4))) float;

__device__ __forceinline__ float b2f(bfr s) {
  return __uint_as_float(((unsigned int)s) << 16);
}
__device__ __forceinline__ bfr f2b(float f) {
  unsigned int u = __float_as_uint(f);
  u += 0x7fffu + ((u >> 16) & 1u);  // RNE
  return (bfr)(u >> 16);
}

struct __align__(8) us4 { bfr x, y, z, w; };

__device__ __forceinline__ float4 load4f(const float* p) { return *(const float4*)p; }
__device__ __forceinline__ float4 load4f(const bfr* p) {
  us4 u = *(const us4*)p;
  return make_float4(b2f(u.x), b2f(u.y), b2f(u.z), b2f(u.w));
}
__device__ __forceinline__ void store4(float* p, float a, float b, float c, float d) {
  *(float4*)p = make_float4(a, b, c, d);
}
__device__ __forceinline__ void store4(bfr* p, float a, float b, float c, float d) {
  us4 v; v.x = f2b(a); v.y = f2b(b); v.z = f2b(c); v.w = f2b(d);
  *(us4*)p = v;
}

// async global(bf16 x8, 16B) -> LDS at wave-uniform base + lane*16B
__device__ __forceinline__ void gll16(const bfr* g, bfr* l) {
  __builtin_amdgcn_global_load_lds(
      (const __attribute__((address_space(1))) unsigned int*)g,
      (__attribute__((address_space(3))) unsigned int*)l, 16, 0, 0);
}

// ---------------------------------------------------------------------------
// Positional encoding
// ---------------------------------------------------------------------------
__device__ __forceinline__ float pe_val(int l, int d) {
  float ang = (float)l * expf((float)(d & ~1) * (-9.210340371976184f / 768.0f));
  return (d & 1) ? cosf(ang) : sinf(ang);
}

// k + PE -> f32 kp (d_out; also K/V projection A/B-input). total = 8*1024*768
__global__ __launch_bounds__(256) void posenc_k(const float* __restrict__ in,
                                                float* __restrict__ outf, int total) {
  int idx = blockIdx.x * 256 + threadIdx.x;
  if (idx >= total) return;
  outf[idx] = in[idx] + pe_val((idx / 768) % 1024, idx % 768);
}

// q + PE -> bf16 qp_all [4096,768]
__global__ __launch_bounds__(256) void posenc_q_all(const float* __restrict__ in,
                                                    bfr* __restrict__ out, int total) {
  int idx = blockIdx.x * 256 + threadIdx.x;
  if (idx >= total) return;
  out[idx] = f2b(in[idx] + pe_val((idx / 768) % 512, idx % 768));
}

// ---------------------------------------------------------------------------
// Weight transpose: src f32 [rows, cols] (row stride ld) -> dst bf16 [cols, rows]
// grid (cols/32, rows/32), 256 threads. mode: dst-row remap for interleaved
// v1|v0 stacking. 0: r=c; 1: r=(c>>6)*128+(c&63); 2: r=(c>>6)*128+64+(c&63).
// ---------------------------------------------------------------------------
__global__ __launch_bounds__(256) void transpose_w(const float* __restrict__ src,
                                                   bfr* __restrict__ dst,
                                                   int rows, int cols, int ld,
                                                   int mode) {
  __shared__ float t[32][33];
  const int bc = blockIdx.x * 32, br = blockIdx.y * 32;
  const int tx = threadIdx.x & 31, ty = threadIdx.x >> 5;  // ty 0..7
#pragma unroll
  for (int i = 0; i < 4; i++)
    t[ty + i * 8][tx] = src[(size_t)(br + ty + i * 8) * ld + bc + tx];
  __syncthreads();
#pragma unroll
  for (int i = 0; i < 4; i++) {
    int c = bc + ty + i * 8;
    int r = (mode == 0) ? c : ((c >> 6) * 128 + (c & 63) + (mode == 2 ? 64 : 0));
    dst[(size_t)r * rows + br + tx] = f2b(t[tx][ty + i * 8]);
  }
}

// ---------------------------------------------------------------------------
// MFMA GEMM body: C[M,N] = A[M,K] @ B[K,N] (+bias, relu, accum). B passed as
// BT[N,K]. 128x128 block, 256 thr = 4 waves, each wave 64x64 via 4x4 of
// v_mfma_f32_16x16x32_bf16. BK=32, double-buffered: STAGE(t+1) issued before
// MFMA(t), one barrier per K-step (hides load latency at 1-2 blocks/CU).
// bf16 operands: global_load_lds width 16 into linear LDS [128][32] (m97).
// f32 operands: global->reg early, convert+ds_write after MFMA (T14 split).
// A-frag: lane holds A[m=lane&15][k=(lane>>4)*8+j]; D: row=(lane>>4)*4+r,
// col=lane&15 (measured m89/m91 layouts).
// ---------------------------------------------------------------------------
template <typename TA, typename TB, typename TC>
__device__ __forceinline__ void mgemm_body(const TA* __restrict__ A,
                                           const TB* __restrict__ BT,
                                           const float* __restrict__ bias,
                                           TC* __restrict__ C,
                                           int K, int ldc, int relu, int accum,
                                           int m0, int n0,
                                           bfr* __restrict__ As,   // [2][4096]
                                           bfr* __restrict__ Bs) { // [2][4096]
  const int tid = threadIdx.x;
  const int lane = tid & 63, w = tid >> 6;
  const int wm = (w & 1) * 64, wn = (w >> 1) * 64;
  const int sr = tid >> 1, sc16 = (tid & 1) * 16;               // f32 staging
  const int grow = w * 32 + (lane >> 2), gkc = (lane & 3) * 8;  // gll coords
  const int fr = lane & 15, fc = (lane >> 4) * 8;
  const int NT = K >> 5;
  f32x4 acc[4][4];
#pragma unroll
  for (int i = 0; i < 4; i++)
#pragma unroll
    for (int j = 0; j < 4; j++) acc[i][j] = (f32x4){0.f, 0.f, 0.f, 0.f};
  float4 aF[4], bF[4];

  auto issue = [&](int t, int buf) {
    const int k0 = t << 5;
    if constexpr (sizeof(TA) == 2) {
      const bfr* Ab = (const bfr*)A;
      gll16(Ab + (size_t)(m0 + grow) * K + k0 + gkc, As + buf * 4096 + (w * 32) * 32);
      gll16(Ab + (size_t)(m0 + grow + 16) * K + k0 + gkc,
            As + buf * 4096 + (w * 32 + 16) * 32);
    } else {
      const float* s = (const float*)A + (size_t)(m0 + sr) * K + k0 + sc16;
#pragma unroll
      for (int i = 0; i < 4; i++) aF[i] = *(const float4*)(s + i * 4);
    }
    if constexpr (sizeof(TB) == 2) {
      const bfr* Bb = (const bfr*)BT;
      gll16(Bb + (size_t)(n0 + grow) * K + k0 + gkc, Bs + buf * 4096 + (w * 32) * 32);
      gll16(Bb + (size_t)(n0 + grow + 16) * K + k0 + gkc,
            Bs + buf * 4096 + (w * 32 + 16) * 32);
    } else {
      const float* s = (const float*)BT + (size_t)(n0 + sr) * K + k0 + sc16;
#pragma unroll
      for (int i = 0; i < 4; i++) bF[i] = *(const float4*)(s + i * 4);
    }
  };
  auto commit = [&](int buf) {
    if constexpr (sizeof(TA) == 4) {
      bfr tmp[16];
#pragma unroll
      for (int i = 0; i < 4; i++) {
        tmp[i * 4 + 0] = f2b(aF[i].x); tmp[i * 4 + 1] = f2b(aF[i].y);
        tmp[i * 4 + 2] = f2b(aF[i].z); tmp[i * 4 + 3] = f2b(aF[i].w);
      }
      bfr* d = As + buf * 4096 + sr * 32 + sc16;
      *(short8*)d = *(short8*)&tmp[0];
      *(short8*)(d + 8) = *(short8*)&tmp[8];
    }
    if constexpr (sizeof(TB) == 4) {
      bfr tmp[16];
#pragma unroll
      for (int i = 0; i < 4; i++) {
        tmp[i * 4 + 0] = f2b(bF[i].x); tmp[i * 4 + 1] = f2b(bF[i].y);
        tmp[i * 4 + 2] = f2b(bF[i].z); tmp[i * 4 + 3] = f2b(bF[i].w);
      }
      bfr* d = Bs + buf * 4096 + sr * 32 + sc16;
      *(short8*)d = *(short8*)&tmp[0];
      *(short8*)(d + 8) = *(short8*)&tmp[8];
    }
  };

  issue(0, 0);
  commit(0);
  __syncthreads();
  int cur = 0;
  for (int t = 0; t < NT; ++t) {
    const bool more = (t + 1 < NT);
    if (more) issue(t + 1, cur ^ 1);
    short8 af[4], bf4[4];
#pragma unroll
    for (int i = 0; i < 4; i++)
      af[i] = *(const short8*)(As + cur * 4096 + (wm + i * 16 + fr) * 32 + fc);
#pragma unroll
    for (int i = 0; i < 4; i++)
      bf4[i] = *(const short8*)(Bs + cur * 4096 + (wn + i * 16 + fr) * 32 + fc);
#pragma unroll
    for (int i = 0; i < 4; i++)
#pragma unroll
      for (int j = 0; j < 4; j++)
        acc[i][j] = __builtin_amdgcn_mfma_f32_16x16x32_bf16(af[i], bf4[j], acc[i][j], 0, 0, 0);
    if (more) {
      commit(cur ^ 1);
      __syncthreads();
      cur ^= 1;
    }
  }
  const int col0 = n0 + wn + fr;
  const int row0 = m0 + wm + (lane >> 4) * 4;
  float bsv[4];
#pragma unroll
  for (int j = 0; j < 4; j++) bsv[j] = bias ? bias[col0 + j * 16] : 0.f;
#pragma unroll
  for (int i = 0; i < 4; i++) {
#pragma unroll
    for (int j = 0; j < 4; j++) {
      const int col = col0 + j * 16;
#pragma unroll
      for (int r = 0; r < 4; r++) {
        const int row = row0 + i * 16 + r;
        float v = acc[i][j][r] + bsv[j];
        if (relu) v = fmaxf(v, 0.f);
        size_t idx = (size_t)row * ldc + col;
        if constexpr (sizeof(TC) == 2) {
          C[idx] = f2b(v);
        } else {
          if (accum) C[idx] += v; else C[idx] = v;
        }
      }
    }
  }
}

// standalone wrapper: 2-D grid, XCD-bijective swizzle (m204)
template <typename TA, typename TB, typename TC>
__global__ __launch_bounds__(256) void mgemm(const TA* __restrict__ A,
                                             const TB* __restrict__ BT,
                                             const float* __restrict__ bias,
                                             TC* __restrict__ C,
                                             int K, int ldc, int relu, int accum) {
  __shared__ bfr As[2][4096];
  __shared__ bfr Bs[2][4096];
  const int nwg = gridDim.x * gridDim.y;
  const int bid = blockIdx.y * gridDim.x + blockIdx.x;
  const int q8 = nwg >> 3, r8 = nwg & 7;
  const int xcd = bid & 7, off = bid >> 3;
  const int swz = (xcd < r8 ? xcd * (q8 + 1) : r8 * (q8 + 1) + (xcd - r8) * q8) + off;
  const int n0 = (swz % gridDim.x) * 128, m0 = (swz / gridDim.x) * 128;
  mgemm_body<TA, TB, TC>(A, BT, bias, C, K, ldc, relu, accum, m0, n0,
                         &As[0][0], &Bs[0][0]);
}

// fused per-batch K/V projection: blocks 0..63 -> kh = kp@WkT + bk (8x8),
// blocks 64..191 -> vT = WTvv@kp^T (16x8). 1-D grid 192, XCD swizzle.
__global__ __launch_bounds__(256) void kv_gemm(const float* __restrict__ kp,
                                               const bfr* __restrict__ WkT,
                                               const float* __restrict__ bk,
                                               bfr* __restrict__ kh,
                                               const bfr* __restrict__ WTvv,
                                               bfr* __restrict__ vT) {
  __shared__ bfr As[2][4096];
  __shared__ bfr Bs[2][4096];
  const int swz = (blockIdx.x & 7) * 24 + (blockIdx.x >> 3);  // nwg=192, r8=0
  if (swz < 64) {
    mgemm_body<float, bfr, bfr>(kp, WkT, bk, kh, 768, 1024, 0, 0,
                                (swz >> 3) * 128, (swz & 7) * 128,
                                &As[0][0], &Bs[0][0]);
  } else {
    const int s = swz - 64;
    mgemm_body<bfr, float, bfr>(WTvv, kp, nullptr, vT, 768, 1024, 0, 0,
                                (s >> 3) * 128, (s & 7) * 128,
                                &As[0][0], &Bs[0][0]);
  }
}

// fused q projections: blocks 0..255 -> q0p = q@Wq0T + bq0 (32x8),
// blocks 256..511 -> qh = qp_all@WqT + bq (32x8). 1-D grid 512.
__global__ __launch_bounds__(256) void proj_gemm(const float* __restrict__ q,
                                                 const bfr* __restrict__ Wq0T,
                                                 const float* __restrict__ bq0,
                                                 bfr* __restrict__ q0p,
                                                 const bfr* __restrict__ qp_all,
                                                 const bfr* __restrict__ WqT,
                                                 const float* __restrict__ bq,
                                                 bfr* __restrict__ qh) {
  __shared__ bfr As[2][4096];
  __shared__ bfr Bs[2][4096];
  const int swz = (blockIdx.x & 7) * 64 + (blockIdx.x >> 3);  // nwg=512, r8=0
  if (swz < 256) {
    mgemm_body<float, bfr, bfr>(q, Wq0T, bq0, q0p, 768, 1024, 0, 0,
                                (swz >> 3) * 128, (swz & 7) * 128,
                                &As[0][0], &Bs[0][0]);
  } else {
    const int s = swz - 256;
    mgemm_body<bfr, bfr, bfr>(qp_all, WqT, bq, qh, 768, 1024, 0, 0,
                              (s >> 3) * 128, (s & 7) * 128,
                              &As[0][0], &Bs[0][0]);
  }
}

// ---------------------------------------------------------------------------
// MFMA scores (one batch): sc[h,q,k] = dot_64(qh[q,h*64+:], kh[k,h*64+:]) / 8
// 128x128 tile, K=64 (two 32-steps, staged once). grid (8 kb, 4 qb, 16 h).
// ---------------------------------------------------------------------------
__global__ __launch_bounds__(256) void score_mfma(const bfr* __restrict__ qh,
                                                  const bfr* __restrict__ kh,
                                                  bfr* __restrict__ sc) {
  __shared__ __align__(16) bfr Qs[128][72];  // stride 144 B: 2-way max, free
  __shared__ __align__(16) bfr Ks[128][72];
  const int h = blockIdx.z, q0 = blockIdx.y * 128, k0 = blockIdx.x * 128;
  const int tid = threadIdx.x, lane = tid & 63;
  const int wm = ((tid >> 6) & 1) * 64, wn = (tid >> 7) * 64;
  const int fr = lane & 15, fc = (lane >> 4) * 8;
  {
    const int r = tid >> 1, c = (tid & 1) * 32;
    const bfr* qsrc = qh + (size_t)(q0 + r) * 1024 + h * 64 + c;
    const bfr* ksrc = kh + (size_t)(k0 + r) * 1024 + h * 64 + c;
#pragma unroll
    for (int i = 0; i < 4; i++) {
      *(short8*)&Qs[r][c + i * 8] = *(const short8*)(qsrc + i * 8);
      *(short8*)&Ks[r][c + i * 8] = *(const short8*)(ksrc + i * 8);
    }
  }
  __syncthreads();
  f32x4 acc[4][4];
#pragma unroll
  for (int i = 0; i < 4; i++)
#pragma unroll
    for (int j = 0; j < 4; j++) acc[i][j] = (f32x4){0.f, 0.f, 0.f, 0.f};
#pragma unroll
  for (int ks = 0; ks < 2; ks++) {
    short8 af[4], bf[4];
#pragma unroll
    for (int t = 0; t < 4; t++) af[t] = *(const short8*)&Qs[wm + t * 16 + fr][ks * 32 + fc];
#pragma unroll
    for (int t = 0; t < 4; t++) bf[t] = *(const short8*)&Ks[wn + t * 16 + fr][ks * 32 + fc];
#pragma unroll
    for (int i = 0; i < 4; i++)
#pragma unroll
      for (int j = 0; j < 4; j++)
        acc[i][j] = __builtin_amdgcn_mfma_f32_16x16x32_bf16(af[i], bf[j], acc[i][j], 0, 0, 0);
  }
  const int col0 = k0 + wn + fr;
  const int row0 = q0 + wm + (lane >> 4) * 4;
#pragma unroll
  for (int i = 0; i < 4; i++)
#pragma unroll
    for (int j = 0; j < 4; j++)
#pragma unroll
      for (int r = 0; r < 4; r++)
        sc[((size_t)h * 512 + row0 + i * 16 + r) * 1024 + col0 + j * 16] =
            f2b(acc[i][j][r] * 0.125f);
}

// ---------------------------------------------------------------------------
// Fused attout + softmax (one batch): block per q (512 blocks). 4 waves x 4 h
// each. Per (h,q)-row of 1024: relu-sum partial (pre-softmax) + in-place
// softmax, wave-level shfl reductions only. Cross-wave relu-sum via LDS ->
// ao[q,k] = sum_h relu(sc)/16 (f32).
// ---------------------------------------------------------------------------
__global__ __launch_bounds__(256) void smax_ao(bfr* __restrict__ sc,
                                               float* __restrict__ ao) {
  __shared__ float part[4][1024];
  const int q = blockIdx.x;
  const int tid = threadIdx.x, lane = tid & 63, w = tid >> 6;
  float aos[16];
#pragma unroll
  for (int i = 0; i < 16; i++) aos[i] = 0.f;
#pragma unroll
  for (int i = 0; i < 4; i++) {
    const int h = w * 4 + i;
    bfr* row = sc + ((size_t)h * 512 + q) * 1024 + lane * 16;
    us4 raw[4];
    float v[16];
#pragma unroll
    for (int j = 0; j < 4; j++) raw[j] = ((const us4*)row)[j];
#pragma unroll
    for (int j = 0; j < 4; j++) {
      v[j * 4 + 0] = b2f(raw[j].x); v[j * 4 + 1] = b2f(raw[j].y);
      v[j * 4 + 2] = b2f(raw[j].z); v[j * 4 + 3] = b2f(raw[j].w);
    }
    float m = v[0];
#pragma unroll
    for (int j = 1; j < 16; j++) m = fmaxf(m, v[j]);
#pragma unroll
    for (int j = 0; j < 16; j++) aos[j] += fmaxf(v[j], 0.f);
    for (int o = 32; o; o >>= 1) m = fmaxf(m, __shfl_xor(m, o, 64));
    float s = 0.f;
#pragma unroll
    for (int j = 0; j < 16; j++) { v[j] = expf(v[j] - m); s += v[j]; }
    for (int o = 32; o; o >>= 1) s += __shfl_xor(s, o, 64);
    const float inv = 1.0f / s;
#pragma unroll
    for (int j = 0; j < 4; j++) {
      raw[j].x = f2b(v[j * 4 + 0] * inv); raw[j].y = f2b(v[j * 4 + 1] * inv);
      raw[j].z = f2b(v[j * 4 + 2] * inv); raw[j].w = f2b(v[j * 4 + 3] * inv);
      ((us4*)row)[j] = raw[j];
    }
  }
#pragma unroll
  for (int j = 0; j < 4; j++)
    *(float4*)&part[w][lane * 16 + j * 4] =
        make_float4(aos[j * 4], aos[j * 4 + 1], aos[j * 4 + 2], aos[j * 4 + 3]);
  __syncthreads();
  const int k4 = tid * 4;
  float4 a0 = *(const float4*)&part[0][k4];
  float4 a1 = *(const float4*)&part[1][k4];
  float4 a2 = *(const float4*)&part[2][k4];
  float4 a3 = *(const float4*)&part[3][k4];
  store4(ao + (size_t)q * 1024 + k4,
         (a0.x + a1.x + a2.x + a3.x) * 0.0625f, (a0.y + a1.y + a2.y + a3.y) * 0.0625f,
         (a0.z + a1.z + a2.z + a3.z) * 0.0625f, (a0.w + a1.w + a2.w + a3.w) * 0.0625f);
}

// ---------------------------------------------------------------------------
// MFMA att@V (one batch): vT is [h][128 d'][1024 k] with d'<64 = v1 rows,
// d'>=64 = v0 rows (interleaved at weight-transpose time). Output tile
// 32q x 128d' per block, grid (16 qb, 16 h), 4 waves (2 row x 2 col halves),
// K-step 64: 8 MFMA per wave per barrier pair. Bias exact (softmax rows sum
// to 1). Waves 0-1 -> atp (+bv), waves 2-3 -> u (+bv0): wave-uniform.
// ---------------------------------------------------------------------------
__global__ __launch_bounds__(256) void attv2(const bfr* __restrict__ att,
                                             const bfr* __restrict__ vT,
                                             const float* __restrict__ bv,
                                             const float* __restrict__ bv0,
                                             bfr* __restrict__ atp,
                                             bfr* __restrict__ u) {
  __shared__ __align__(16) bfr As[32][72];
  __shared__ __align__(16) bfr Bs[128][72];
  const int h = blockIdx.y, q0 = blockIdx.x * 32;
  const int tid = threadIdx.x, lane = tid & 63, w = tid >> 6;
  const int fr = lane & 15, fc = (lane >> 4) * 8;
  const int wm = (w & 1) * 16, wn = (w >> 1) * 64;
  const bfr* attb = att + ((size_t)h * 512 + q0) * 1024;
  const bfr* vb = vT + (size_t)h * 128 * 1024;
  const int ar = tid >> 3, ac = (tid & 7) * 8;
  const int br = tid >> 2, bc = (tid & 3) * 16;
  f32x4 acc[4];
#pragma unroll
  for (int t = 0; t < 4; t++) acc[t] = (f32x4){0.f, 0.f, 0.f, 0.f};
  for (int k0 = 0; k0 < 1024; k0 += 64) {
    *(short8*)&As[ar][ac] = *(const short8*)(attb + (size_t)ar * 1024 + k0 + ac);
    *(short8*)&Bs[br][bc] = *(const short8*)(vb + (size_t)br * 1024 + k0 + bc);
    *(short8*)&Bs[br][bc + 8] = *(const short8*)(vb + (size_t)br * 1024 + k0 + bc + 8);
    *(short8*)&Bs[br + 64][bc] = *(const short8*)(vb + (size_t)(br + 64) * 1024 + k0 + bc);
    *(short8*)&Bs[br + 64][bc + 8] =
        *(const short8*)(vb + (size_t)(br + 64) * 1024 + k0 + bc + 8);
    __syncthreads();
#pragma unroll
    for (int ks = 0; ks < 2; ks++) {
      short8 af = *(const short8*)&As[wm + fr][ks * 32 + fc];
#pragma unroll
      for (int t = 0; t < 4; t++) {
        short8 bf = *(const short8*)&Bs[wn + t * 16 + fr][ks * 32 + fc];
        acc[t] = __builtin_amdgcn_mfma_f32_16x16x32_bf16(af, bf, acc[t], 0, 0, 0);
      }
    }
    __syncthreads();
  }
  const int row0 = q0 + wm + (lane >> 4) * 4;
  bfr* o = (wn == 0) ? atp : u;
  const float* bias = (wn == 0) ? bv : bv0;
#pragma unroll
  for (int t = 0; t < 4; t++) {
    const int cm = t * 16 + fr;  // 0..63 within the selected half
    const float bb = bias[h * 64 + cm];
#pragma unroll
    for (int r = 0; r < 4; r++)
      o[(size_t)(row0 + r) * 1024 + h * 64 + cm] = f2b(acc[t][r] + bb);
  }
}

// xpre_b[c] += sum over 64 rows of q0p_b[v,c]*u_b[v,c] (per batch), grid (4,8)
__global__ __launch_bounds__(256) void xpre_kernel(const bfr* __restrict__ q0p,
                                                   const bfr* __restrict__ u,
                                                   float* __restrict__ xpre) {
  const int c = blockIdx.x * 256 + threadIdx.x;
  const int r0 = blockIdx.y * 64;
  const bfr* qp = q0p + (size_t)r0 * 1024 + c;
  const bfr* up = u + (size_t)r0 * 1024 + c;
  float s = 0.f;
#pragma unroll 8
  for (int r = 0; r < 64; r++)
    s = fmaf(b2f(qp[(size_t)r * 1024]), b2f(up[(size_t)r * 1024]), s);
  atomicAdd(&xpre[c], s);
}

// torch_ln over rows of 1024: a*(x-mean)/(sqrt(var_unbiased)+1e-6)+b, X (+Y)
template <typename TX, typename TY, typename OT>
__global__ __launch_bounds__(256) void ln_kernel(const TX* __restrict__ X,
                                                 const TY* __restrict__ Y,
                                                 const float* __restrict__ ga,
                                                 const float* __restrict__ be,
                                                 OT* __restrict__ out) {
  __shared__ float sm[4];
  const size_t row = blockIdx.x;
  const int tid = threadIdx.x;
  float4 v = load4f(X + row * 1024 + tid * 4);
  if (Y) {
    float4 w = load4f(Y + row * 1024 + tid * 4);
    v.x += w.x; v.y += w.y; v.z += w.z; v.w += w.w;
  }
  float s = v.x + v.y + v.z + v.w;
  for (int o = 32; o; o >>= 1) s += __shfl_down(s, o, 64);
  if ((tid & 63) == 0) sm[tid >> 6] = s;
  __syncthreads();
  s = sm[0] + sm[1] + sm[2] + sm[3];
  float mean = s * (1.0f / 1024.0f);
  float d0 = v.x - mean, d1 = v.y - mean, d2 = v.z - mean, d3 = v.w - mean;
  float q = d0 * d0 + d1 * d1 + d2 * d2 + d3 * d3;
  __syncthreads();
  for (int o = 32; o; o >>= 1) q += __shfl_down(q, o, 64);
  if ((tid & 63) == 0) sm[tid >> 6] = q;
  __syncthreads();
  q = sm[0] + sm[1] + sm[2] + sm[3];
  float rs = 1.0f / (sqrtf(q * (1.0f / 1023.0f)) + 1e-6f);
  float4 g = *(const float4*)(ga + tid * 4);
  float4 bb = *(const float4*)(be + tid * 4);
  store4(out + row * 1024 + tid * 4,
         g.x * d0 * rs + bb.x, g.y * d1 * rs + bb.y,
         g.z * d2 * rs + bb.z, g.w * d3 * rs + bb.w);
}

// ---------------------------------------------------------------------------
extern "C" void kernel_launch(void* const* d_in, const int* in_sizes, int n_in,
                              void* d_out, int out_size, void* d_ws, size_t ws_size,
                              hipStream_t stream) {
  (void)in_sizes; (void)n_in; (void)out_size; (void)ws_size;
  const float* q   = (const float*)d_in[0];
  const float* k   = (const float*)d_in[1];
  const float* Wq  = (const float*)d_in[2];
  const float* bq  = (const float*)d_in[3];
  const float* Wk  = (const float*)d_in[4];
  const float* bk  = (const float*)d_in[5];
  const float* Wv  = (const float*)d_in[6];
  const float* bv  = (const float*)d_in[7];
  const float* Wv0 = (const float*)d_in[8];
  const float* bv0 = (const float*)d_in[9];
  const float* Wq0 = (const float*)d_in[10];
  const float* bq0 = (const float*)d_in[11];
  const float* nqa = (const float*)d_in[12];
  const float* nqb = (const float*)d_in[13];
  const float* nxa = (const float*)d_in[14];
  const float* nxb = (const float*)d_in[15];
  const float* W1  = (const float*)d_in[16];
  const float* b1  = (const float*)d_in[17];
  const float* W2  = (const float*)d_in[18];
  const float* b2  = (const float*)d_in[19];
  const float* nsa = (const float*)d_in[20];
  const float* nsb = (const float*)d_in[21];

  float* out = (float*)d_out;
  float* x_out  = out;                       // 8,192
  float* qq_out = out + 8192;                // 4,194,304
  float* kp_out = out + 4202496;             // 6,291,456
  float* ao_out = out + 10493952;            // 4,194,304

  char* base = (char*)d_ws;
  // persistent (attention phase)
  bfr* q0p   = (bfr*)(base + 0);            // 8,388,608  [4096,1024]
  bfr* qh    = (bfr*)(base + 8388608);      // 8,388,608  [4096,1024]
  bfr* atl   = (bfr*)(base + 16777216);     // 8,388,608  [4096,1024]
  bfr* WqT   = (bfr*)(base + 25165824);     // 1,572,864  [1024,768]
  bfr* Wq0T  = (bfr*)(base + 26738688);     // 1,572,864
  bfr* WTkv  = (bfr*)(base + 28311552);     // 4,718,592  [WkT 1024; vv-interleaved 2048][768]
  float* xpre = (float*)(base + 33030144);  //    32,768  [8,1024]
  char* S = base + 33062912;                // scratch region (25,165,824 B)
  // attention-loop overlay
  bfr* sc    = (bfr*)(S + 0);               // 16,777,216 [16,512,1024]
  bfr* vT    = (bfr*)(S + 16777216);        //  4,194,304 [16][128][1024] v1|v0
  bfr* atpb  = (bfr*)(S + 20971520);        //  1,048,576 [512,1024]
  bfr* ub    = (bfr*)(S + 22020096);        //  1,048,576
  bfr* kh    = (bfr*)(S + 23068672);        //  2,097,152 [1024,1024]
  // pre-loop overlay (dead before attention buffers first written)
  bfr* qp_all = (bfr*)(S + 0);              //  6,291,456 [4096,768]
  // FFN-phase overlay (attention buffers dead; q0p/qh dead)
  bfr* W1Tn  = (bfr*)(S + 0);               //  4,194,304 [2048,1024]
  bfr* W2Tn  = (bfr*)(S + 4194304);         //  4,194,304 [1024,2048]
  bfr* ff1n  = (bfr*)(S + 8388608);         // 16,777,216 [4096,2048]
  float* ff2a = (float*)(base + 0);         // 16,777,216 [4096,1024] f32 (over q0p/qh)
  // peak footprint: 33,062,912 + 25,165,824 = 58,228,736 B

  // --- setup ---
  posenc_k<<<24576, 256, 0, stream>>>(k, kp_out, 6291456);
  posenc_q_all<<<12288, 256, 0, stream>>>(q, qp_all, 3145728);
  transpose_w<<<dim3(32, 24), 256, 0, stream>>>(Wq, WqT, 768, 1024, 1024, 0);
  transpose_w<<<dim3(32, 24), 256, 0, stream>>>(Wq0, Wq0T, 768, 1024, 1024, 0);
  transpose_w<<<dim3(32, 24), 256, 0, stream>>>(Wk, WTkv, 768, 1024, 1024, 0);
  transpose_w<<<dim3(32, 24), 256, 0, stream>>>(Wv, WTkv + 786432, 768, 1024, 1024, 1);
  transpose_w<<<dim3(32, 24), 256, 0, stream>>>(Wv0, WTkv + 786432, 768, 1024, 1024, 2);

  // full-batch projections (fused, MFMA)
  proj_gemm<<<512, 256, 0, stream>>>(q, Wq0T, bq0, q0p, qp_all, WqT, bq, qh);
  hipMemsetAsync(xpre, 0, 32768, stream);

  // --- per-batch attention ---
  for (int b = 0; b < 8; b++) {
    const float* kp_b = kp_out + (size_t)b * 786432;
    kv_gemm<<<192, 256, 0, stream>>>(kp_b, WTkv, bk, kh, WTkv + 786432, vT);
    score_mfma<<<dim3(8, 4, 16), 256, 0, stream>>>(qh + (size_t)b * 524288, kh, sc);
    smax_ao<<<512, 256, 0, stream>>>(sc, ao_out + (size_t)b * 524288);
    attv2<<<dim3(16, 16), 256, 0, stream>>>(sc, vT, bv, bv0, atpb, ub);
    xpre_kernel<<<dim3(4, 8), 256, 0, stream>>>(q0p + (size_t)b * 524288, ub,
                                                xpre + b * 1024);
    ln_kernel<bfr, bfr, bfr><<<512, 256, 0, stream>>>(
        q0p + (size_t)b * 524288, atpb, nqa, nqb, atl + (size_t)b * 524288);
  }

  // x = LN(bilinear)
  ln_kernel<float, float, float><<<8, 256, 0, stream>>>(xpre, (const float*)nullptr,
                                                        nxa, nxb, x_out);

  // --- FFN, K-split into 2 chunks of 2048, f32 accumulation in ff2a ---
  for (int nc = 0; nc < 2; nc++) {
    transpose_w<<<dim3(64, 32), 256, 0, stream>>>(W1 + nc * 2048, W1Tn,
                                                  1024, 2048, 4096, 0);
    transpose_w<<<dim3(32, 64), 256, 0, stream>>>(W2 + (size_t)nc * 2048 * 1024, W2Tn,
                                                  2048, 1024, 1024, 0);
    mgemm<bfr, bfr, bfr><<<dim3(16, 32), 256, 0, stream>>>(
        atl, W1Tn, b1 + nc * 2048, ff1n, 1024, 2048, 1, 0);
    mgemm<bfr, bfr, float><<<dim3(8, 32), 256, 0, stream>>>(
        ff1n, W2Tn, nc == 0 ? b2 : nullptr, ff2a, 2048, 1024, 0, nc);
  }
  ln_kernel<bfr, float, float><<<4096, 256, 0, stream>>>(atl, ff2a, nsa, nsb, qq_out);
}

// Round 5
// 846.138 us; speedup vs baseline: 2.4750x; 1.0860x over previous
//
#include <hip/hip_runtime.h>

// ---------------------------------------------------------------------------
// FocalAtt (CA mode): B=8, Lq=512, Lk=1024, qd=kd=768, hid=1024, mid=4096,
// H=16, dh=64. Inputs f32, outputs f32. bf16 MFMA GEMMs (16x16x32), fp32 acc.
// R5: all GEMM operands pre-converted to bf16 (kp_b16 parked in the unused
// qq_out region until FFN; q_b16 in pre-loop scratch) -> every mgemm_body is
// pure global_load_lds staging. BK 32 -> 64: 32 MFMA per barrier, half the
// barriers, 2x latency-hiding compute per phase. LDS 64 KB/block (2 blk/CU,
// matches grid-limited residency).
// Workspace peak 58,228,736 B (< known-good 58,490,880).
// ---------------------------------------------------------------------------

typedef unsigned short bfr;  // raw bf16 bits
using short8 = __attribute__((ext_vector_type(8))) short;
using f32x4  = __attribute__((ext_vector_type(4))) float;

__device__ __forceinline__ float b2f(bfr s) {
  return __uint_as_float(((unsigned int)s) << 16);
}
__device__ __forceinline__ bfr f2b(float f) {
  unsigned int u = __float_as_uint(f);
  u += 0x7fffu + ((u >> 16) & 1u);  // RNE
  return (bfr)(u >> 16);
}

struct __align__(8) us4 { bfr x, y, z, w; };

__device__ __forceinline__ float4 load4f(const float* p) { return *(const float4*)p; }
__device__ __forceinline__ float4 load4f(const bfr* p) {
  us4 u = *(const us4*)p;
  return make_float4(b2f(u.x), b2f(u.y), b2f(u.z), b2f(u.w));
}
__device__ __forceinline__ void store4(float* p, float a, float b, float c, float d) {
  *(float4*)p = make_float4(a, b, c, d);
}
__device__ __forceinline__ void store4(bfr* p, float a, float b, float c, float d) {
  us4 v; v.x = f2b(a); v.y = f2b(b); v.z = f2b(c); v.w = f2b(d);
  *(us4*)p = v;
}

// async global(bf16 x8, 16B) -> LDS at wave-uniform base + lane*16B
__device__ __forceinline__ void gll16(const bfr* g, bfr* l) {
  __builtin_amdgcn_global_load_lds(
      (const __attribute__((address_space(1))) unsigned int*)g,
      (__attribute__((address_space(3))) unsigned int*)l, 16, 0, 0);
}

// ---------------------------------------------------------------------------
// Positional encoding
// ---------------------------------------------------------------------------
__device__ __forceinline__ float pe_val(int l, int d) {
  float ang = (float)l * expf((float)(d & ~1) * (-9.210340371976184f / 768.0f));
  return (d & 1) ? cosf(ang) : sinf(ang);
}

// k + PE -> f32 kp (output) AND bf16 copy (GEMM operand). total = 8*1024*768
__global__ __launch_bounds__(256) void posenc_k(const float* __restrict__ in,
                                                float* __restrict__ outf,
                                                bfr* __restrict__ outb, int total) {
  int idx = blockIdx.x * 256 + threadIdx.x;
  if (idx >= total) return;
  float v = in[idx] + pe_val((idx / 768) % 1024, idx % 768);
  outf[idx] = v;
  outb[idx] = f2b(v);
}

// q + PE -> bf16 qp_all [4096,768]; plain q -> bf16 q_b16
__global__ __launch_bounds__(256) void posenc_q_all(const float* __restrict__ in,
                                                    bfr* __restrict__ out,
                                                    bfr* __restrict__ outraw,
                                                    int total) {
  int idx = blockIdx.x * 256 + threadIdx.x;
  if (idx >= total) return;
  float v = in[idx];
  out[idx] = f2b(v + pe_val((idx / 768) % 512, idx % 768));
  outraw[idx] = f2b(v);
}

// ---------------------------------------------------------------------------
// Weight transpose: src f32 [rows, cols] (row stride ld) -> dst bf16 [cols, rows]
// grid (cols/32, rows/32), 256 threads. mode: dst-row remap for interleaved
// v1|v0 stacking. 0: r=c; 1: r=(c>>6)*128+(c&63); 2: r=(c>>6)*128+64+(c&63).
// ---------------------------------------------------------------------------
__global__ __launch_bounds__(256) void transpose_w(const float* __restrict__ src,
                                                   bfr* __restrict__ dst,
                                                   int rows, int cols, int ld,
                                                   int mode) {
  __shared__ float t[32][33];
  const int bc = blockIdx.x * 32, br = blockIdx.y * 32;
  const int tx = threadIdx.x & 31, ty = threadIdx.x >> 5;  // ty 0..7
#pragma unroll
  for (int i = 0; i < 4; i++)
    t[ty + i * 8][tx] = src[(size_t)(br + ty + i * 8) * ld + bc + tx];
  __syncthreads();
#pragma unroll
  for (int i = 0; i < 4; i++) {
    int c = bc + ty + i * 8;
    int r = (mode == 0) ? c : ((c >> 6) * 128 + (c & 63) + (mode == 2 ? 64 : 0));
    dst[(size_t)r * rows + br + tx] = f2b(t[tx][ty + i * 8]);
  }
}

// ---------------------------------------------------------------------------
// MFMA GEMM body (all-bf16): C[M,N] = A[M,K] @ B[K,N] (+bias, relu, accum).
// B passed as BT[N,K]. 128x128 block, 256 thr = 4 waves, each wave 64x64 via
// 4x4 of v_mfma_f32_16x16x32_bf16. BK=64, double-buffered: STAGE(t+1) issued
// before MFMA(t), one barrier per K-step. All staging via global_load_lds
// width 16 into linear LDS [128][64] (m97 recipe). K % 64 == 0.
// A-frag: lane holds A[m=lane&15][k=(lane>>4)*8+j]; D: row=(lane>>4)*4+r,
// col=lane&15 (measured m89/m91 layouts).
// ---------------------------------------------------------------------------
template <typename TC>
__device__ __forceinline__ void mgemm_body(const bfr* __restrict__ A,
                                           const bfr* __restrict__ BT,
                                           const float* __restrict__ bias,
                                           TC* __restrict__ C,
                                           int K, int ldc, int relu, int accum,
                                           int m0, int n0,
                                           bfr* __restrict__ As,   // [2][8192]
                                           bfr* __restrict__ Bs) { // [2][8192]
  const int tid = threadIdx.x;
  const int lane = tid & 63, w = tid >> 6;
  const int wm = (w & 1) * 64, wn = (w >> 1) * 64;
  const int grow = w * 32 + (lane >> 3);  // 8 lanes/row (64 cols x 2B = 128 B)
  const int gkc = (lane & 7) * 8;
  const int fr = lane & 15, fc = (lane >> 4) * 8;
  const int NT = K >> 6;
  f32x4 acc[4][4];
#pragma unroll
  for (int i = 0; i < 4; i++)
#pragma unroll
    for (int j = 0; j < 4; j++) acc[i][j] = (f32x4){0.f, 0.f, 0.f, 0.f};

  auto issue = [&](int t, int buf) {
    const int k0 = t << 6;
    const bfr* Ag = A + (size_t)(m0 + grow) * K + k0 + gkc;
    const bfr* Bg = BT + (size_t)(n0 + grow) * K + k0 + gkc;
#pragma unroll
    for (int i = 0; i < 4; i++)
      gll16(Ag + (size_t)(i * 8) * K, As + buf * 8192 + (w * 32 + i * 8) * 64);
#pragma unroll
    for (int i = 0; i < 4; i++)
      gll16(Bg + (size_t)(i * 8) * K, Bs + buf * 8192 + (w * 32 + i * 8) * 64);
  };

  issue(0, 0);
  __syncthreads();
  int cur = 0;
  for (int t = 0; t < NT; ++t) {
    const bool more = (t + 1 < NT);
    if (more) issue(t + 1, cur ^ 1);
#pragma unroll
    for (int ks = 0; ks < 2; ks++) {
      short8 af[4], bf4[4];
#pragma unroll
      for (int i = 0; i < 4; i++)
        af[i] = *(const short8*)(As + cur * 8192 + (wm + i * 16 + fr) * 64 + ks * 32 + fc);
#pragma unroll
      for (int i = 0; i < 4; i++)
        bf4[i] = *(const short8*)(Bs + cur * 8192 + (wn + i * 16 + fr) * 64 + ks * 32 + fc);
#pragma unroll
      for (int i = 0; i < 4; i++)
#pragma unroll
        for (int j = 0; j < 4; j++)
          acc[i][j] = __builtin_amdgcn_mfma_f32_16x16x32_bf16(af[i], bf4[j], acc[i][j], 0, 0, 0);
    }
    if (more) {
      __syncthreads();
      cur ^= 1;
    }
  }
  const int col0 = n0 + wn + fr;
  const int row0 = m0 + wm + (lane >> 4) * 4;
  float bsv[4];
#pragma unroll
  for (int j = 0; j < 4; j++) bsv[j] = bias ? bias[col0 + j * 16] : 0.f;
#pragma unroll
  for (int i = 0; i < 4; i++) {
#pragma unroll
    for (int j = 0; j < 4; j++) {
      const int col = col0 + j * 16;
#pragma unroll
      for (int r = 0; r < 4; r++) {
        const int row = row0 + i * 16 + r;
        float v = acc[i][j][r] + bsv[j];
        if (relu) v = fmaxf(v, 0.f);
        size_t idx = (size_t)row * ldc + col;
        if constexpr (sizeof(TC) == 2) {
          C[idx] = f2b(v);
        } else {
          if (accum) C[idx] += v; else C[idx] = v;
        }
      }
    }
  }
}

// standalone wrapper: 2-D grid, XCD-bijective swizzle (m204)
template <typename TC>
__global__ __launch_bounds__(256) void mgemm(const bfr* __restrict__ A,
                                             const bfr* __restrict__ BT,
                                             const float* __restrict__ bias,
                                             TC* __restrict__ C,
                                             int K, int ldc, int relu, int accum) {
  __shared__ bfr As[2][8192];
  __shared__ bfr Bs[2][8192];
  const int nwg = gridDim.x * gridDim.y;
  const int bid = blockIdx.y * gridDim.x + blockIdx.x;
  const int q8 = nwg >> 3, r8 = nwg & 7;
  const int xcd = bid & 7, off = bid >> 3;
  const int swz = (xcd < r8 ? xcd * (q8 + 1) : r8 * (q8 + 1) + (xcd - r8) * q8) + off;
  const int n0 = (swz % gridDim.x) * 128, m0 = (swz / gridDim.x) * 128;
  mgemm_body<TC>(A, BT, bias, C, K, ldc, relu, accum, m0, n0,
                 &As[0][0], &Bs[0][0]);
}

// fused per-batch K/V projection: blocks 0..63 -> kh = kp@WkT + bk (8x8),
// blocks 64..191 -> vT = WTvv@kp^T (16x8). 1-D grid 192, XCD swizzle.
__global__ __launch_bounds__(256) void kv_gemm(const bfr* __restrict__ kp16,
                                               const bfr* __restrict__ WkT,
                                               const float* __restrict__ bk,
                                               bfr* __restrict__ kh,
                                               const bfr* __restrict__ WTvv,
                                               bfr* __restrict__ vT) {
  __shared__ bfr As[2][8192];
  __shared__ bfr Bs[2][8192];
  const int swz = (blockIdx.x & 7) * 24 + (blockIdx.x >> 3);  // nwg=192, r8=0
  if (swz < 64) {
    mgemm_body<bfr>(kp16, WkT, bk, kh, 768, 1024, 0, 0,
                    (swz >> 3) * 128, (swz & 7) * 128, &As[0][0], &Bs[0][0]);
  } else {
    const int s = swz - 64;
    mgemm_body<bfr>(WTvv, kp16, nullptr, vT, 768, 1024, 0, 0,
                    (s >> 3) * 128, (s & 7) * 128, &As[0][0], &Bs[0][0]);
  }
}

// fused q projections: blocks 0..255 -> q0p = q_b16@Wq0T + bq0 (32x8),
// blocks 256..511 -> qh = qp_all@WqT + bq (32x8). 1-D grid 512.
__global__ __launch_bounds__(256) void proj_gemm(const bfr* __restrict__ q16,
                                                 const bfr* __restrict__ Wq0T,
                                                 const float* __restrict__ bq0,
                                                 bfr* __restrict__ q0p,
                                                 const bfr* __restrict__ qp_all,
                                                 const bfr* __restrict__ WqT,
                                                 const float* __restrict__ bq,
                                                 bfr* __restrict__ qh) {
  __shared__ bfr As[2][8192];
  __shared__ bfr Bs[2][8192];
  const int swz = (blockIdx.x & 7) * 64 + (blockIdx.x >> 3);  // nwg=512, r8=0
  if (swz < 256) {
    mgemm_body<bfr>(q16, Wq0T, bq0, q0p, 768, 1024, 0, 0,
                    (swz >> 3) * 128, (swz & 7) * 128, &As[0][0], &Bs[0][0]);
  } else {
    const int s = swz - 256;
    mgemm_body<bfr>(qp_all, WqT, bq, qh, 768, 1024, 0, 0,
                    (s >> 3) * 128, (s & 7) * 128, &As[0][0], &Bs[0][0]);
  }
}

// ---------------------------------------------------------------------------
// MFMA scores (one batch): sc[h,q,k] = dot_64(qh[q,h*64+:], kh[k,h*64+:]) / 8
// 128x128 tile, K=64 (two 32-steps, staged once). grid (8 kb, 4 qb, 16 h).
// ---------------------------------------------------------------------------
__global__ __launch_bounds__(256) void score_mfma(const bfr* __restrict__ qh,
                                                  const bfr* __restrict__ kh,
                                                  bfr* __restrict__ sc) {
  __shared__ __align__(16) bfr Qs[128][72];  // stride 144 B: 2-way max, free
  __shared__ __align__(16) bfr Ks[128][72];
  const int h = blockIdx.z, q0 = blockIdx.y * 128, k0 = blockIdx.x * 128;
  const int tid = threadIdx.x, lane = tid & 63;
  const int wm = ((tid >> 6) & 1) * 64, wn = (tid >> 7) * 64;
  const int fr = lane & 15, fc = (lane >> 4) * 8;
  {
    const int r = tid >> 1, c = (tid & 1) * 32;
    const bfr* qsrc = qh + (size_t)(q0 + r) * 1024 + h * 64 + c;
    const bfr* ksrc = kh + (size_t)(k0 + r) * 1024 + h * 64 + c;
#pragma unroll
    for (int i = 0; i < 4; i++) {
      *(short8*)&Qs[r][c + i * 8] = *(const short8*)(qsrc + i * 8);
      *(short8*)&Ks[r][c + i * 8] = *(const short8*)(ksrc + i * 8);
    }
  }
  __syncthreads();
  f32x4 acc[4][4];
#pragma unroll
  for (int i = 0; i < 4; i++)
#pragma unroll
    for (int j = 0; j < 4; j++) acc[i][j] = (f32x4){0.f, 0.f, 0.f, 0.f};
#pragma unroll
  for (int ks = 0; ks < 2; ks++) {
    short8 af[4], bf[4];
#pragma unroll
    for (int t = 0; t < 4; t++) af[t] = *(const short8*)&Qs[wm + t * 16 + fr][ks * 32 + fc];
#pragma unroll
    for (int t = 0; t < 4; t++) bf[t] = *(const short8*)&Ks[wn + t * 16 + fr][ks * 32 + fc];
#pragma unroll
    for (int i = 0; i < 4; i++)
#pragma unroll
      for (int j = 0; j < 4; j++)
        acc[i][j] = __builtin_amdgcn_mfma_f32_16x16x32_bf16(af[i], bf[j], acc[i][j], 0, 0, 0);
  }
  const int col0 = k0 + wn + fr;
  const int row0 = q0 + wm + (lane >> 4) * 4;
#pragma unroll
  for (int i = 0; i < 4; i++)
#pragma unroll
    for (int j = 0; j < 4; j++)
#pragma unroll
      for (int r = 0; r < 4; r++)
        sc[((size_t)h * 512 + row0 + i * 16 + r) * 1024 + col0 + j * 16] =
            f2b(acc[i][j][r] * 0.125f);
}

// ---------------------------------------------------------------------------
// Fused attout + softmax (one batch): block per q (512 blocks). 4 waves x 4 h
// each. Per (h,q)-row of 1024: relu-sum partial (pre-softmax) + in-place
// softmax, wave-level shfl reductions only. Cross-wave relu-sum via LDS ->
// ao[q,k] = sum_h relu(sc)/16 (f32).
// ---------------------------------------------------------------------------
__global__ __launch_bounds__(256) void smax_ao(bfr* __restrict__ sc,
                                               float* __restrict__ ao) {
  __shared__ float part[4][1024];
  const int q = blockIdx.x;
  const int tid = threadIdx.x, lane = tid & 63, w = tid >> 6;
  float aos[16];
#pragma unroll
  for (int i = 0; i < 16; i++) aos[i] = 0.f;
#pragma unroll
  for (int i = 0; i < 4; i++) {
    const int h = w * 4 + i;
    bfr* row = sc + ((size_t)h * 512 + q) * 1024 + lane * 16;
    us4 raw[4];
    float v[16];
#pragma unroll
    for (int j = 0; j < 4; j++) raw[j] = ((const us4*)row)[j];
#pragma unroll
    for (int j = 0; j < 4; j++) {
      v[j * 4 + 0] = b2f(raw[j].x); v[j * 4 + 1] = b2f(raw[j].y);
      v[j * 4 + 2] = b2f(raw[j].z); v[j * 4 + 3] = b2f(raw[j].w);
    }
    float m = v[0];
#pragma unroll
    for (int j = 1; j < 16; j++) m = fmaxf(m, v[j]);
#pragma unroll
    for (int j = 0; j < 16; j++) aos[j] += fmaxf(v[j], 0.f);
    for (int o = 32; o; o >>= 1) m = fmaxf(m, __shfl_xor(m, o, 64));
    float s = 0.f;
#pragma unroll
    for (int j = 0; j < 16; j++) { v[j] = expf(v[j] - m); s += v[j]; }
    for (int o = 32; o; o >>= 1) s += __shfl_xor(s, o, 64);
    const float inv = 1.0f / s;
#pragma unroll
    for (int j = 0; j < 4; j++) {
      raw[j].x = f2b(v[j * 4 + 0] * inv); raw[j].y = f2b(v[j * 4 + 1] * inv);
      raw[j].z = f2b(v[j * 4 + 2] * inv); raw[j].w = f2b(v[j * 4 + 3] * inv);
      ((us4*)row)[j] = raw[j];
    }
  }
#pragma unroll
  for (int j = 0; j < 4; j++)
    *(float4*)&part[w][lane * 16 + j * 4] =
        make_float4(aos[j * 4], aos[j * 4 + 1], aos[j * 4 + 2], aos[j * 4 + 3]);
  __syncthreads();
  const int k4 = tid * 4;
  float4 a0 = *(const float4*)&part[0][k4];
  float4 a1 = *(const float4*)&part[1][k4];
  float4 a2 = *(const float4*)&part[2][k4];
  float4 a3 = *(const float4*)&part[3][k4];
  store4(ao + (size_t)q * 1024 + k4,
         (a0.x + a1.x + a2.x + a3.x) * 0.0625f, (a0.y + a1.y + a2.y + a3.y) * 0.0625f,
         (a0.z + a1.z + a2.z + a3.z) * 0.0625f, (a0.w + a1.w + a2.w + a3.w) * 0.0625f);
}

// ---------------------------------------------------------------------------
// MFMA att@V (one batch): vT is [h][128 d'][1024 k] with d'<64 = v1 rows,
// d'>=64 = v0 rows (interleaved at weight-transpose time). Output tile
// 32q x 128d' per block, grid (16 qb, 16 h), 4 waves (2 row x 2 col halves),
// K-step 64: 8 MFMA per wave per barrier pair. Bias exact (softmax rows sum
// to 1). Waves 0-1 -> atp (+bv), waves 2-3 -> u (+bv0): wave-uniform.
// ---------------------------------------------------------------------------
__global__ __launch_bounds__(256) void attv2(const bfr* __restrict__ att,
                                             const bfr* __restrict__ vT,
                                             const float* __restrict__ bv,
                                             const float* __restrict__ bv0,
                                             bfr* __restrict__ atp,
                                             bfr* __restrict__ u) {
  __shared__ __align__(16) bfr As[32][72];
  __shared__ __align__(16) bfr Bs[128][72];
  const int h = blockIdx.y, q0 = blockIdx.x * 32;
  const int tid = threadIdx.x, lane = tid & 63, w = tid >> 6;
  const int fr = lane & 15, fc = (lane >> 4) * 8;
  const int wm = (w & 1) * 16, wn = (w >> 1) * 64;
  const bfr* attb = att + ((size_t)h * 512 + q0) * 1024;
  const bfr* vb = vT + (size_t)h * 128 * 1024;
  const int ar = tid >> 3, ac = (tid & 7) * 8;
  const int br = tid >> 2, bc = (tid & 3) * 16;
  f32x4 acc[4];
#pragma unroll
  for (int t = 0; t < 4; t++) acc[t] = (f32x4){0.f, 0.f, 0.f, 0.f};
  for (int k0 = 0; k0 < 1024; k0 += 64) {
    *(short8*)&As[ar][ac] = *(const short8*)(attb + (size_t)ar * 1024 + k0 + ac);
    *(short8*)&Bs[br][bc] = *(const short8*)(vb + (size_t)br * 1024 + k0 + bc);
    *(short8*)&Bs[br][bc + 8] = *(const short8*)(vb + (size_t)br * 1024 + k0 + bc + 8);
    *(short8*)&Bs[br + 64][bc] = *(const short8*)(vb + (size_t)(br + 64) * 1024 + k0 + bc);
    *(short8*)&Bs[br + 64][bc + 8] =
        *(const short8*)(vb + (size_t)(br + 64) * 1024 + k0 + bc + 8);
    __syncthreads();
#pragma unroll
    for (int ks = 0; ks < 2; ks++) {
      short8 af = *(const short8*)&As[wm + fr][ks * 32 + fc];
#pragma unroll
      for (int t = 0; t < 4; t++) {
        short8 bf = *(const short8*)&Bs[wn + t * 16 + fr][ks * 32 + fc];
        acc[t] = __builtin_amdgcn_mfma_f32_16x16x32_bf16(af, bf, acc[t], 0, 0, 0);
      }
    }
    __syncthreads();
  }
  const int row0 = q0 + wm + (lane >> 4) * 4;
  bfr* o = (wn == 0) ? atp : u;
  const float* bias = (wn == 0) ? bv : bv0;
#pragma unroll
  for (int t = 0; t < 4; t++) {
    const int cm = t * 16 + fr;  // 0..63 within the selected half
    const float bb = bias[h * 64 + cm];
#pragma unroll
    for (int r = 0; r < 4; r++)
      o[(size_t)(row0 + r) * 1024 + h * 64 + cm] = f2b(acc[t][r] + bb);
  }
}

// xpre_b[c] += sum over 64 rows of q0p_b[v,c]*u_b[v,c] (per batch), grid (4,8)
__global__ __launch_bounds__(256) void xpre_kernel(const bfr* __restrict__ q0p,
                                                   const bfr* __restrict__ u,
                                                   float* __restrict__ xpre) {
  const int c = blockIdx.x * 256 + threadIdx.x;
  const int r0 = blockIdx.y * 64;
  const bfr* qp = q0p + (size_t)r0 * 1024 + c;
  const bfr* up = u + (size_t)r0 * 1024 + c;
  float s = 0.f;
#pragma unroll 8
  for (int r = 0; r < 64; r++)
    s = fmaf(b2f(qp[(size_t)r * 1024]), b2f(up[(size_t)r * 1024]), s);
  atomicAdd(&xpre[c], s);
}

// torch_ln over rows of 1024: a*(x-mean)/(sqrt(var_unbiased)+1e-6)+b, X (+Y)
template <typename TX, typename TY, typename OT>
__global__ __launch_bounds__(256) void ln_kernel(const TX* __restrict__ X,
                                                 const TY* __restrict__ Y,
                                                 const float* __restrict__ ga,
                                                 const float* __restrict__ be,
                                                 OT* __restrict__ out) {
  __shared__ float sm[4];
  const size_t row = blockIdx.x;
  const int tid = threadIdx.x;
  float4 v = load4f(X + row * 1024 + tid * 4);
  if (Y) {
    float4 w = load4f(Y + row * 1024 + tid * 4);
    v.x += w.x; v.y += w.y; v.z += w.z; v.w += w.w;
  }
  float s = v.x + v.y + v.z + v.w;
  for (int o = 32; o; o >>= 1) s += __shfl_down(s, o, 64);
  if ((tid & 63) == 0) sm[tid >> 6] = s;
  __syncthreads();
  s = sm[0] + sm[1] + sm[2] + sm[3];
  float mean = s * (1.0f / 1024.0f);
  float d0 = v.x - mean, d1 = v.y - mean, d2 = v.z - mean, d3 = v.w - mean;
  float q = d0 * d0 + d1 * d1 + d2 * d2 + d3 * d3;
  __syncthreads();
  for (int o = 32; o; o >>= 1) q += __shfl_down(q, o, 64);
  if ((tid & 63) == 0) sm[tid >> 6] = q;
  __syncthreads();
  q = sm[0] + sm[1] + sm[2] + sm[3];
  float rs = 1.0f / (sqrtf(q * (1.0f / 1023.0f)) + 1e-6f);
  float4 g = *(const float4*)(ga + tid * 4);
  float4 bb = *(const float4*)(be + tid * 4);
  store4(out + row * 1024 + tid * 4,
         g.x * d0 * rs + bb.x, g.y * d1 * rs + bb.y,
         g.z * d2 * rs + bb.z, g.w * d3 * rs + bb.w);
}

// ---------------------------------------------------------------------------
extern "C" void kernel_launch(void* const* d_in, const int* in_sizes, int n_in,
                              void* d_out, int out_size, void* d_ws, size_t ws_size,
                              hipStream_t stream) {
  (void)in_sizes; (void)n_in; (void)out_size; (void)ws_size;
  const float* q   = (const float*)d_in[0];
  const float* k   = (const float*)d_in[1];
  const float* Wq  = (const float*)d_in[2];
  const float* bq  = (const float*)d_in[3];
  const float* Wk  = (const float*)d_in[4];
  const float* bk  = (const float*)d_in[5];
  const float* Wv  = (const float*)d_in[6];
  const float* bv  = (const float*)d_in[7];
  const float* Wv0 = (const float*)d_in[8];
  const float* bv0 = (const float*)d_in[9];
  const float* Wq0 = (const float*)d_in[10];
  const float* bq0 = (const float*)d_in[11];
  const float* nqa = (const float*)d_in[12];
  const float* nqb = (const float*)d_in[13];
  const float* nxa = (const float*)d_in[14];
  const float* nxb = (const float*)d_in[15];
  const float* W1  = (const float*)d_in[16];
  const float* b1  = (const float*)d_in[17];
  const float* W2  = (const float*)d_in[18];
  const float* b2  = (const float*)d_in[19];
  const float* nsa = (const float*)d_in[20];
  const float* nsb = (const float*)d_in[21];

  float* out = (float*)d_out;
  float* x_out  = out;                       // 8,192
  float* qq_out = out + 8192;                // 4,194,304 f32 (written LAST)
  float* kp_out = out + 4202496;             // 6,291,456
  float* ao_out = out + 10493952;            // 4,194,304
  // kp bf16 parked in the qq_out region until the final LN writes qq
  bfr* kp16 = (bfr*)qq_out;                  // 12,582,912 B used of 16 MiB

  char* base = (char*)d_ws;
  // persistent (attention phase)
  bfr* q0p   = (bfr*)(base + 0);            // 8,388,608  [4096,1024]
  bfr* qh    = (bfr*)(base + 8388608);      // 8,388,608  [4096,1024]
  bfr* atl   = (bfr*)(base + 16777216);     // 8,388,608  [4096,1024]
  bfr* WqT   = (bfr*)(base + 25165824);     // 1,572,864  [1024,768]
  bfr* Wq0T  = (bfr*)(base + 26738688);     // 1,572,864
  bfr* WTkv  = (bfr*)(base + 28311552);     // 4,718,592  [WkT 1024; vv-interleaved 2048][768]
  float* xpre = (float*)(base + 33030144);  //    32,768  [8,1024]
  char* S = base + 33062912;                // scratch region (25,165,824 B)
  // attention-loop overlay
  bfr* sc    = (bfr*)(S + 0);               // 16,777,216 [16,512,1024]
  bfr* vT    = (bfr*)(S + 16777216);        //  4,194,304 [16][128][1024] v1|v0
  bfr* atpb  = (bfr*)(S + 20971520);        //  1,048,576 [512,1024]
  bfr* ub    = (bfr*)(S + 22020096);        //  1,048,576
  bfr* kh    = (bfr*)(S + 23068672);        //  2,097,152 [1024,1024]
  // pre-loop overlay (dead before attention buffers first written)
  bfr* qp_all = (bfr*)(S + 0);              //  6,291,456 [4096,768]
  bfr* q16    = (bfr*)(S + 6291456);        //  6,291,456 [4096,768] plain q bf16
  // FFN-phase overlay (attention buffers dead; q0p/qh dead)
  bfr* W1Tn  = (bfr*)(S + 0);               //  4,194,304 [2048,1024]
  bfr* W2Tn  = (bfr*)(S + 4194304);         //  4,194,304 [1024,2048]
  bfr* ff1n  = (bfr*)(S + 8388608);         // 16,777,216 [4096,2048]
  float* ff2a = (float*)(base + 0);         // 16,777,216 [4096,1024] f32 (over q0p/qh)
  // peak footprint: 33,062,912 + 25,165,824 = 58,228,736 B

  // --- setup ---
  posenc_k<<<24576, 256, 0, stream>>>(k, kp_out, kp16, 6291456);
  posenc_q_all<<<12288, 256, 0, stream>>>(q, qp_all, q16, 3145728);
  transpose_w<<<dim3(32, 24), 256, 0, stream>>>(Wq, WqT, 768, 1024, 1024, 0);
  transpose_w<<<dim3(32, 24), 256, 0, stream>>>(Wq0, Wq0T, 768, 1024, 1024, 0);
  transpose_w<<<dim3(32, 24), 256, 0, stream>>>(Wk, WTkv, 768, 1024, 1024, 0);
  transpose_w<<<dim3(32, 24), 256, 0, stream>>>(Wv, WTkv + 786432, 768, 1024, 1024, 1);
  transpose_w<<<dim3(32, 24), 256, 0, stream>>>(Wv0, WTkv + 786432, 768, 1024, 1024, 2);

  // full-batch projections (fused, MFMA)
  proj_gemm<<<512, 256, 0, stream>>>(q16, Wq0T, bq0, q0p, qp_all, WqT, bq, qh);
  hipMemsetAsync(xpre, 0, 32768, stream);

  // --- per-batch attention ---
  for (int b = 0; b < 8; b++) {
    const bfr* kp_b = kp16 + (size_t)b * 786432;
    kv_gemm<<<192, 256, 0, stream>>>(kp_b, WTkv, bk, kh, WTkv + 786432, vT);
    score_mfma<<<dim3(8, 4, 16), 256, 0, stream>>>(qh + (size_t)b * 524288, kh, sc);
    smax_ao<<<512, 256, 0, stream>>>(sc, ao_out + (size_t)b * 524288);
    attv2<<<dim3(16, 16), 256, 0, stream>>>(sc, vT, bv, bv0, atpb, ub);
    xpre_kernel<<<dim3(4, 8), 256, 0, stream>>>(q0p + (size_t)b * 524288, ub,
                                                xpre + b * 1024);
    ln_kernel<bfr, bfr, bfr><<<512, 256, 0, stream>>>(
        q0p + (size_t)b * 524288, atpb, nqa, nqb, atl + (size_t)b * 524288);
  }

  // x = LN(bilinear)
  ln_kernel<float, float, float><<<8, 256, 0, stream>>>(xpre, (const float*)nullptr,
                                                        nxa, nxb, x_out);

  // --- FFN, K-split into 2 chunks of 2048, f32 accumulation in ff2a ---
  for (int nc = 0; nc < 2; nc++) {
    transpose_w<<<dim3(64, 32), 256, 0, stream>>>(W1 + nc * 2048, W1Tn,
                                                  1024, 2048, 4096, 0);
    transpose_w<<<dim3(32, 64), 256, 0, stream>>>(W2 + (size_t)nc * 2048 * 1024, W2Tn,
                                                  2048, 1024, 1024, 0);
    mgemm<bfr><<<dim3(16, 32), 256, 0, stream>>>(
        atl, W1Tn, b1 + nc * 2048, ff1n, 1024, 2048, 1, 0);
    mgemm<float><<<dim3(8, 32), 256, 0, stream>>>(
        ff1n, W2Tn, nc == 0 ? b2 : nullptr, ff2a, 2048, 1024, 0, nc);
  }
  ln_kernel<bfr, float, float><<<4096, 256, 0, stream>>>(atl, ff2a, nsa, nsb, qq_out);
}

// Round 6
// 801.148 us; speedup vs baseline: 2.6140x; 1.0562x over previous
//
#include <hip/hip_runtime.h>

// ---------------------------------------------------------------------------
// FocalAtt (CA mode): B=8, Lq=512, Lk=1024, qd=kd=768, hid=1024, mid=4096,
// H=16, dh=64. Inputs f32, outputs f32. bf16 MFMA GEMMs (16x16x32), fp32 acc.
// R6: batch-paired K/V projections (kv_gemm2, 768 blocks @128x64 tiles, 4
// launches; vT(b1) parked in qq_out spare, atpb/ub overlay dead kh); ff2 on
// 128x64 tiles (grid 512); attv2 ported to global_load_lds dbuf; setprio
// around MFMA clusters (T5).
// Workspace peak 58,241,024 B (< known-good 58,490,880).
// ---------------------------------------------------------------------------

typedef unsigned short bfr;  // raw bf16 bits
using short8 = __attribute__((ext_vector_type(8))) short;
using f32x4  = __attribute__((ext_vector_type(4))) float;

__device__ __forceinline__ float b2f(bfr s) {
  return __uint_as_float(((unsigned int)s) << 16);
}
__device__ __forceinline__ bfr f2b(float f) {
  unsigned int u = __float_as_uint(f);
  u += 0x7fffu + ((u >> 16) & 1u);  // RNE
  return (bfr)(u >> 16);
}

struct __align__(8) us4 { bfr x, y, z, w; };

__device__ __forceinline__ float4 load4f(const float* p) { return *(const float4*)p; }
__device__ __forceinline__ float4 load4f(const bfr* p) {
  us4 u = *(const us4*)p;
  return make_float4(b2f(u.x), b2f(u.y), b2f(u.z), b2f(u.w));
}
__device__ __forceinline__ void store4(float* p, float a, float b, float c, float d) {
  *(float4*)p = make_float4(a, b, c, d);
}
__device__ __forceinline__ void store4(bfr* p, float a, float b, float c, float d) {
  us4 v; v.x = f2b(a); v.y = f2b(b); v.z = f2b(c); v.w = f2b(d);
  *(us4*)p = v;
}

// async global(bf16 x8, 16B) -> LDS at wave-uniform base + lane*16B
__device__ __forceinline__ void gll16(const bfr* g, bfr* l) {
  __builtin_amdgcn_global_load_lds(
      (const __attribute__((address_space(1))) unsigned int*)g,
      (__attribute__((address_space(3))) unsigned int*)l, 16, 0, 0);
}

// ---------------------------------------------------------------------------
// Positional encoding
// ---------------------------------------------------------------------------
__device__ __forceinline__ float pe_val(int l, int d) {
  float ang = (float)l * expf((float)(d & ~1) * (-9.210340371976184f / 768.0f));
  return (d & 1) ? cosf(ang) : sinf(ang);
}

// k + PE -> f32 kp (output) AND bf16 copy (GEMM operand). total = 8*1024*768
__global__ __launch_bounds__(256) void posenc_k(const float* __restrict__ in,
                                                float* __restrict__ outf,
                                                bfr* __restrict__ outb, int total) {
  int idx = blockIdx.x * 256 + threadIdx.x;
  if (idx >= total) return;
  float v = in[idx] + pe_val((idx / 768) % 1024, idx % 768);
  outf[idx] = v;
  outb[idx] = f2b(v);
}

// q + PE -> bf16 qp_all [4096,768]; plain q -> bf16 q_b16
__global__ __launch_bounds__(256) void posenc_q_all(const float* __restrict__ in,
                                                    bfr* __restrict__ out,
                                                    bfr* __restrict__ outraw,
                                                    int total) {
  int idx = blockIdx.x * 256 + threadIdx.x;
  if (idx >= total) return;
  float v = in[idx];
  out[idx] = f2b(v + pe_val((idx / 768) % 512, idx % 768));
  outraw[idx] = f2b(v);
}

// ---------------------------------------------------------------------------
// Weight transpose: src f32 [rows, cols] (row stride ld) -> dst bf16 [cols, rows]
// grid (cols/32, rows/32), 256 threads. mode: dst-row remap for interleaved
// v1|v0 stacking. 0: r=c; 1: r=(c>>6)*128+(c&63); 2: r=(c>>6)*128+64+(c&63).
// ---------------------------------------------------------------------------
__global__ __launch_bounds__(256) void transpose_w(const float* __restrict__ src,
                                                   bfr* __restrict__ dst,
                                                   int rows, int cols, int ld,
                                                   int mode) {
  __shared__ float t[32][33];
  const int bc = blockIdx.x * 32, br = blockIdx.y * 32;
  const int tx = threadIdx.x & 31, ty = threadIdx.x >> 5;  // ty 0..7
#pragma unroll
  for (int i = 0; i < 4; i++)
    t[ty + i * 8][tx] = src[(size_t)(br + ty + i * 8) * ld + bc + tx];
  __syncthreads();
#pragma unroll
  for (int i = 0; i < 4; i++) {
    int c = bc + ty + i * 8;
    int r = (mode == 0) ? c : ((c >> 6) * 128 + (c & 63) + (mode == 2 ? 64 : 0));
    dst[(size_t)r * rows + br + tx] = f2b(t[tx][ty + i * 8]);
  }
}

// ---------------------------------------------------------------------------
// MFMA GEMM body (all-bf16): C[M,N] = A[M,K] @ B[K,N] (+bias, relu, accum).
// B passed as BT[N,K]. 128x128 block, 256 thr = 4 waves, each wave 64x64 via
// 4x4 of v_mfma_f32_16x16x32_bf16. BK=64, double-buffered: STAGE(t+1) issued
// before MFMA(t), one barrier per K-step. All staging via global_load_lds
// width 16 into linear LDS [128][64] (m97 recipe). K % 64 == 0.
// A-frag: lane holds A[m=lane&15][k=(lane>>4)*8+j]; D: row=(lane>>4)*4+r,
// col=lane&15 (measured m89/m91 layouts).
// ---------------------------------------------------------------------------
template <typename TC>
__device__ __forceinline__ void mgemm_body(const bfr* __restrict__ A,
                                           const bfr* __restrict__ BT,
                                           const float* __restrict__ bias,
                                           TC* __restrict__ C,
                                           int K, int ldc, int relu, int accum,
                                           int m0, int n0,
                                           bfr* __restrict__ As,   // [2][8192]
                                           bfr* __restrict__ Bs) { // [2][8192]
  const int tid = threadIdx.x;
  const int lane = tid & 63, w = tid >> 6;
  const int wm = (w & 1) * 64, wn = (w >> 1) * 64;
  const int grow = w * 32 + (lane >> 3);  // 8 lanes/row (64 cols x 2B = 128 B)
  const int gkc = (lane & 7) * 8;
  const int fr = lane & 15, fc = (lane >> 4) * 8;
  const int NT = K >> 6;
  f32x4 acc[4][4];
#pragma unroll
  for (int i = 0; i < 4; i++)
#pragma unroll
    for (int j = 0; j < 4; j++) acc[i][j] = (f32x4){0.f, 0.f, 0.f, 0.f};

  auto issue = [&](int t, int buf) {
    const int k0 = t << 6;
    const bfr* Ag = A + (size_t)(m0 + grow) * K + k0 + gkc;
    const bfr* Bg = BT + (size_t)(n0 + grow) * K + k0 + gkc;
#pragma unroll
    for (int i = 0; i < 4; i++)
      gll16(Ag + (size_t)(i * 8) * K, As + buf * 8192 + (w * 32 + i * 8) * 64);
#pragma unroll
    for (int i = 0; i < 4; i++)
      gll16(Bg + (size_t)(i * 8) * K, Bs + buf * 8192 + (w * 32 + i * 8) * 64);
  };

  issue(0, 0);
  __syncthreads();
  int cur = 0;
  for (int t = 0; t < NT; ++t) {
    const bool more = (t + 1 < NT);
    if (more) issue(t + 1, cur ^ 1);
    __builtin_amdgcn_s_setprio(1);
#pragma unroll
    for (int ks = 0; ks < 2; ks++) {
      short8 af[4], bf4[4];
#pragma unroll
      for (int i = 0; i < 4; i++)
        af[i] = *(const short8*)(As + cur * 8192 + (wm + i * 16 + fr) * 64 + ks * 32 + fc);
#pragma unroll
      for (int i = 0; i < 4; i++)
        bf4[i] = *(const short8*)(Bs + cur * 8192 + (wn + i * 16 + fr) * 64 + ks * 32 + fc);
#pragma unroll
      for (int i = 0; i < 4; i++)
#pragma unroll
        for (int j = 0; j < 4; j++)
          acc[i][j] = __builtin_amdgcn_mfma_f32_16x16x32_bf16(af[i], bf4[j], acc[i][j], 0, 0, 0);
    }
    __builtin_amdgcn_s_setprio(0);
    if (more) {
      __syncthreads();
      cur ^= 1;
    }
  }
  const int col0 = n0 + wn + fr;
  const int row0 = m0 + wm + (lane >> 4) * 4;
  float bsv[4];
#pragma unroll
  for (int j = 0; j < 4; j++) bsv[j] = bias ? bias[col0 + j * 16] : 0.f;
#pragma unroll
  for (int i = 0; i < 4; i++) {
#pragma unroll
    for (int j = 0; j < 4; j++) {
      const int col = col0 + j * 16;
#pragma unroll
      for (int r = 0; r < 4; r++) {
        const int row = row0 + i * 16 + r;
        float v = acc[i][j][r] + bsv[j];
        if (relu) v = fmaxf(v, 0.f);
        size_t idx = (size_t)row * ldc + col;
        if constexpr (sizeof(TC) == 2) {
          C[idx] = f2b(v);
        } else {
          if (accum) C[idx] += v; else C[idx] = v;
        }
      }
    }
  }
}

// 128x64-tile body: 4 waves (2m x 2n), each wave 64x32 = 4x2 fragments.
// As [2][128*64], Bs [2][64*64].
template <typename TC>
__device__ __forceinline__ void mgemm_body64(const bfr* __restrict__ A,
                                             const bfr* __restrict__ BT,
                                             const float* __restrict__ bias,
                                             TC* __restrict__ C,
                                             int K, int ldc, int relu, int accum,
                                             int m0, int n0,
                                             bfr* __restrict__ As,
                                             bfr* __restrict__ Bs) {
  const int tid = threadIdx.x;
  const int lane = tid & 63, w = tid >> 6;
  const int wm = (w & 1) * 64, wn = (w >> 1) * 32;
  const int grow = lane >> 3, gkc = (lane & 7) * 8;
  const int fr = lane & 15, fc = (lane >> 4) * 8;
  const int NT = K >> 6;
  f32x4 acc[4][2];
#pragma unroll
  for (int i = 0; i < 4; i++)
#pragma unroll
    for (int j = 0; j < 2; j++) acc[i][j] = (f32x4){0.f, 0.f, 0.f, 0.f};

  auto issue = [&](int t, int buf) {
    const int k0 = t << 6;
    const bfr* Ag = A + (size_t)(m0 + w * 32 + grow) * K + k0 + gkc;
#pragma unroll
    for (int i = 0; i < 4; i++)
      gll16(Ag + (size_t)(i * 8) * K, As + buf * 8192 + (w * 32 + i * 8) * 64);
    const bfr* Bg = BT + (size_t)(n0 + w * 16 + grow) * K + k0 + gkc;
#pragma unroll
    for (int i = 0; i < 2; i++)
      gll16(Bg + (size_t)(i * 8) * K, Bs + buf * 4096 + (w * 16 + i * 8) * 64);
  };

  issue(0, 0);
  __syncthreads();
  int cur = 0;
  for (int t = 0; t < NT; ++t) {
    const bool more = (t + 1 < NT);
    if (more) issue(t + 1, cur ^ 1);
    __builtin_amdgcn_s_setprio(1);
#pragma unroll
    for (int ks = 0; ks < 2; ks++) {
      short8 af[4], bf4[2];
#pragma unroll
      for (int i = 0; i < 4; i++)
        af[i] = *(const short8*)(As + cur * 8192 + (wm + i * 16 + fr) * 64 + ks * 32 + fc);
#pragma unroll
      for (int j = 0; j < 2; j++)
        bf4[j] = *(const short8*)(Bs + cur * 4096 + (wn + j * 16 + fr) * 64 + ks * 32 + fc);
#pragma unroll
      for (int i = 0; i < 4; i++)
#pragma unroll
        for (int j = 0; j < 2; j++)
          acc[i][j] = __builtin_amdgcn_mfma_f32_16x16x32_bf16(af[i], bf4[j], acc[i][j], 0, 0, 0);
    }
    __builtin_amdgcn_s_setprio(0);
    if (more) {
      __syncthreads();
      cur ^= 1;
    }
  }
  const int col0 = n0 + wn + fr;
  const int row0 = m0 + wm + (lane >> 4) * 4;
  float bsv[2];
#pragma unroll
  for (int j = 0; j < 2; j++) bsv[j] = bias ? bias[col0 + j * 16] : 0.f;
#pragma unroll
  for (int i = 0; i < 4; i++) {
#pragma unroll
    for (int j = 0; j < 2; j++) {
      const int col = col0 + j * 16;
#pragma unroll
      for (int r = 0; r < 4; r++) {
        const int row = row0 + i * 16 + r;
        float v = acc[i][j][r] + bsv[j];
        if (relu) v = fmaxf(v, 0.f);
        size_t idx = (size_t)row * ldc + col;
        if constexpr (sizeof(TC) == 2) {
          C[idx] = f2b(v);
        } else {
          if (accum) C[idx] += v; else C[idx] = v;
        }
      }
    }
  }
}

// standalone wrapper: 2-D grid, XCD-bijective swizzle (m204)
template <typename TC>
__global__ __launch_bounds__(256) void mgemm(const bfr* __restrict__ A,
                                             const bfr* __restrict__ BT,
                                             const float* __restrict__ bias,
                                             TC* __restrict__ C,
                                             int K, int ldc, int relu, int accum) {
  __shared__ bfr As[2][8192];
  __shared__ bfr Bs[2][8192];
  const int nwg = gridDim.x * gridDim.y;
  const int bid = blockIdx.y * gridDim.x + blockIdx.x;
  const int q8 = nwg >> 3, r8 = nwg & 7;
  const int xcd = bid & 7, off = bid >> 3;
  const int swz = (xcd < r8 ? xcd * (q8 + 1) : r8 * (q8 + 1) + (xcd - r8) * q8) + off;
  const int n0 = (swz % gridDim.x) * 128, m0 = (swz / gridDim.x) * 128;
  mgemm_body<TC>(A, BT, bias, C, K, ldc, relu, accum, m0, n0,
                 &As[0][0], &Bs[0][0]);
}

// standalone 128x64-tile wrapper
template <typename TC>
__global__ __launch_bounds__(256) void mgemm64(const bfr* __restrict__ A,
                                               const bfr* __restrict__ BT,
                                               const float* __restrict__ bias,
                                               TC* __restrict__ C,
                                               int K, int ldc, int relu, int accum) {
  __shared__ bfr As[2][8192];
  __shared__ bfr Bs[2][4096];
  const int nwg = gridDim.x * gridDim.y;
  const int bid = blockIdx.y * gridDim.x + blockIdx.x;
  const int q8 = nwg >> 3, r8 = nwg & 7;
  const int xcd = bid & 7, off = bid >> 3;
  const int swz = (xcd < r8 ? xcd * (q8 + 1) : r8 * (q8 + 1) + (xcd - r8) * q8) + off;
  const int n0 = (swz % gridDim.x) * 64, m0 = (swz / gridDim.x) * 128;
  mgemm_body64<TC>(A, BT, bias, C, K, ldc, relu, accum, m0, n0,
                   &As[0][0], &Bs[0][0]);
}

// batch-paired K/V projection: 768 blocks @128x64 tiles (3 blocks/CU).
// blocks 0..127 kh0, 128..255 kh1, 256..511 vT0, 512..767 vT1.
__global__ __launch_bounds__(256) void kv_gemm2(const bfr* __restrict__ kp0,
                                                const bfr* __restrict__ kp1,
                                                const bfr* __restrict__ WkT,
                                                const float* __restrict__ bk,
                                                bfr* __restrict__ kh0,
                                                bfr* __restrict__ kh1,
                                                const bfr* __restrict__ WTvv,
                                                bfr* __restrict__ vT0,
                                                bfr* __restrict__ vT1) {
  __shared__ bfr As[2][8192];
  __shared__ bfr Bs[2][4096];
  const int swz = (blockIdx.x & 7) * 96 + (blockIdx.x >> 3);  // nwg=768, r8=0
  if (swz < 128) {          // kh0: M=1024 (8x128), N=1024 (16x64)
    mgemm_body64<bfr>(kp0, WkT, bk, kh0, 768, 1024, 0, 0,
                      (swz >> 4) * 128, (swz & 15) * 64, &As[0][0], &Bs[0][0]);
  } else if (swz < 256) {
    const int s = swz - 128;
    mgemm_body64<bfr>(kp1, WkT, bk, kh1, 768, 1024, 0, 0,
                      (s >> 4) * 128, (s & 15) * 64, &As[0][0], &Bs[0][0]);
  } else if (swz < 512) {   // vT0: M=2048 (16x128), N=1024 (16x64)
    const int s = swz - 256;
    mgemm_body64<bfr>(WTvv, kp0, nullptr, vT0, 768, 1024, 0, 0,
                      (s >> 4) * 128, (s & 15) * 64, &As[0][0], &Bs[0][0]);
  } else {
    const int s = swz - 512;
    mgemm_body64<bfr>(WTvv, kp1, nullptr, vT1, 768, 1024, 0, 0,
                      (s >> 4) * 128, (s & 15) * 64, &As[0][0], &Bs[0][0]);
  }
}

// fused q projections: blocks 0..255 -> q0p = q_b16@Wq0T + bq0 (32x8),
// blocks 256..511 -> qh = qp_all@WqT + bq (32x8). 1-D grid 512.
__global__ __launch_bounds__(256) void proj_gemm(const bfr* __restrict__ q16,
                                                 const bfr* __restrict__ Wq0T,
                                                 const float* __restrict__ bq0,
                                                 bfr* __restrict__ q0p,
                                                 const bfr* __restrict__ qp_all,
                                                 const bfr* __restrict__ WqT,
                                                 const float* __restrict__ bq,
                                                 bfr* __restrict__ qh) {
  __shared__ bfr As[2][8192];
  __shared__ bfr Bs[2][8192];
  const int swz = (blockIdx.x & 7) * 64 + (blockIdx.x >> 3);  // nwg=512, r8=0
  if (swz < 256) {
    mgemm_body<bfr>(q16, Wq0T, bq0, q0p, 768, 1024, 0, 0,
                    (swz >> 3) * 128, (swz & 7) * 128, &As[0][0], &Bs[0][0]);
  } else {
    const int s = swz - 256;
    mgemm_body<bfr>(qp_all, WqT, bq, qh, 768, 1024, 0, 0,
                    (s >> 3) * 128, (s & 7) * 128, &As[0][0], &Bs[0][0]);
  }
}

// ---------------------------------------------------------------------------
// MFMA scores (one batch): sc[h,q,k] = dot_64(qh[q,h*64+:], kh[k,h*64+:]) / 8
// 128x128 tile, K=64 (two 32-steps, staged once). grid (8 kb, 4 qb, 16 h).
// ---------------------------------------------------------------------------
__global__ __launch_bounds__(256) void score_mfma(const bfr* __restrict__ qh,
                                                  const bfr* __restrict__ kh,
                                                  bfr* __restrict__ sc) {
  __shared__ __align__(16) bfr Qs[128][72];  // stride 144 B: 2-way max, free
  __shared__ __align__(16) bfr Ks[128][72];
  const int h = blockIdx.z, q0 = blockIdx.y * 128, k0 = blockIdx.x * 128;
  const int tid = threadIdx.x, lane = tid & 63;
  const int wm = ((tid >> 6) & 1) * 64, wn = (tid >> 7) * 64;
  const int fr = lane & 15, fc = (lane >> 4) * 8;
  {
    const int r = tid >> 1, c = (tid & 1) * 32;
    const bfr* qsrc = qh + (size_t)(q0 + r) * 1024 + h * 64 + c;
    const bfr* ksrc = kh + (size_t)(k0 + r) * 1024 + h * 64 + c;
#pragma unroll
    for (int i = 0; i < 4; i++) {
      *(short8*)&Qs[r][c + i * 8] = *(const short8*)(qsrc + i * 8);
      *(short8*)&Ks[r][c + i * 8] = *(const short8*)(ksrc + i * 8);
    }
  }
  __syncthreads();
  f32x4 acc[4][4];
#pragma unroll
  for (int i = 0; i < 4; i++)
#pragma unroll
    for (int j = 0; j < 4; j++) acc[i][j] = (f32x4){0.f, 0.f, 0.f, 0.f};
  __builtin_amdgcn_s_setprio(1);
#pragma unroll
  for (int ks = 0; ks < 2; ks++) {
    short8 af[4], bf[4];
#pragma unroll
    for (int t = 0; t < 4; t++) af[t] = *(const short8*)&Qs[wm + t * 16 + fr][ks * 32 + fc];
#pragma unroll
    for (int t = 0; t < 4; t++) bf[t] = *(const short8*)&Ks[wn + t * 16 + fr][ks * 32 + fc];
#pragma unroll
    for (int i = 0; i < 4; i++)
#pragma unroll
      for (int j = 0; j < 4; j++)
        acc[i][j] = __builtin_amdgcn_mfma_f32_16x16x32_bf16(af[i], bf[j], acc[i][j], 0, 0, 0);
  }
  __builtin_amdgcn_s_setprio(0);
  const int col0 = k0 + wn + fr;
  const int row0 = q0 + wm + (lane >> 4) * 4;
#pragma unroll
  for (int i = 0; i < 4; i++)
#pragma unroll
    for (int j = 0; j < 4; j++)
#pragma unroll
      for (int r = 0; r < 4; r++)
        sc[((size_t)h * 512 + row0 + i * 16 + r) * 1024 + col0 + j * 16] =
            f2b(acc[i][j][r] * 0.125f);
}

// ---------------------------------------------------------------------------
// Fused attout + softmax (one batch): block per q (512 blocks). 4 waves x 4 h
// each. Per (h,q)-row of 1024: relu-sum partial (pre-softmax) + in-place
// softmax, wave-level shfl reductions only. Cross-wave relu-sum via LDS ->
// ao[q,k] = sum_h relu(sc)/16 (f32).
// ---------------------------------------------------------------------------
__global__ __launch_bounds__(256) void smax_ao(bfr* __restrict__ sc,
                                               float* __restrict__ ao) {
  __shared__ float part[4][1024];
  const int q = blockIdx.x;
  const int tid = threadIdx.x, lane = tid & 63, w = tid >> 6;
  float aos[16];
#pragma unroll
  for (int i = 0; i < 16; i++) aos[i] = 0.f;
#pragma unroll
  for (int i = 0; i < 4; i++) {
    const int h = w * 4 + i;
    bfr* row = sc + ((size_t)h * 512 + q) * 1024 + lane * 16;
    us4 raw[4];
    float v[16];
#pragma unroll
    for (int j = 0; j < 4; j++) raw[j] = ((const us4*)row)[j];
#pragma unroll
    for (int j = 0; j < 4; j++) {
      v[j * 4 + 0] = b2f(raw[j].x); v[j * 4 + 1] = b2f(raw[j].y);
      v[j * 4 + 2] = b2f(raw[j].z); v[j * 4 + 3] = b2f(raw[j].w);
    }
    float m = v[0];
#pragma unroll
    for (int j = 1; j < 16; j++) m = fmaxf(m, v[j]);
#pragma unroll
    for (int j = 0; j < 16; j++) aos[j] += fmaxf(v[j], 0.f);
    for (int o = 32; o; o >>= 1) m = fmaxf(m, __shfl_xor(m, o, 64));
    float s = 0.f;
#pragma unroll
    for (int j = 0; j < 16; j++) { v[j] = expf(v[j] - m); s += v[j]; }
    for (int o = 32; o; o >>= 1) s += __shfl_xor(s, o, 64);
    const float inv = 1.0f / s;
#pragma unroll
    for (int j = 0; j < 4; j++) {
      raw[j].x = f2b(v[j * 4 + 0] * inv); raw[j].y = f2b(v[j * 4 + 1] * inv);
      raw[j].z = f2b(v[j * 4 + 2] * inv); raw[j].w = f2b(v[j * 4 + 3] * inv);
      ((us4*)row)[j] = raw[j];
    }
  }
#pragma unroll
  for (int j = 0; j < 4; j++)
    *(float4*)&part[w][lane * 16 + j * 4] =
        make_float4(aos[j * 4], aos[j * 4 + 1], aos[j * 4 + 2], aos[j * 4 + 3]);
  __syncthreads();
  const int k4 = tid * 4;
  float4 a0 = *(const float4*)&part[0][k4];
  float4 a1 = *(const float4*)&part[1][k4];
  float4 a2 = *(const float4*)&part[2][k4];
  float4 a3 = *(const float4*)&part[3][k4];
  store4(ao + (size_t)q * 1024 + k4,
         (a0.x + a1.x + a2.x + a3.x) * 0.0625f, (a0.y + a1.y + a2.y + a3.y) * 0.0625f,
         (a0.z + a1.z + a2.z + a3.z) * 0.0625f, (a0.w + a1.w + a2.w + a3.w) * 0.0625f);
}

// ---------------------------------------------------------------------------
// MFMA att@V (one batch): vT is [h][128 d'][1024 k] with d'<64 = v1 rows,
// d'>=64 = v0 rows. Output tile 32q x 128d' per block, grid (16 qb, 16 h),
// 4 waves (2 q-halves x {atp,u}). global_load_lds dbuf staging, K-step 64:
// 8 MFMA per wave per barrier. Bias exact (softmax rows sum to 1).
// ---------------------------------------------------------------------------
__global__ __launch_bounds__(256) void attv2(const bfr* __restrict__ att,
                                             const bfr* __restrict__ vT,
                                             const float* __restrict__ bv,
                                             const float* __restrict__ bv0,
                                             bfr* __restrict__ atp,
                                             bfr* __restrict__ u) {
  __shared__ bfr As[2][32 * 64];   // 8 KB
  __shared__ bfr Bs[2][128 * 64];  // 32 KB
  const int h = blockIdx.y, q0 = blockIdx.x * 32;
  const int tid = threadIdx.x, lane = tid & 63, w = tid >> 6;
  const int fr = lane & 15, fc = (lane >> 4) * 8;
  const int wm = (w & 1) * 16, wn = (w >> 1) * 64;
  const bfr* attb = att + ((size_t)h * 512 + q0) * 1024;
  const bfr* vb = vT + (size_t)h * 128 * 1024;
  const int grow = lane >> 3, gkc = (lane & 7) * 8;
  f32x4 acc[4];
#pragma unroll
  for (int t = 0; t < 4; t++) acc[t] = (f32x4){0.f, 0.f, 0.f, 0.f};

  auto issue = [&](int t, int buf) {
    const int k0 = t << 6;
    gll16(attb + (size_t)(w * 8 + grow) * 1024 + k0 + gkc, &As[buf][(w * 8) * 64]);
#pragma unroll
    for (int i = 0; i < 4; i++)
      gll16(vb + (size_t)(w * 32 + i * 8 + grow) * 1024 + k0 + gkc,
            &Bs[buf][(w * 32 + i * 8) * 64]);
  };

  issue(0, 0);
  __syncthreads();
  int cur = 0;
  for (int t = 0; t < 16; ++t) {
    const bool more = (t + 1 < 16);
    if (more) issue(t + 1, cur ^ 1);
    __builtin_amdgcn_s_setprio(1);
#pragma unroll
    for (int ks = 0; ks < 2; ks++) {
      short8 af = *(const short8*)&As[cur][(wm + fr) * 64 + ks * 32 + fc];
#pragma unroll
      for (int j = 0; j < 4; j++) {
        short8 bf = *(const short8*)&Bs[cur][(wn + j * 16 + fr) * 64 + ks * 32 + fc];
        acc[j] = __builtin_amdgcn_mfma_f32_16x16x32_bf16(af, bf, acc[j], 0, 0, 0);
      }
    }
    __builtin_amdgcn_s_setprio(0);
    if (more) {
      __syncthreads();
      cur ^= 1;
    }
  }
  const int row0 = q0 + wm + (lane >> 4) * 4;
  bfr* o = (wn == 0) ? atp : u;
  const float* bias = (wn == 0) ? bv : bv0;
#pragma unroll
  for (int t = 0; t < 4; t++) {
    const int cm = t * 16 + fr;  // 0..63 within the selected half
    const float bb = bias[h * 64 + cm];
#pragma unroll
    for (int r = 0; r < 4; r++)
      o[(size_t)(row0 + r) * 1024 + h * 64 + cm] = f2b(acc[t][r] + bb);
  }
}

// xpre_b[c] += sum over 64 rows of q0p_b[v,c]*u_b[v,c] (per batch), grid (4,8)
__global__ __launch_bounds__(256) void xpre_kernel(const bfr* __restrict__ q0p,
                                                   const bfr* __restrict__ u,
                                                   float* __restrict__ xpre) {
  const int c = blockIdx.x * 256 + threadIdx.x;
  const int r0 = blockIdx.y * 64;
  const bfr* qp = q0p + (size_t)r0 * 1024 + c;
  const bfr* up = u + (size_t)r0 * 1024 + c;
  float s = 0.f;
#pragma unroll 8
  for (int r = 0; r < 64; r++)
    s = fmaf(b2f(qp[(size_t)r * 1024]), b2f(up[(size_t)r * 1024]), s);
  atomicAdd(&xpre[c], s);
}

// torch_ln over rows of 1024: a*(x-mean)/(sqrt(var_unbiased)+1e-6)+b, X (+Y)
template <typename TX, typename TY, typename OT>
__global__ __launch_bounds__(256) void ln_kernel(const TX* __restrict__ X,
                                                 const TY* __restrict__ Y,
                                                 const float* __restrict__ ga,
                                                 const float* __restrict__ be,
                                                 OT* __restrict__ out) {
  __shared__ float sm[4];
  const size_t row = blockIdx.x;
  const int tid = threadIdx.x;
  float4 v = load4f(X + row * 1024 + tid * 4);
  if (Y) {
    float4 w = load4f(Y + row * 1024 + tid * 4);
    v.x += w.x; v.y += w.y; v.z += w.z; v.w += w.w;
  }
  float s = v.x + v.y + v.z + v.w;
  for (int o = 32; o; o >>= 1) s += __shfl_down(s, o, 64);
  if ((tid & 63) == 0) sm[tid >> 6] = s;
  __syncthreads();
  s = sm[0] + sm[1] + sm[2] + sm[3];
  float mean = s * (1.0f / 1024.0f);
  float d0 = v.x - mean, d1 = v.y - mean, d2 = v.z - mean, d3 = v.w - mean;
  float q = d0 * d0 + d1 * d1 + d2 * d2 + d3 * d3;
  __syncthreads();
  for (int o = 32; o; o >>= 1) q += __shfl_down(q, o, 64);
  if ((tid & 63) == 0) sm[tid >> 6] = q;
  __syncthreads();
  q = sm[0] + sm[1] + sm[2] + sm[3];
  float rs = 1.0f / (sqrtf(q * (1.0f / 1023.0f)) + 1e-6f);
  float4 g = *(const float4*)(ga + tid * 4);
  float4 bb = *(const float4*)(be + tid * 4);
  store4(out + row * 1024 + tid * 4,
         g.x * d0 * rs + bb.x, g.y * d1 * rs + bb.y,
         g.z * d2 * rs + bb.z, g.w * d3 * rs + bb.w);
}

// ---------------------------------------------------------------------------
extern "C" void kernel_launch(void* const* d_in, const int* in_sizes, int n_in,
                              void* d_out, int out_size, void* d_ws, size_t ws_size,
                              hipStream_t stream) {
  (void)in_sizes; (void)n_in; (void)out_size; (void)ws_size;
  const float* q   = (const float*)d_in[0];
  const float* k   = (const float*)d_in[1];
  const float* Wq  = (const float*)d_in[2];
  const float* bq  = (const float*)d_in[3];
  const float* Wk  = (const float*)d_in[4];
  const float* bk  = (const float*)d_in[5];
  const float* Wv  = (const float*)d_in[6];
  const float* bv  = (const float*)d_in[7];
  const float* Wv0 = (const float*)d_in[8];
  const float* bv0 = (const float*)d_in[9];
  const float* Wq0 = (const float*)d_in[10];
  const float* bq0 = (const float*)d_in[11];
  const float* nqa = (const float*)d_in[12];
  const float* nqb = (const float*)d_in[13];
  const float* nxa = (const float*)d_in[14];
  const float* nxb = (const float*)d_in[15];
  const float* W1  = (const float*)d_in[16];
  const float* b1  = (const float*)d_in[17];
  const float* W2  = (const float*)d_in[18];
  const float* b2  = (const float*)d_in[19];
  const float* nsa = (const float*)d_in[20];
  const float* nsb = (const float*)d_in[21];

  float* out = (float*)d_out;
  float* x_out  = out;                       // 8,192
  float* qq_out = out + 8192;                // 4,194,304 f32 (written LAST)
  float* kp_out = out + 4202496;             // 6,291,456
  float* ao_out = out + 10493952;            // 4,194,304
  // qq_out region doubles as scratch until the final LN:
  bfr* kp16 = (bfr*)qq_out;                  // 12,582,912 B
  bfr* vT1  = kp16 + 6291456;                //  4,194,304 B (tail of qq_out)

  char* base = (char*)d_ws;
  // persistent (attention phase)
  bfr* q0p   = (bfr*)(base + 0);            // 8,388,608  [4096,1024]
  bfr* qh    = (bfr*)(base + 8388608);      // 8,388,608  [4096,1024]
  bfr* atl   = (bfr*)(base + 16777216);     // 8,388,608  [4096,1024]
  bfr* WqT   = (bfr*)(base + 25165824);     // 1,572,864  [1024,768]
  bfr* Wq0T  = (bfr*)(base + 26738688);     // 1,572,864
  bfr* WTkv  = (bfr*)(base + 28311552);     // 4,718,592  [WkT 1024; vv-interleaved 2048][768]
  float* xpre = (float*)(base + 33030144);  //    32,768  [8,1024]
  char* S = base + 33062912;                // scratch region (25,165,824 B)
  // attention-loop overlay (batch-paired)
  bfr* sc    = (bfr*)(S + 0);               // 16,777,216 [16,512,1024]
  bfr* kh0   = (bfr*)(S + 16777216);        //  2,097,152 [1024,1024]
  bfr* kh1   = (bfr*)(S + 18874368);        //  2,097,152
  bfr* vT0   = (bfr*)(S + 20971520);        //  4,194,304 [16][128][1024] v1|v0
  // atpb/ub overlay the dead kh of the same batch (kh dead after its score)
  bfr* atp0  = (bfr*)(S + 16777216);        //  1,048,576 [512,1024]
  bfr* ub0   = (bfr*)(S + 17825792);        //  1,048,576
  bfr* atp1  = (bfr*)(S + 18874368);        //  1,048,576
  bfr* ub1   = (bfr*)(S + 19922944);        //  1,048,576
  // pre-loop overlay (dead before attention buffers first written)
  bfr* qp_all = (bfr*)(S + 0);              //  6,291,456 [4096,768]
  bfr* q16    = (bfr*)(S + 6291456);        //  6,291,456 [4096,768] plain q bf16
  // FFN-phase overlay (attention buffers dead; q0p/qh dead)
  bfr* W1Tn  = (bfr*)(S + 0);               //  4,194,304 [2048,1024]
  bfr* W2Tn  = (bfr*)(S + 4194304);         //  4,194,304 [1024,2048]
  bfr* ff1n  = (bfr*)(S + 8388608);         // 16,777,216 [4096,2048]
  float* ff2a = (float*)(base + 0);         // 16,777,216 [4096,1024] f32 (over q0p/qh)

  // --- setup ---
  posenc_k<<<24576, 256, 0, stream>>>(k, kp_out, kp16, 6291456);
  posenc_q_all<<<12288, 256, 0, stream>>>(q, qp_all, q16, 3145728);
  transpose_w<<<dim3(32, 24), 256, 0, stream>>>(Wq, WqT, 768, 1024, 1024, 0);
  transpose_w<<<dim3(32, 24), 256, 0, stream>>>(Wq0, Wq0T, 768, 1024, 1024, 0);
  transpose_w<<<dim3(32, 24), 256, 0, stream>>>(Wk, WTkv, 768, 1024, 1024, 0);
  transpose_w<<<dim3(32, 24), 256, 0, stream>>>(Wv, WTkv + 786432, 768, 1024, 1024, 1);
  transpose_w<<<dim3(32, 24), 256, 0, stream>>>(Wv0, WTkv + 786432, 768, 1024, 1024, 2);

  // full-batch projections (fused, MFMA)
  proj_gemm<<<512, 256, 0, stream>>>(q16, Wq0T, bq0, q0p, qp_all, WqT, bq, qh);
  hipMemsetAsync(xpre, 0, 32768, stream);

  // --- per-batch-pair attention ---
  for (int p = 0; p < 4; p++) {
    const int b0 = 2 * p, b1 = 2 * p + 1;
    kv_gemm2<<<768, 256, 0, stream>>>(kp16 + (size_t)b0 * 786432,
                                      kp16 + (size_t)b1 * 786432,
                                      WTkv, bk, kh0, kh1,
                                      WTkv + 786432, vT0, vT1);
    for (int j = 0; j < 2; j++) {
      const int b = b0 + j;
      bfr* kh = j ? kh1 : kh0;
      bfr* vT = j ? vT1 : vT0;
      bfr* atpb = j ? atp1 : atp0;
      bfr* ub = j ? ub1 : ub0;
      score_mfma<<<dim3(8, 4, 16), 256, 0, stream>>>(qh + (size_t)b * 524288, kh, sc);
      smax_ao<<<512, 256, 0, stream>>>(sc, ao_out + (size_t)b * 524288);
      attv2<<<dim3(16, 16), 256, 0, stream>>>(sc, vT, bv, bv0, atpb, ub);
      xpre_kernel<<<dim3(4, 8), 256, 0, stream>>>(q0p + (size_t)b * 524288, ub,
                                                  xpre + b * 1024);
      ln_kernel<bfr, bfr, bfr><<<512, 256, 0, stream>>>(
          q0p + (size_t)b * 524288, atpb, nqa, nqb, atl + (size_t)b * 524288);
    }
  }

  // x = LN(bilinear)
  ln_kernel<float, float, float><<<8, 256, 0, stream>>>(xpre, (const float*)nullptr,
                                                        nxa, nxb, x_out);

  // --- FFN, K-split into 2 chunks of 2048, f32 accumulation in ff2a ---
  for (int nc = 0; nc < 2; nc++) {
    transpose_w<<<dim3(64, 32), 256, 0, stream>>>(W1 + nc * 2048, W1Tn,
                                                  1024, 2048, 4096, 0);
    transpose_w<<<dim3(32, 64), 256, 0, stream>>>(W2 + (size_t)nc * 2048 * 1024, W2Tn,
                                                  2048, 1024, 1024, 0);
    mgemm<bfr><<<dim3(16, 32), 256, 0, stream>>>(
        atl, W1Tn, b1 + nc * 2048, ff1n, 1024, 2048, 1, 0);
    mgemm64<float><<<dim3(16, 32), 256, 0, stream>>>(
        ff1n, W2Tn, nc == 0 ? b2 : nullptr, ff2a, 2048, 1024, 0, nc);
  }
  ln_kernel<bfr, float, float><<<4096, 256, 0, stream>>>(atl, ff2a, nsa, nsb, qq_out);
}

// Round 7
// 779.983 us; speedup vs baseline: 2.6849x; 1.0271x over previous
//
#include <hip/hip_runtime.h>

// ---------------------------------------------------------------------------
// FocalAtt (CA mode): B=8, Lq=512, Lk=1024, qd=kd=768, hid=1024, mid=4096,
// H=16, dh=64. Inputs f32, outputs f32. bf16 MFMA GEMMs (16x16x32), fp32 acc.
// R7: (1) bank-conflict fix via both-sides XOR swizzle -- pre-swizzled
// global_load_lds source chunk + matching XOR on fragment ds_read (rule #21);
// (2) 3-deep pipeline with counted s_waitcnt vmcnt(6) + raw s_barrier (T4,
// never vmcnt(0) in steady state); (3) all GEMMs unified on the 128x64 body.
// Workspace peak 58,241,024 B (< known-good 58,490,880).
// ---------------------------------------------------------------------------

typedef unsigned short bfr;  // raw bf16 bits
using short8 = __attribute__((ext_vector_type(8))) short;
using f32x4  = __attribute__((ext_vector_type(4))) float;

__device__ __forceinline__ float b2f(bfr s) {
  return __uint_as_float(((unsigned int)s) << 16);
}
__device__ __forceinline__ bfr f2b(float f) {
  unsigned int u = __float_as_uint(f);
  u += 0x7fffu + ((u >> 16) & 1u);  // RNE
  return (bfr)(u >> 16);
}

struct __align__(8) us4 { bfr x, y, z, w; };

__device__ __forceinline__ float4 load4f(const float* p) { return *(const float4*)p; }
__device__ __forceinline__ float4 load4f(const bfr* p) {
  us4 u = *(const us4*)p;
  return make_float4(b2f(u.x), b2f(u.y), b2f(u.z), b2f(u.w));
}
__device__ __forceinline__ void store4(float* p, float a, float b, float c, float d) {
  *(float4*)p = make_float4(a, b, c, d);
}
__device__ __forceinline__ void store4(bfr* p, float a, float b, float c, float d) {
  us4 v; v.x = f2b(a); v.y = f2b(b); v.z = f2b(c); v.w = f2b(d);
  *(us4*)p = v;
}

// async global(bf16 x8, 16B) -> LDS at wave-uniform base + lane*16B
__device__ __forceinline__ void gll16(const bfr* g, bfr* l) {
  __builtin_amdgcn_global_load_lds(
      (const __attribute__((address_space(1))) unsigned int*)g,
      (__attribute__((address_space(3))) unsigned int*)l, 16, 0, 0);
}

// element offset into a [rows][64-bf16] tile, chunk = 16B unit 0..7,
// XOR-swizzled: slot(r,c) = r*8 + (c ^ (r&7))  (bank-conflict-free reads)
__device__ __forceinline__ int swz_off(int row, int chunk) {
  return row * 64 + ((chunk ^ (row & 7)) * 8);
}

// ---------------------------------------------------------------------------
// Positional encoding
// ---------------------------------------------------------------------------
__device__ __forceinline__ float pe_val(int l, int d) {
  float ang = (float)l * expf((float)(d & ~1) * (-9.210340371976184f / 768.0f));
  return (d & 1) ? cosf(ang) : sinf(ang);
}

// k + PE -> f32 kp (output) AND bf16 copy (GEMM operand). total = 8*1024*768
__global__ __launch_bounds__(256) void posenc_k(const float* __restrict__ in,
                                                float* __restrict__ outf,
                                                bfr* __restrict__ outb, int total) {
  int idx = blockIdx.x * 256 + threadIdx.x;
  if (idx >= total) return;
  float v = in[idx] + pe_val((idx / 768) % 1024, idx % 768);
  outf[idx] = v;
  outb[idx] = f2b(v);
}

// q + PE -> bf16 qp_all [4096,768]; plain q -> bf16 q_b16
__global__ __launch_bounds__(256) void posenc_q_all(const float* __restrict__ in,
                                                    bfr* __restrict__ out,
                                                    bfr* __restrict__ outraw,
                                                    int total) {
  int idx = blockIdx.x * 256 + threadIdx.x;
  if (idx >= total) return;
  float v = in[idx];
  out[idx] = f2b(v + pe_val((idx / 768) % 512, idx % 768));
  outraw[idx] = f2b(v);
}

// ---------------------------------------------------------------------------
// Weight transpose: src f32 [rows, cols] (row stride ld) -> dst bf16 [cols, rows]
// grid (cols/32, rows/32), 256 threads. mode: dst-row remap for interleaved
// v1|v0 stacking. 0: r=c; 1: r=(c>>6)*128+(c&63); 2: r=(c>>6)*128+64+(c&63).
// ---------------------------------------------------------------------------
__global__ __launch_bounds__(256) void transpose_w(const float* __restrict__ src,
                                                   bfr* __restrict__ dst,
                                                   int rows, int cols, int ld,
                                                   int mode) {
  __shared__ float t[32][33];
  const int bc = blockIdx.x * 32, br = blockIdx.y * 32;
  const int tx = threadIdx.x & 31, ty = threadIdx.x >> 5;  // ty 0..7
#pragma unroll
  for (int i = 0; i < 4; i++)
    t[ty + i * 8][tx] = src[(size_t)(br + ty + i * 8) * ld + bc + tx];
  __syncthreads();
#pragma unroll
  for (int i = 0; i < 4; i++) {
    int c = bc + ty + i * 8;
    int r = (mode == 0) ? c : ((c >> 6) * 128 + (c & 63) + (mode == 2 ? 64 : 0));
    dst[(size_t)r * rows + br + tx] = f2b(t[tx][ty + i * 8]);
  }
}

// ---------------------------------------------------------------------------
// MFMA GEMM body, 128x64 tile: C[M,N] = A[M,K] @ B[K,N] (+bias, relu, accum).
// B passed as BT[N,K]. 4 waves (2m x 2n), each wave 64x32 = 4x2 fragments,
// BK=64. 3-deep pipeline: issue tile t+2, MFMA tile t, s_waitcnt vmcnt(6)
// (t+2's 6 loads stay in flight; t+1 guaranteed done) + raw s_barrier.
// Staging: global_load_lds w16, linear LDS dest, pre-swizzled global source
// chunk ((lane&7)^(lane>>3)); reads apply matching XOR (conflict-free).
// A-frag: lane holds A[m=lane&15][k=(lane>>4)*8+j]; D: row=(lane>>4)*4+r,
// col=lane&15 (measured m89/m91 layouts). K % 64 == 0, NT >= 2.
// ---------------------------------------------------------------------------
template <typename TC>
__device__ __forceinline__ void mgemm_body64(const bfr* __restrict__ A,
                                             const bfr* __restrict__ BT,
                                             const float* __restrict__ bias,
                                             TC* __restrict__ C,
                                             int K, int ldc, int relu, int accum,
                                             int m0, int n0,
                                             bfr* __restrict__ As,   // [3][8192]
                                             bfr* __restrict__ Bs) { // [3][4096]
  const int tid = threadIdx.x;
  const int lane = tid & 63, w = tid >> 6;
  const int wm = (w & 1) * 64, wn = (w >> 1) * 32;
  const int grow = lane >> 3;
  const int gkc = ((lane & 7) ^ (lane >> 3)) * 8;  // pre-swizzled source chunk
  const int fr = lane & 15, fcg = lane >> 4;
  const int NT = K >> 6;
  f32x4 acc[4][2];
#pragma unroll
  for (int i = 0; i < 4; i++)
#pragma unroll
    for (int j = 0; j < 2; j++) acc[i][j] = (f32x4){0.f, 0.f, 0.f, 0.f};

  auto issue = [&](int t, int buf) {  // 6 gll16 per wave
    const int k0 = t << 6;
    const bfr* Ag = A + (size_t)(m0 + w * 32 + grow) * K + k0 + gkc;
#pragma unroll
    for (int i = 0; i < 4; i++)
      gll16(Ag + (size_t)(i * 8) * K, As + buf * 8192 + (w * 32 + i * 8) * 64);
    const bfr* Bg = BT + (size_t)(n0 + w * 16 + grow) * K + k0 + gkc;
#pragma unroll
    for (int i = 0; i < 2; i++)
      gll16(Bg + (size_t)(i * 8) * K, Bs + buf * 4096 + (w * 16 + i * 8) * 64);
  };

  issue(0, 0);
  issue(1, 1);
  asm volatile("s_waitcnt vmcnt(6)" ::: "memory");  // tile 0 landed
  __builtin_amdgcn_s_barrier();
  __builtin_amdgcn_sched_barrier(0);
  int cur = 0, ib = 2;
  for (int t = 0; t < NT; ++t) {
    if (t + 2 < NT) {
      issue(t + 2, ib);
      ib = (ib == 2) ? 0 : ib + 1;
    }
    __builtin_amdgcn_s_setprio(1);
#pragma unroll
    for (int ks = 0; ks < 2; ks++) {
      short8 af[4], bf4[2];
#pragma unroll
      for (int i = 0; i < 4; i++)
        af[i] = *(const short8*)(As + cur * 8192 + swz_off(wm + i * 16 + fr, ks * 4 + fcg));
#pragma unroll
      for (int j = 0; j < 2; j++)
        bf4[j] = *(const short8*)(Bs + cur * 4096 + swz_off(wn + j * 16 + fr, ks * 4 + fcg));
#pragma unroll
      for (int i = 0; i < 4; i++)
#pragma unroll
        for (int j = 0; j < 2; j++)
          acc[i][j] = __builtin_amdgcn_mfma_f32_16x16x32_bf16(af[i], bf4[j], acc[i][j], 0, 0, 0);
    }
    __builtin_amdgcn_s_setprio(0);
    if (t + 1 < NT) {
      if (t + 2 < NT)
        asm volatile("s_waitcnt vmcnt(6)" ::: "memory");  // t+1 done, t+2 in flight
      else
        asm volatile("s_waitcnt vmcnt(0)" ::: "memory");  // tail
      __builtin_amdgcn_s_barrier();
      __builtin_amdgcn_sched_barrier(0);
      cur = (cur == 2) ? 0 : cur + 1;
    }
  }
  const int col0 = n0 + wn + fr;
  const int row0 = m0 + wm + (lane >> 4) * 4;
  float bsv[2];
#pragma unroll
  for (int j = 0; j < 2; j++) bsv[j] = bias ? bias[col0 + j * 16] : 0.f;
#pragma unroll
  for (int i = 0; i < 4; i++) {
#pragma unroll
    for (int j = 0; j < 2; j++) {
      const int col = col0 + j * 16;
#pragma unroll
      for (int r = 0; r < 4; r++) {
        const int row = row0 + i * 16 + r;
        float v = acc[i][j][r] + bsv[j];
        if (relu) v = fmaxf(v, 0.f);
        size_t idx = (size_t)row * ldc + col;
        if constexpr (sizeof(TC) == 2) {
          C[idx] = f2b(v);
        } else {
          if (accum) C[idx] += v; else C[idx] = v;
        }
      }
    }
  }
}

// standalone 128x64-tile wrapper: 2-D grid, XCD-bijective swizzle (m204)
template <typename TC>
__global__ __launch_bounds__(256) void mgemm64(const bfr* __restrict__ A,
                                               const bfr* __restrict__ BT,
                                               const float* __restrict__ bias,
                                               TC* __restrict__ C,
                                               int K, int ldc, int relu, int accum) {
  __shared__ bfr As[3][8192];
  __shared__ bfr Bs[3][4096];
  const int nwg = gridDim.x * gridDim.y;
  const int bid = blockIdx.y * gridDim.x + blockIdx.x;
  const int q8 = nwg >> 3, r8 = nwg & 7;
  const int xcd = bid & 7, off = bid >> 3;
  const int swz = (xcd < r8 ? xcd * (q8 + 1) : r8 * (q8 + 1) + (xcd - r8) * q8) + off;
  const int n0 = (swz % gridDim.x) * 64, m0 = (swz / gridDim.x) * 128;
  mgemm_body64<TC>(A, BT, bias, C, K, ldc, relu, accum, m0, n0,
                   &As[0][0], &Bs[0][0]);
}

// batch-paired K/V projection: 768 blocks @128x64 tiles.
// blocks 0..127 kh0, 128..255 kh1, 256..511 vT0, 512..767 vT1.
__global__ __launch_bounds__(256) void kv_gemm2(const bfr* __restrict__ kp0,
                                                const bfr* __restrict__ kp1,
                                                const bfr* __restrict__ WkT,
                                                const float* __restrict__ bk,
                                                bfr* __restrict__ kh0,
                                                bfr* __restrict__ kh1,
                                                const bfr* __restrict__ WTvv,
                                                bfr* __restrict__ vT0,
                                                bfr* __restrict__ vT1) {
  __shared__ bfr As[3][8192];
  __shared__ bfr Bs[3][4096];
  const int swz = (blockIdx.x & 7) * 96 + (blockIdx.x >> 3);  // nwg=768, r8=0
  if (swz < 128) {          // kh0: M=1024 (8x128), N=1024 (16x64)
    mgemm_body64<bfr>(kp0, WkT, bk, kh0, 768, 1024, 0, 0,
                      (swz >> 4) * 128, (swz & 15) * 64, &As[0][0], &Bs[0][0]);
  } else if (swz < 256) {
    const int s = swz - 128;
    mgemm_body64<bfr>(kp1, WkT, bk, kh1, 768, 1024, 0, 0,
                      (s >> 4) * 128, (s & 15) * 64, &As[0][0], &Bs[0][0]);
  } else if (swz < 512) {   // vT0: M=2048 (16x128), N=1024 (16x64)
    const int s = swz - 256;
    mgemm_body64<bfr>(WTvv, kp0, nullptr, vT0, 768, 1024, 0, 0,
                      (s >> 4) * 128, (s & 15) * 64, &As[0][0], &Bs[0][0]);
  } else {
    const int s = swz - 512;
    mgemm_body64<bfr>(WTvv, kp1, nullptr, vT1, 768, 1024, 0, 0,
                      (s >> 4) * 128, (s & 15) * 64, &As[0][0], &Bs[0][0]);
  }
}

// fused q projections: blocks 0..511 -> q0p = q_b16@Wq0T + bq0 (32x16),
// blocks 512..1023 -> qh = qp_all@WqT + bq (32x16). 1-D grid 1024.
__global__ __launch_bounds__(256) void proj_gemm(const bfr* __restrict__ q16,
                                                 const bfr* __restrict__ Wq0T,
                                                 const float* __restrict__ bq0,
                                                 bfr* __restrict__ q0p,
                                                 const bfr* __restrict__ qp_all,
                                                 const bfr* __restrict__ WqT,
                                                 const float* __restrict__ bq,
                                                 bfr* __restrict__ qh) {
  __shared__ bfr As[3][8192];
  __shared__ bfr Bs[3][4096];
  const int swz = (blockIdx.x & 7) * 128 + (blockIdx.x >> 3);  // nwg=1024, r8=0
  if (swz < 512) {
    mgemm_body64<bfr>(q16, Wq0T, bq0, q0p, 768, 1024, 0, 0,
                      (swz >> 4) * 128, (swz & 15) * 64, &As[0][0], &Bs[0][0]);
  } else {
    const int s = swz - 512;
    mgemm_body64<bfr>(qp_all, WqT, bq, qh, 768, 1024, 0, 0,
                      (s >> 4) * 128, (s & 15) * 64, &As[0][0], &Bs[0][0]);
  }
}

// ---------------------------------------------------------------------------
// MFMA scores (one batch): sc[h,q,k] = dot_64(qh[q,h*64+:], kh[k,h*64+:]) / 8
// 128x128 tile, K=64 (two 32-steps, staged once). grid (8 kb, 4 qb, 16 h).
// ---------------------------------------------------------------------------
__global__ __launch_bounds__(256) void score_mfma(const bfr* __restrict__ qh,
                                                  const bfr* __restrict__ kh,
                                                  bfr* __restrict__ sc) {
  __shared__ __align__(16) bfr Qs[128][72];  // stride 144 B: 2-way max, free
  __shared__ __align__(16) bfr Ks[128][72];
  const int h = blockIdx.z, q0 = blockIdx.y * 128, k0 = blockIdx.x * 128;
  const int tid = threadIdx.x, lane = tid & 63;
  const int wm = ((tid >> 6) & 1) * 64, wn = (tid >> 7) * 64;
  const int fr = lane & 15, fc = (lane >> 4) * 8;
  {
    const int r = tid >> 1, c = (tid & 1) * 32;
    const bfr* qsrc = qh + (size_t)(q0 + r) * 1024 + h * 64 + c;
    const bfr* ksrc = kh + (size_t)(k0 + r) * 1024 + h * 64 + c;
#pragma unroll
    for (int i = 0; i < 4; i++) {
      *(short8*)&Qs[r][c + i * 8] = *(const short8*)(qsrc + i * 8);
      *(short8*)&Ks[r][c + i * 8] = *(const short8*)(ksrc + i * 8);
    }
  }
  __syncthreads();
  f32x4 acc[4][4];
#pragma unroll
  for (int i = 0; i < 4; i++)
#pragma unroll
    for (int j = 0; j < 4; j++) acc[i][j] = (f32x4){0.f, 0.f, 0.f, 0.f};
  __builtin_amdgcn_s_setprio(1);
#pragma unroll
  for (int ks = 0; ks < 2; ks++) {
    short8 af[4], bf[4];
#pragma unroll
    for (int t = 0; t < 4; t++) af[t] = *(const short8*)&Qs[wm + t * 16 + fr][ks * 32 + fc];
#pragma unroll
    for (int t = 0; t < 4; t++) bf[t] = *(const short8*)&Ks[wn + t * 16 + fr][ks * 32 + fc];
#pragma unroll
    for (int i = 0; i < 4; i++)
#pragma unroll
      for (int j = 0; j < 4; j++)
        acc[i][j] = __builtin_amdgcn_mfma_f32_16x16x32_bf16(af[i], bf[j], acc[i][j], 0, 0, 0);
  }
  __builtin_amdgcn_s_setprio(0);
  const int col0 = k0 + wn + fr;
  const int row0 = q0 + wm + (lane >> 4) * 4;
#pragma unroll
  for (int i = 0; i < 4; i++)
#pragma unroll
    for (int j = 0; j < 4; j++)
#pragma unroll
      for (int r = 0; r < 4; r++)
        sc[((size_t)h * 512 + row0 + i * 16 + r) * 1024 + col0 + j * 16] =
            f2b(acc[i][j][r] * 0.125f);
}

// ---------------------------------------------------------------------------
// Fused attout + softmax (one batch): block per q (512 blocks). 4 waves x 4 h
// each. Per (h,q)-row of 1024: relu-sum partial (pre-softmax) + in-place
// softmax, wave-level shfl reductions only. Cross-wave relu-sum via LDS ->
// ao[q,k] = sum_h relu(sc)/16 (f32).
// ---------------------------------------------------------------------------
__global__ __launch_bounds__(256) void smax_ao(bfr* __restrict__ sc,
                                               float* __restrict__ ao) {
  __shared__ float part[4][1024];
  const int q = blockIdx.x;
  const int tid = threadIdx.x, lane = tid & 63, w = tid >> 6;
  float aos[16];
#pragma unroll
  for (int i = 0; i < 16; i++) aos[i] = 0.f;
#pragma unroll
  for (int i = 0; i < 4; i++) {
    const int h = w * 4 + i;
    bfr* row = sc + ((size_t)h * 512 + q) * 1024 + lane * 16;
    us4 raw[4];
    float v[16];
#pragma unroll
    for (int j = 0; j < 4; j++) raw[j] = ((const us4*)row)[j];
#pragma unroll
    for (int j = 0; j < 4; j++) {
      v[j * 4 + 0] = b2f(raw[j].x); v[j * 4 + 1] = b2f(raw[j].y);
      v[j * 4 + 2] = b2f(raw[j].z); v[j * 4 + 3] = b2f(raw[j].w);
    }
    float m = v[0];
#pragma unroll
    for (int j = 1; j < 16; j++) m = fmaxf(m, v[j]);
#pragma unroll
    for (int j = 0; j < 16; j++) aos[j] += fmaxf(v[j], 0.f);
    for (int o = 32; o; o >>= 1) m = fmaxf(m, __shfl_xor(m, o, 64));
    float s = 0.f;
#pragma unroll
    for (int j = 0; j < 16; j++) { v[j] = expf(v[j] - m); s += v[j]; }
    for (int o = 32; o; o >>= 1) s += __shfl_xor(s, o, 64);
    const float inv = 1.0f / s;
#pragma unroll
    for (int j = 0; j < 4; j++) {
      raw[j].x = f2b(v[j * 4 + 0] * inv); raw[j].y = f2b(v[j * 4 + 1] * inv);
      raw[j].z = f2b(v[j * 4 + 2] * inv); raw[j].w = f2b(v[j * 4 + 3] * inv);
      ((us4*)row)[j] = raw[j];
    }
  }
#pragma unroll
  for (int j = 0; j < 4; j++)
    *(float4*)&part[w][lane * 16 + j * 4] =
        make_float4(aos[j * 4], aos[j * 4 + 1], aos[j * 4 + 2], aos[j * 4 + 3]);
  __syncthreads();
  const int k4 = tid * 4;
  float4 a0 = *(const float4*)&part[0][k4];
  float4 a1 = *(const float4*)&part[1][k4];
  float4 a2 = *(const float4*)&part[2][k4];
  float4 a3 = *(const float4*)&part[3][k4];
  store4(ao + (size_t)q * 1024 + k4,
         (a0.x + a1.x + a2.x + a3.x) * 0.0625f, (a0.y + a1.y + a2.y + a3.y) * 0.0625f,
         (a0.z + a1.z + a2.z + a3.z) * 0.0625f, (a0.w + a1.w + a2.w + a3.w) * 0.0625f);
}

// ---------------------------------------------------------------------------
// MFMA att@V (one batch): vT is [h][128 d'][1024 k] with d'<64 = v1 rows,
// d'>=64 = v0 rows. Output tile 32q x 128d' per block, grid (16 qb, 16 h),
// 4 waves (2 q-halves x {atp,u}). 3-deep pipeline, counted vmcnt(5),
// swizzled staging as in mgemm_body64. Bias exact (softmax rows sum to 1).
// ---------------------------------------------------------------------------
__global__ __launch_bounds__(256) void attv2(const bfr* __restrict__ att,
                                             const bfr* __restrict__ vT,
                                             const float* __restrict__ bv,
                                             const float* __restrict__ bv0,
                                             bfr* __restrict__ atp,
                                             bfr* __restrict__ u) {
  __shared__ bfr As[3][32 * 64];   // 12 KB
  __shared__ bfr Bs[3][128 * 64];  // 48 KB
  const int h = blockIdx.y, q0 = blockIdx.x * 32;
  const int tid = threadIdx.x, lane = tid & 63, w = tid >> 6;
  const int fr = lane & 15, fcg = lane >> 4;
  const int wm = (w & 1) * 16, wn = (w >> 1) * 64;
  const bfr* attb = att + ((size_t)h * 512 + q0) * 1024;
  const bfr* vb = vT + (size_t)h * 128 * 1024;
  const int grow = lane >> 3;
  const int gkc = ((lane & 7) ^ (lane >> 3)) * 8;  // pre-swizzled source chunk
  f32x4 acc[4];
#pragma unroll
  for (int t = 0; t < 4; t++) acc[t] = (f32x4){0.f, 0.f, 0.f, 0.f};

  auto issue = [&](int t, int buf) {  // 5 gll16 per wave
    const int k0 = t << 6;
    gll16(attb + (size_t)(w * 8 + grow) * 1024 + k0 + gkc, &As[buf][(w * 8) * 64]);
#pragma unroll
    for (int i = 0; i < 4; i++)
      gll16(vb + (size_t)(w * 32 + i * 8 + grow) * 1024 + k0 + gkc,
            &Bs[buf][(w * 32 + i * 8) * 64]);
  };

  issue(0, 0);
  issue(1, 1);
  asm volatile("s_waitcnt vmcnt(5)" ::: "memory");
  __builtin_amdgcn_s_barrier();
  __builtin_amdgcn_sched_barrier(0);
  int cur = 0, ib = 2;
  for (int t = 0; t < 16; ++t) {
    if (t + 2 < 16) {
      issue(t + 2, ib);
      ib = (ib == 2) ? 0 : ib + 1;
    }
    __builtin_amdgcn_s_setprio(1);
#pragma unroll
    for (int ks = 0; ks < 2; ks++) {
      short8 af = *(const short8*)&As[cur][swz_off(wm + fr, ks * 4 + fcg)];
#pragma unroll
      for (int j = 0; j < 4; j++) {
        short8 bf = *(const short8*)&Bs[cur][swz_off(wn + j * 16 + fr, ks * 4 + fcg)];
        acc[j] = __builtin_amdgcn_mfma_f32_16x16x32_bf16(af, bf, acc[j], 0, 0, 0);
      }
    }
    __builtin_amdgcn_s_setprio(0);
    if (t + 1 < 16) {
      if (t + 2 < 16)
        asm volatile("s_waitcnt vmcnt(5)" ::: "memory");
      else
        asm volatile("s_waitcnt vmcnt(0)" ::: "memory");
      __builtin_amdgcn_s_barrier();
      __builtin_amdgcn_sched_barrier(0);
      cur = (cur == 2) ? 0 : cur + 1;
    }
  }
  const int row0 = q0 + wm + (lane >> 4) * 4;
  bfr* o = (wn == 0) ? atp : u;
  const float* bias = (wn == 0) ? bv : bv0;
#pragma unroll
  for (int t = 0; t < 4; t++) {
    const int cm = t * 16 + fr;  // 0..63 within the selected half
    const float bb = bias[h * 64 + cm];
#pragma unroll
    for (int r = 0; r < 4; r++)
      o[(size_t)(row0 + r) * 1024 + h * 64 + cm] = f2b(acc[t][r] + bb);
  }
}

// xpre_b[c] += sum over 64 rows of q0p_b[v,c]*u_b[v,c] (per batch), grid (4,8)
__global__ __launch_bounds__(256) void xpre_kernel(const bfr* __restrict__ q0p,
                                                   const bfr* __restrict__ u,
                                                   float* __restrict__ xpre) {
  const int c = blockIdx.x * 256 + threadIdx.x;
  const int r0 = blockIdx.y * 64;
  const bfr* qp = q0p + (size_t)r0 * 1024 + c;
  const bfr* up = u + (size_t)r0 * 1024 + c;
  float s = 0.f;
#pragma unroll 8
  for (int r = 0; r < 64; r++)
    s = fmaf(b2f(qp[(size_t)r * 1024]), b2f(up[(size_t)r * 1024]), s);
  atomicAdd(&xpre[c], s);
}

// torch_ln over rows of 1024: a*(x-mean)/(sqrt(var_unbiased)+1e-6)+b, X (+Y)
template <typename TX, typename TY, typename OT>
__global__ __launch_bounds__(256) void ln_kernel(const TX* __restrict__ X,
                                                 const TY* __restrict__ Y,
                                                 const float* __restrict__ ga,
                                                 const float* __restrict__ be,
                                                 OT* __restrict__ out) {
  __shared__ float sm[4];
  const size_t row = blockIdx.x;
  const int tid = threadIdx.x;
  float4 v = load4f(X + row * 1024 + tid * 4);
  if (Y) {
    float4 w = load4f(Y + row * 1024 + tid * 4);
    v.x += w.x; v.y += w.y; v.z += w.z; v.w += w.w;
  }
  float s = v.x + v.y + v.z + v.w;
  for (int o = 32; o; o >>= 1) s += __shfl_down(s, o, 64);
  if ((tid & 63) == 0) sm[tid >> 6] = s;
  __syncthreads();
  s = sm[0] + sm[1] + sm[2] + sm[3];
  float mean = s * (1.0f / 1024.0f);
  float d0 = v.x - mean, d1 = v.y - mean, d2 = v.z - mean, d3 = v.w - mean;
  float q = d0 * d0 + d1 * d1 + d2 * d2 + d3 * d3;
  __syncthreads();
  for (int o = 32; o; o >>= 1) q += __shfl_down(q, o, 64);
  if ((tid & 63) == 0) sm[tid >> 6] = q;
  __syncthreads();
  q = sm[0] + sm[1] + sm[2] + sm[3];
  float rs = 1.0f / (sqrtf(q * (1.0f / 1023.0f)) + 1e-6f);
  float4 g = *(const float4*)(ga + tid * 4);
  float4 bb = *(const float4*)(be + tid * 4);
  store4(out + row * 1024 + tid * 4,
         g.x * d0 * rs + bb.x, g.y * d1 * rs + bb.y,
         g.z * d2 * rs + bb.z, g.w * d3 * rs + bb.w);
}

// ---------------------------------------------------------------------------
extern "C" void kernel_launch(void* const* d_in, const int* in_sizes, int n_in,
                              void* d_out, int out_size, void* d_ws, size_t ws_size,
                              hipStream_t stream) {
  (void)in_sizes; (void)n_in; (void)out_size; (void)ws_size;
  const float* q   = (const float*)d_in[0];
  const float* k   = (const float*)d_in[1];
  const float* Wq  = (const float*)d_in[2];
  const float* bq  = (const float*)d_in[3];
  const float* Wk  = (const float*)d_in[4];
  const float* bk  = (const float*)d_in[5];
  const float* Wv  = (const float*)d_in[6];
  const float* bv  = (const float*)d_in[7];
  const float* Wv0 = (const float*)d_in[8];
  const float* bv0 = (const float*)d_in[9];
  const float* Wq0 = (const float*)d_in[10];
  const float* bq0 = (const float*)d_in[11];
  const float* nqa = (const float*)d_in[12];
  const float* nqb = (const float*)d_in[13];
  const float* nxa = (const float*)d_in[14];
  const float* nxb = (const float*)d_in[15];
  const float* W1  = (const float*)d_in[16];
  const float* b1  = (const float*)d_in[17];
  const float* W2  = (const float*)d_in[18];
  const float* b2  = (const float*)d_in[19];
  const float* nsa = (const float*)d_in[20];
  const float* nsb = (const float*)d_in[21];

  float* out = (float*)d_out;
  float* x_out  = out;                       // 8,192
  float* qq_out = out + 8192;                // 4,194,304 f32 (written LAST)
  float* kp_out = out + 4202496;             // 6,291,456
  float* ao_out = out + 10493952;            // 4,194,304
  // qq_out region doubles as scratch until the final LN:
  bfr* kp16 = (bfr*)qq_out;                  // 12,582,912 B
  bfr* vT1  = kp16 + 6291456;                //  4,194,304 B (tail of qq_out)

  char* base = (char*)d_ws;
  // persistent (attention phase)
  bfr* q0p   = (bfr*)(base + 0);            // 8,388,608  [4096,1024]
  bfr* qh    = (bfr*)(base + 8388608);      // 8,388,608  [4096,1024]
  bfr* atl   = (bfr*)(base + 16777216);     // 8,388,608  [4096,1024]
  bfr* WqT   = (bfr*)(base + 25165824);     // 1,572,864  [1024,768]
  bfr* Wq0T  = (bfr*)(base + 26738688);     // 1,572,864
  bfr* WTkv  = (bfr*)(base + 28311552);     // 4,718,592  [WkT 1024; vv-interleaved 2048][768]
  float* xpre = (float*)(base + 33030144);  //    32,768  [8,1024]
  char* S = base + 33062912;                // scratch region (25,165,824 B)
  // attention-loop overlay (batch-paired)
  bfr* sc    = (bfr*)(S + 0);               // 16,777,216 [16,512,1024]
  bfr* kh0   = (bfr*)(S + 16777216);        //  2,097,152 [1024,1024]
  bfr* kh1   = (bfr*)(S + 18874368);        //  2,097,152
  bfr* vT0   = (bfr*)(S + 20971520);        //  4,194,304 [16][128][1024] v1|v0
  // atpb/ub overlay the dead kh of the same batch (kh dead after its score)
  bfr* atp0  = (bfr*)(S + 16777216);        //  1,048,576 [512,1024]
  bfr* ub0   = (bfr*)(S + 17825792);        //  1,048,576
  bfr* atp1  = (bfr*)(S + 18874368);        //  1,048,576
  bfr* ub1   = (bfr*)(S + 19922944);        //  1,048,576
  // pre-loop overlay (dead before attention buffers first written)
  bfr* qp_all = (bfr*)(S + 0);              //  6,291,456 [4096,768]
  bfr* q16    = (bfr*)(S + 6291456);        //  6,291,456 [4096,768] plain q bf16
  // FFN-phase overlay (attention buffers dead; q0p/qh dead)
  bfr* W1Tn  = (bfr*)(S + 0);               //  4,194,304 [2048,1024]
  bfr* W2Tn  = (bfr*)(S + 4194304);         //  4,194,304 [1024,2048]
  bfr* ff1n  = (bfr*)(S + 8388608);         // 16,777,216 [4096,2048]
  float* ff2a = (float*)(base + 0);         // 16,777,216 [4096,1024] f32 (over q0p/qh)

  // --- setup ---
  posenc_k<<<24576, 256, 0, stream>>>(k, kp_out, kp16, 6291456);
  posenc_q_all<<<12288, 256, 0, stream>>>(q, qp_all, q16, 3145728);
  transpose_w<<<dim3(32, 24), 256, 0, stream>>>(Wq, WqT, 768, 1024, 1024, 0);
  transpose_w<<<dim3(32, 24), 256, 0, stream>>>(Wq0, Wq0T, 768, 1024, 1024, 0);
  transpose_w<<<dim3(32, 24), 256, 0, stream>>>(Wk, WTkv, 768, 1024, 1024, 0);
  transpose_w<<<dim3(32, 24), 256, 0, stream>>>(Wv, WTkv + 786432, 768, 1024, 1024, 1);
  transpose_w<<<dim3(32, 24), 256, 0, stream>>>(Wv0, WTkv + 786432, 768, 1024, 1024, 2);

  // full-batch projections (fused, MFMA)
  proj_gemm<<<1024, 256, 0, stream>>>(q16, Wq0T, bq0, q0p, qp_all, WqT, bq, qh);
  hipMemsetAsync(xpre, 0, 32768, stream);

  // --- per-batch-pair attention ---
  for (int p = 0; p < 4; p++) {
    const int b0 = 2 * p, b1 = 2 * p + 1;
    kv_gemm2<<<768, 256, 0, stream>>>(kp16 + (size_t)b0 * 786432,
                                      kp16 + (size_t)b1 * 786432,
                                      WTkv, bk, kh0, kh1,
                                      WTkv + 786432, vT0, vT1);
    for (int j = 0; j < 2; j++) {
      const int b = b0 + j;
      bfr* kh = j ? kh1 : kh0;
      bfr* vT = j ? vT1 : vT0;
      bfr* atpb = j ? atp1 : atp0;
      bfr* ub = j ? ub1 : ub0;
      score_mfma<<<dim3(8, 4, 16), 256, 0, stream>>>(qh + (size_t)b * 524288, kh, sc);
      smax_ao<<<512, 256, 0, stream>>>(sc, ao_out + (size_t)b * 524288);
      attv2<<<dim3(16, 16), 256, 0, stream>>>(sc, vT, bv, bv0, atpb, ub);
      xpre_kernel<<<dim3(4, 8), 256, 0, stream>>>(q0p + (size_t)b * 524288, ub,
                                                  xpre + b * 1024);
      ln_kernel<bfr, bfr, bfr><<<512, 256, 0, stream>>>(
          q0p + (size_t)b * 524288, atpb, nqa, nqb, atl + (size_t)b * 524288);
    }
  }

  // x = LN(bilinear)
  ln_kernel<float, float, float><<<8, 256, 0, stream>>>(xpre, (const float*)nullptr,
                                                        nxa, nxb, x_out);

  // --- FFN, K-split into 2 chunks of 2048, f32 accumulation in ff2a ---
  for (int nc = 0; nc < 2; nc++) {
    transpose_w<<<dim3(64, 32), 256, 0, stream>>>(W1 + nc * 2048, W1Tn,
                                                  1024, 2048, 4096, 0);
    transpose_w<<<dim3(32, 64), 256, 0, stream>>>(W2 + (size_t)nc * 2048 * 1024, W2Tn,
                                                  2048, 1024, 1024, 0);
    mgemm64<bfr><<<dim3(32, 32), 256, 0, stream>>>(
        atl, W1Tn, b1 + nc * 2048, ff1n, 1024, 2048, 1, 0);
    mgemm64<float><<<dim3(16, 32), 256, 0, stream>>>(
        ff1n, W2Tn, nc == 0 ? b2 : nullptr, ff2a, 2048, 1024, 0, nc);
  }
  ln_kernel<bfr, float, float><<<4096, 256, 0, stream>>>(atl, ff2a, nsa, nsb, qq_out);
}

// Round 8
// 719.508 us; speedup vs baseline: 2.9106x; 1.0841x over previous
//
#include <hip/hip_runtime.h>

// ---------------------------------------------------------------------------
// FocalAtt (CA mode): B=8, Lq=512, Lk=1024, qd=kd=768, hid=1024, mid=4096,
// H=16, dh=64. Inputs f32, outputs f32. bf16 MFMA GEMMs (16x16x32), fp32 acc.
// R8: mgemm64 back to 2-deep (48 KB -> 3 blocks/CU) keeping the XOR swizzle
// (conflict-free) -- inter-block overlap beats pipeline depth here (m114);
// attv3 with 16-row q-tiles, grid (32,16)=512 = 2 blocks/CU; xpre/ln
// pair-merged (xpre2 / ln2), 4 fewer launches per batch-pair.
// Workspace peak 58,241,024 B (< known-good 58,490,880).
// ---------------------------------------------------------------------------

typedef unsigned short bfr;  // raw bf16 bits
using short8 = __attribute__((ext_vector_type(8))) short;
using f32x4  = __attribute__((ext_vector_type(4))) float;

__device__ __forceinline__ float b2f(bfr s) {
  return __uint_as_float(((unsigned int)s) << 16);
}
__device__ __forceinline__ bfr f2b(float f) {
  unsigned int u = __float_as_uint(f);
  u += 0x7fffu + ((u >> 16) & 1u);  // RNE
  return (bfr)(u >> 16);
}

struct __align__(8) us4 { bfr x, y, z, w; };

__device__ __forceinline__ float4 load4f(const float* p) { return *(const float4*)p; }
__device__ __forceinline__ float4 load4f(const bfr* p) {
  us4 u = *(const us4*)p;
  return make_float4(b2f(u.x), b2f(u.y), b2f(u.z), b2f(u.w));
}
__device__ __forceinline__ void store4(float* p, float a, float b, float c, float d) {
  *(float4*)p = make_float4(a, b, c, d);
}
__device__ __forceinline__ void store4(bfr* p, float a, float b, float c, float d) {
  us4 v; v.x = f2b(a); v.y = f2b(b); v.z = f2b(c); v.w = f2b(d);
  *(us4*)p = v;
}

// async global(bf16 x8, 16B) -> LDS at wave-uniform base + lane*16B
__device__ __forceinline__ void gll16(const bfr* g, bfr* l) {
  __builtin_amdgcn_global_load_lds(
      (const __attribute__((address_space(1))) unsigned int*)g,
      (__attribute__((address_space(3))) unsigned int*)l, 16, 0, 0);
}

// element offset into a [rows][64-bf16] tile, chunk = 16B unit 0..7,
// XOR-swizzled: slot(r,c) = r*8 + (c ^ (r&7))  (bank-conflict-free reads)
__device__ __forceinline__ int swz_off(int row, int chunk) {
  return row * 64 + ((chunk ^ (row & 7)) * 8);
}

// ---------------------------------------------------------------------------
// Positional encoding
// ---------------------------------------------------------------------------
__device__ __forceinline__ float pe_val(int l, int d) {
  float ang = (float)l * expf((float)(d & ~1) * (-9.210340371976184f / 768.0f));
  return (d & 1) ? cosf(ang) : sinf(ang);
}

// k + PE -> f32 kp (output) AND bf16 copy (GEMM operand). total = 8*1024*768
__global__ __launch_bounds__(256) void posenc_k(const float* __restrict__ in,
                                                float* __restrict__ outf,
                                                bfr* __restrict__ outb, int total) {
  int idx = blockIdx.x * 256 + threadIdx.x;
  if (idx >= total) return;
  float v = in[idx] + pe_val((idx / 768) % 1024, idx % 768);
  outf[idx] = v;
  outb[idx] = f2b(v);
}

// q + PE -> bf16 qp_all [4096,768]; plain q -> bf16 q_b16
__global__ __launch_bounds__(256) void posenc_q_all(const float* __restrict__ in,
                                                    bfr* __restrict__ out,
                                                    bfr* __restrict__ outraw,
                                                    int total) {
  int idx = blockIdx.x * 256 + threadIdx.x;
  if (idx >= total) return;
  float v = in[idx];
  out[idx] = f2b(v + pe_val((idx / 768) % 512, idx % 768));
  outraw[idx] = f2b(v);
}

// ---------------------------------------------------------------------------
// Weight transpose: src f32 [rows, cols] (row stride ld) -> dst bf16 [cols, rows]
// grid (cols/32, rows/32), 256 threads. mode: dst-row remap for interleaved
// v1|v0 stacking. 0: r=c; 1: r=(c>>6)*128+(c&63); 2: r=(c>>6)*128+64+(c&63).
// ---------------------------------------------------------------------------
__global__ __launch_bounds__(256) void transpose_w(const float* __restrict__ src,
                                                   bfr* __restrict__ dst,
                                                   int rows, int cols, int ld,
                                                   int mode) {
  __shared__ float t[32][33];
  const int bc = blockIdx.x * 32, br = blockIdx.y * 32;
  const int tx = threadIdx.x & 31, ty = threadIdx.x >> 5;  // ty 0..7
#pragma unroll
  for (int i = 0; i < 4; i++)
    t[ty + i * 8][tx] = src[(size_t)(br + ty + i * 8) * ld + bc + tx];
  __syncthreads();
#pragma unroll
  for (int i = 0; i < 4; i++) {
    int c = bc + ty + i * 8;
    int r = (mode == 0) ? c : ((c >> 6) * 128 + (c & 63) + (mode == 2 ? 64 : 0));
    dst[(size_t)r * rows + br + tx] = f2b(t[tx][ty + i * 8]);
  }
}

// ---------------------------------------------------------------------------
// MFMA GEMM body, 128x64 tile: C[M,N] = A[M,K] @ B[K,N] (+bias, relu, accum).
// B passed as BT[N,K]. 4 waves (2m x 2n), each wave 64x32 = 4x2 fragments,
// BK=64. 2-deep: issue(t+1, buf^1) before MFMA(t); vmcnt(0)+barrier per step.
// 48 KB LDS -> 3 blocks/CU; inter-block overlap hides the drain (m114).
// Staging: global_load_lds w16, linear LDS dest, pre-swizzled global source
// chunk ((lane&7)^(lane>>3)); reads apply matching XOR (conflict-free).
// A-frag: lane holds A[m=lane&15][k=(lane>>4)*8+j]; D: row=(lane>>4)*4+r,
// col=lane&15 (measured m89/m91 layouts). K % 64 == 0, NT >= 2.
// ---------------------------------------------------------------------------
template <typename TC>
__device__ __forceinline__ void mgemm_body64(const bfr* __restrict__ A,
                                             const bfr* __restrict__ BT,
                                             const float* __restrict__ bias,
                                             TC* __restrict__ C,
                                             int K, int ldc, int relu, int accum,
                                             int m0, int n0,
                                             bfr* __restrict__ As,   // [2][8192]
                                             bfr* __restrict__ Bs) { // [2][4096]
  const int tid = threadIdx.x;
  const int lane = tid & 63, w = tid >> 6;
  const int wm = (w & 1) * 64, wn = (w >> 1) * 32;
  const int grow = lane >> 3;
  const int gkc = ((lane & 7) ^ (lane >> 3)) * 8;  // pre-swizzled source chunk
  const int fr = lane & 15, fcg = lane >> 4;
  const int NT = K >> 6;
  f32x4 acc[4][2];
#pragma unroll
  for (int i = 0; i < 4; i++)
#pragma unroll
    for (int j = 0; j < 2; j++) acc[i][j] = (f32x4){0.f, 0.f, 0.f, 0.f};

  auto issue = [&](int t, int buf) {  // 6 gll16 per wave
    const int k0 = t << 6;
    const bfr* Ag = A + (size_t)(m0 + w * 32 + grow) * K + k0 + gkc;
#pragma unroll
    for (int i = 0; i < 4; i++)
      gll16(Ag + (size_t)(i * 8) * K, As + buf * 8192 + (w * 32 + i * 8) * 64);
    const bfr* Bg = BT + (size_t)(n0 + w * 16 + grow) * K + k0 + gkc;
#pragma unroll
    for (int i = 0; i < 2; i++)
      gll16(Bg + (size_t)(i * 8) * K, Bs + buf * 4096 + (w * 16 + i * 8) * 64);
  };

  issue(0, 0);
  asm volatile("s_waitcnt vmcnt(0)" ::: "memory");
  __builtin_amdgcn_s_barrier();
  __builtin_amdgcn_sched_barrier(0);
  int cur = 0;
  for (int t = 0; t < NT; ++t) {
    const bool more = (t + 1 < NT);
    if (more) issue(t + 1, cur ^ 1);
    __builtin_amdgcn_s_setprio(1);
#pragma unroll
    for (int ks = 0; ks < 2; ks++) {
      short8 af[4], bf4[2];
#pragma unroll
      for (int i = 0; i < 4; i++)
        af[i] = *(const short8*)(As + cur * 8192 + swz_off(wm + i * 16 + fr, ks * 4 + fcg));
#pragma unroll
      for (int j = 0; j < 2; j++)
        bf4[j] = *(const short8*)(Bs + cur * 4096 + swz_off(wn + j * 16 + fr, ks * 4 + fcg));
#pragma unroll
      for (int i = 0; i < 4; i++)
#pragma unroll
        for (int j = 0; j < 2; j++)
          acc[i][j] = __builtin_amdgcn_mfma_f32_16x16x32_bf16(af[i], bf4[j], acc[i][j], 0, 0, 0);
    }
    __builtin_amdgcn_s_setprio(0);
    if (more) {
      asm volatile("s_waitcnt vmcnt(0)" ::: "memory");
      __builtin_amdgcn_s_barrier();
      __builtin_amdgcn_sched_barrier(0);
      cur ^= 1;
    }
  }
  const int col0 = n0 + wn + fr;
  const int row0 = m0 + wm + (lane >> 4) * 4;
  float bsv[2];
#pragma unroll
  for (int j = 0; j < 2; j++) bsv[j] = bias ? bias[col0 + j * 16] : 0.f;
#pragma unroll
  for (int i = 0; i < 4; i++) {
#pragma unroll
    for (int j = 0; j < 2; j++) {
      const int col = col0 + j * 16;
#pragma unroll
      for (int r = 0; r < 4; r++) {
        const int row = row0 + i * 16 + r;
        float v = acc[i][j][r] + bsv[j];
        if (relu) v = fmaxf(v, 0.f);
        size_t idx = (size_t)row * ldc + col;
        if constexpr (sizeof(TC) == 2) {
          C[idx] = f2b(v);
        } else {
          if (accum) C[idx] += v; else C[idx] = v;
        }
      }
    }
  }
}

// standalone 128x64-tile wrapper: 2-D grid, XCD-bijective swizzle (m204)
template <typename TC>
__global__ __launch_bounds__(256) void mgemm64(const bfr* __restrict__ A,
                                               const bfr* __restrict__ BT,
                                               const float* __restrict__ bias,
                                               TC* __restrict__ C,
                                               int K, int ldc, int relu, int accum) {
  __shared__ bfr As[2][8192];
  __shared__ bfr Bs[2][4096];
  const int nwg = gridDim.x * gridDim.y;
  const int bid = blockIdx.y * gridDim.x + blockIdx.x;
  const int q8 = nwg >> 3, r8 = nwg & 7;
  const int xcd = bid & 7, off = bid >> 3;
  const int swz = (xcd < r8 ? xcd * (q8 + 1) : r8 * (q8 + 1) + (xcd - r8) * q8) + off;
  const int n0 = (swz % gridDim.x) * 64, m0 = (swz / gridDim.x) * 128;
  mgemm_body64<TC>(A, BT, bias, C, K, ldc, relu, accum, m0, n0,
                   &As[0][0], &Bs[0][0]);
}

// batch-paired K/V projection: 768 blocks @128x64 tiles.
// blocks 0..127 kh0, 128..255 kh1, 256..511 vT0, 512..767 vT1.
__global__ __launch_bounds__(256) void kv_gemm2(const bfr* __restrict__ kp0,
                                                const bfr* __restrict__ kp1,
                                                const bfr* __restrict__ WkT,
                                                const float* __restrict__ bk,
                                                bfr* __restrict__ kh0,
                                                bfr* __restrict__ kh1,
                                                const bfr* __restrict__ WTvv,
                                                bfr* __restrict__ vT0,
                                                bfr* __restrict__ vT1) {
  __shared__ bfr As[2][8192];
  __shared__ bfr Bs[2][4096];
  const int swz = (blockIdx.x & 7) * 96 + (blockIdx.x >> 3);  // nwg=768, r8=0
  if (swz < 128) {          // kh0: M=1024 (8x128), N=1024 (16x64)
    mgemm_body64<bfr>(kp0, WkT, bk, kh0, 768, 1024, 0, 0,
                      (swz >> 4) * 128, (swz & 15) * 64, &As[0][0], &Bs[0][0]);
  } else if (swz < 256) {
    const int s = swz - 128;
    mgemm_body64<bfr>(kp1, WkT, bk, kh1, 768, 1024, 0, 0,
                      (s >> 4) * 128, (s & 15) * 64, &As[0][0], &Bs[0][0]);
  } else if (swz < 512) {   // vT0: M=2048 (16x128), N=1024 (16x64)
    const int s = swz - 256;
    mgemm_body64<bfr>(WTvv, kp0, nullptr, vT0, 768, 1024, 0, 0,
                      (s >> 4) * 128, (s & 15) * 64, &As[0][0], &Bs[0][0]);
  } else {
    const int s = swz - 512;
    mgemm_body64<bfr>(WTvv, kp1, nullptr, vT1, 768, 1024, 0, 0,
                      (s >> 4) * 128, (s & 15) * 64, &As[0][0], &Bs[0][0]);
  }
}

// fused q projections: blocks 0..511 -> q0p = q_b16@Wq0T + bq0 (32x16),
// blocks 512..1023 -> qh = qp_all@WqT + bq (32x16). 1-D grid 1024.
__global__ __launch_bounds__(256) void proj_gemm(const bfr* __restrict__ q16,
                                                 const bfr* __restrict__ Wq0T,
                                                 const float* __restrict__ bq0,
                                                 bfr* __restrict__ q0p,
                                                 const bfr* __restrict__ qp_all,
                                                 const bfr* __restrict__ WqT,
                                                 const float* __restrict__ bq,
                                                 bfr* __restrict__ qh) {
  __shared__ bfr As[2][8192];
  __shared__ bfr Bs[2][4096];
  const int swz = (blockIdx.x & 7) * 128 + (blockIdx.x >> 3);  // nwg=1024, r8=0
  if (swz < 512) {
    mgemm_body64<bfr>(q16, Wq0T, bq0, q0p, 768, 1024, 0, 0,
                      (swz >> 4) * 128, (swz & 15) * 64, &As[0][0], &Bs[0][0]);
  } else {
    const int s = swz - 512;
    mgemm_body64<bfr>(qp_all, WqT, bq, qh, 768, 1024, 0, 0,
                      (s >> 4) * 128, (s & 15) * 64, &As[0][0], &Bs[0][0]);
  }
}

// ---------------------------------------------------------------------------
// MFMA scores (one batch): sc[h,q,k] = dot_64(qh[q,h*64+:], kh[k,h*64+:]) / 8
// 128x128 tile, K=64 (two 32-steps, staged once). grid (8 kb, 4 qb, 16 h).
// ---------------------------------------------------------------------------
__global__ __launch_bounds__(256) void score_mfma(const bfr* __restrict__ qh,
                                                  const bfr* __restrict__ kh,
                                                  bfr* __restrict__ sc) {
  __shared__ __align__(16) bfr Qs[128][72];  // stride 144 B: 2-way max, free
  __shared__ __align__(16) bfr Ks[128][72];
  const int h = blockIdx.z, q0 = blockIdx.y * 128, k0 = blockIdx.x * 128;
  const int tid = threadIdx.x, lane = tid & 63;
  const int wm = ((tid >> 6) & 1) * 64, wn = (tid >> 7) * 64;
  const int fr = lane & 15, fc = (lane >> 4) * 8;
  {
    const int r = tid >> 1, c = (tid & 1) * 32;
    const bfr* qsrc = qh + (size_t)(q0 + r) * 1024 + h * 64 + c;
    const bfr* ksrc = kh + (size_t)(k0 + r) * 1024 + h * 64 + c;
#pragma unroll
    for (int i = 0; i < 4; i++) {
      *(short8*)&Qs[r][c + i * 8] = *(const short8*)(qsrc + i * 8);
      *(short8*)&Ks[r][c + i * 8] = *(const short8*)(ksrc + i * 8);
    }
  }
  __syncthreads();
  f32x4 acc[4][4];
#pragma unroll
  for (int i = 0; i < 4; i++)
#pragma unroll
    for (int j = 0; j < 4; j++) acc[i][j] = (f32x4){0.f, 0.f, 0.f, 0.f};
  __builtin_amdgcn_s_setprio(1);
#pragma unroll
  for (int ks = 0; ks < 2; ks++) {
    short8 af[4], bf[4];
#pragma unroll
    for (int t = 0; t < 4; t++) af[t] = *(const short8*)&Qs[wm + t * 16 + fr][ks * 32 + fc];
#pragma unroll
    for (int t = 0; t < 4; t++) bf[t] = *(const short8*)&Ks[wn + t * 16 + fr][ks * 32 + fc];
#pragma unroll
    for (int i = 0; i < 4; i++)
#pragma unroll
      for (int j = 0; j < 4; j++)
        acc[i][j] = __builtin_amdgcn_mfma_f32_16x16x32_bf16(af[i], bf[j], acc[i][j], 0, 0, 0);
  }
  __builtin_amdgcn_s_setprio(0);
  const int col0 = k0 + wn + fr;
  const int row0 = q0 + wm + (lane >> 4) * 4;
#pragma unroll
  for (int i = 0; i < 4; i++)
#pragma unroll
    for (int j = 0; j < 4; j++)
#pragma unroll
      for (int r = 0; r < 4; r++)
        sc[((size_t)h * 512 + row0 + i * 16 + r) * 1024 + col0 + j * 16] =
            f2b(acc[i][j][r] * 0.125f);
}

// ---------------------------------------------------------------------------
// Fused attout + softmax (one batch): block per q (512 blocks). 4 waves x 4 h
// each. Per (h,q)-row of 1024: relu-sum partial (pre-softmax) + in-place
// softmax, wave-level shfl reductions only. Cross-wave relu-sum via LDS ->
// ao[q,k] = sum_h relu(sc)/16 (f32).
// ---------------------------------------------------------------------------
__global__ __launch_bounds__(256) void smax_ao(bfr* __restrict__ sc,
                                               float* __restrict__ ao) {
  __shared__ float part[4][1024];
  const int q = blockIdx.x;
  const int tid = threadIdx.x, lane = tid & 63, w = tid >> 6;
  float aos[16];
#pragma unroll
  for (int i = 0; i < 16; i++) aos[i] = 0.f;
#pragma unroll
  for (int i = 0; i < 4; i++) {
    const int h = w * 4 + i;
    bfr* row = sc + ((size_t)h * 512 + q) * 1024 + lane * 16;
    us4 raw[4];
    float v[16];
#pragma unroll
    for (int j = 0; j < 4; j++) raw[j] = ((const us4*)row)[j];
#pragma unroll
    for (int j = 0; j < 4; j++) {
      v[j * 4 + 0] = b2f(raw[j].x); v[j * 4 + 1] = b2f(raw[j].y);
      v[j * 4 + 2] = b2f(raw[j].z); v[j * 4 + 3] = b2f(raw[j].w);
    }
    float m = v[0];
#pragma unroll
    for (int j = 1; j < 16; j++) m = fmaxf(m, v[j]);
#pragma unroll
    for (int j = 0; j < 16; j++) aos[j] += fmaxf(v[j], 0.f);
    for (int o = 32; o; o >>= 1) m = fmaxf(m, __shfl_xor(m, o, 64));
    float s = 0.f;
#pragma unroll
    for (int j = 0; j < 16; j++) { v[j] = expf(v[j] - m); s += v[j]; }
    for (int o = 32; o; o >>= 1) s += __shfl_xor(s, o, 64);
    const float inv = 1.0f / s;
#pragma unroll
    for (int j = 0; j < 4; j++) {
      raw[j].x = f2b(v[j * 4 + 0] * inv); raw[j].y = f2b(v[j * 4 + 1] * inv);
      raw[j].z = f2b(v[j * 4 + 2] * inv); raw[j].w = f2b(v[j * 4 + 3] * inv);
      ((us4*)row)[j] = raw[j];
    }
  }
#pragma unroll
  for (int j = 0; j < 4; j++)
    *(float4*)&part[w][lane * 16 + j * 4] =
        make_float4(aos[j * 4], aos[j * 4 + 1], aos[j * 4 + 2], aos[j * 4 + 3]);
  __syncthreads();
  const int k4 = tid * 4;
  float4 a0 = *(const float4*)&part[0][k4];
  float4 a1 = *(const float4*)&part[1][k4];
  float4 a2 = *(const float4*)&part[2][k4];
  float4 a3 = *(const float4*)&part[3][k4];
  store4(ao + (size_t)q * 1024 + k4,
         (a0.x + a1.x + a2.x + a3.x) * 0.0625f, (a0.y + a1.y + a2.y + a3.y) * 0.0625f,
         (a0.z + a1.z + a2.z + a3.z) * 0.0625f, (a0.w + a1.w + a2.w + a3.w) * 0.0625f);
}

// ---------------------------------------------------------------------------
// MFMA att@V (one batch): vT is [h][128 d'][1024 k] with d'<64 = v1 rows,
// d'>=64 = v0 rows. Output tile 16q x 128d' per block, grid (32 qb, 16 h)
// = 512 blocks (2 blocks/CU). 4 waves split d' (32 each): w0,w1 -> atp,
// w2,w3 -> u. 2-deep pipeline, swizzled staging. Bias exact (softmax rows
// sum to 1). A (16 rows) staged by waves 0,1; B rows by owning wave.
// ---------------------------------------------------------------------------
__global__ __launch_bounds__(256) void attv3(const bfr* __restrict__ att,
                                             const bfr* __restrict__ vT,
                                             const float* __restrict__ bv,
                                             const float* __restrict__ bv0,
                                             bfr* __restrict__ atp,
                                             bfr* __restrict__ u) {
  __shared__ bfr As[2][16 * 64];   // 2x2 KB
  __shared__ bfr Bs[2][128 * 64];  // 2x16 KB  (total 36 KB)
  const int h = blockIdx.y, q0 = blockIdx.x * 16;
  const int tid = threadIdx.x, lane = tid & 63, w = tid >> 6;
  const int fr = lane & 15, fcg = lane >> 4;
  const int wn = w * 32;  // d' base for this wave
  const bfr* attb = att + ((size_t)h * 512 + q0) * 1024;
  const bfr* vb = vT + (size_t)h * 128 * 1024;
  const int grow = lane >> 3;
  const int gkc = ((lane & 7) ^ (lane >> 3)) * 8;  // pre-swizzled source chunk
  f32x4 acc[2];
#pragma unroll
  for (int j = 0; j < 2; j++) acc[j] = (f32x4){0.f, 0.f, 0.f, 0.f};

  auto issue = [&](int t, int buf) {
    const int k0 = t << 6;
    if (w < 2)  // A: 16 rows, waves 0,1 stage 8 rows each
      gll16(attb + (size_t)(w * 8 + grow) * 1024 + k0 + gkc, &As[buf][(w * 8) * 64]);
#pragma unroll
    for (int i = 0; i < 4; i++)  // B: each wave stages its own 32 d'-rows
      gll16(vb + (size_t)(wn + i * 8 + grow) * 1024 + k0 + gkc,
            &Bs[buf][(wn + i * 8) * 64]);
  };

  issue(0, 0);
  asm volatile("s_waitcnt vmcnt(0)" ::: "memory");
  __builtin_amdgcn_s_barrier();
  __builtin_amdgcn_sched_barrier(0);
  int cur = 0;
  for (int t = 0; t < 16; ++t) {
    const bool more = (t + 1 < 16);
    if (more) issue(t + 1, cur ^ 1);
    __builtin_amdgcn_s_setprio(1);
#pragma unroll
    for (int ks = 0; ks < 2; ks++) {
      short8 af = *(const short8*)&As[cur][swz_off(fr, ks * 4 + fcg)];
#pragma unroll
      for (int j = 0; j < 2; j++) {
        short8 bf = *(const short8*)&Bs[cur][swz_off(wn + j * 16 + fr, ks * 4 + fcg)];
        acc[j] = __builtin_amdgcn_mfma_f32_16x16x32_bf16(af, bf, acc[j], 0, 0, 0);
      }
    }
    __builtin_amdgcn_s_setprio(0);
    if (more) {
      asm volatile("s_waitcnt vmcnt(0)" ::: "memory");
      __builtin_amdgcn_s_barrier();
      __builtin_amdgcn_sched_barrier(0);
      cur ^= 1;
    }
  }
  const int row0 = q0 + (lane >> 4) * 4;
  bfr* o = (w < 2) ? atp : u;
  const float* bias = (w < 2) ? bv : bv0;
  const int dbase = wn & 63;  // 0 or 32 within the selected output half
#pragma unroll
  for (int j = 0; j < 2; j++) {
    const int cm = dbase + j * 16 + fr;  // 0..63
    const float bb = bias[h * 64 + cm];
#pragma unroll
    for (int r = 0; r < 4; r++)
      o[(size_t)(row0 + r) * 1024 + h * 64 + cm] = f2b(acc[j][r] + bb);
  }
}

// pair-merged xpre: grid (4,8,2). xpre[b][c] += sum_64rows q0p_b ⊙ u_b.
// u buffers are at stride 1,048,576 elements (atp0,ub0,atp1,ub1 packed).
__global__ __launch_bounds__(256) void xpre2(const bfr* __restrict__ q0p0,
                                             const bfr* __restrict__ u0,
                                             float* __restrict__ xpre0) {
  const int c = blockIdx.x * 256 + threadIdx.x;
  const int r0 = blockIdx.y * 64;
  const int j = blockIdx.z;
  const bfr* qp = q0p0 + (size_t)j * 524288 + (size_t)r0 * 1024 + c;
  const bfr* up = u0 + (size_t)j * 1048576 + (size_t)r0 * 1024 + c;
  float s = 0.f;
#pragma unroll 8
  for (int r = 0; r < 64; r++)
    s = fmaf(b2f(qp[(size_t)r * 1024]), b2f(up[(size_t)r * 1024]), s);
  atomicAdd(&xpre0[j * 1024 + c], s);
}

// ln body shared by all LN variants
template <typename OT>
__device__ __forceinline__ void ln_body(float4 v, const float* ga, const float* be,
                                        OT* outp, int tid, float* sm) {
  float s = v.x + v.y + v.z + v.w;
  for (int o = 32; o; o >>= 1) s += __shfl_down(s, o, 64);
  if ((tid & 63) == 0) sm[tid >> 6] = s;
  __syncthreads();
  s = sm[0] + sm[1] + sm[2] + sm[3];
  float mean = s * (1.0f / 1024.0f);
  float d0 = v.x - mean, d1 = v.y - mean, d2 = v.z - mean, d3 = v.w - mean;
  float q = d0 * d0 + d1 * d1 + d2 * d2 + d3 * d3;
  __syncthreads();
  for (int o = 32; o; o >>= 1) q += __shfl_down(q, o, 64);
  if ((tid & 63) == 0) sm[tid >> 6] = q;
  __syncthreads();
  q = sm[0] + sm[1] + sm[2] + sm[3];
  float rs = 1.0f / (sqrtf(q * (1.0f / 1023.0f)) + 1e-6f);
  float4 g = *(const float4*)(ga + tid * 4);
  float4 bb = *(const float4*)(be + tid * 4);
  store4(outp, g.x * d0 * rs + bb.x, g.y * d1 * rs + bb.y,
         g.z * d2 * rs + bb.z, g.w * d3 * rs + bb.w);
}

// torch_ln over rows of 1024: a*(x-mean)/(sqrt(var_unbiased)+1e-6)+b, X (+Y)
template <typename TX, typename TY, typename OT>
__global__ __launch_bounds__(256) void ln_kernel(const TX* __restrict__ X,
                                                 const TY* __restrict__ Y,
                                                 const float* __restrict__ ga,
                                                 const float* __restrict__ be,
                                                 OT* __restrict__ out) {
  __shared__ float sm[4];
  const size_t row = blockIdx.x;
  const int tid = threadIdx.x;
  float4 v = load4f(X + row * 1024 + tid * 4);
  if (Y) {
    float4 w = load4f(Y + row * 1024 + tid * 4);
    v.x += w.x; v.y += w.y; v.z += w.z; v.w += w.w;
  }
  ln_body(v, ga, be, out + row * 1024 + tid * 4, tid, sm);
}

// pair-merged attention LN: grid 1024. atl_b = LN(q0p_b + atp_b).
// atp buffers at stride 1,048,576 elements.
__global__ __launch_bounds__(256) void ln2_kernel(const bfr* __restrict__ q0p0,
                                                  const bfr* __restrict__ atp0,
                                                  const float* __restrict__ ga,
                                                  const float* __restrict__ be,
                                                  bfr* __restrict__ atl0) {
  __shared__ float sm[4];
  const int row = blockIdx.x;
  const int b = row >> 9, r = row & 511;
  const int tid = threadIdx.x;
  float4 v = load4f(q0p0 + (size_t)b * 524288 + (size_t)r * 1024 + tid * 4);
  float4 w = load4f(atp0 + (size_t)b * 1048576 + (size_t)r * 1024 + tid * 4);
  v.x += w.x; v.y += w.y; v.z += w.z; v.w += w.w;
  ln_body(v, ga, be, atl0 + (size_t)b * 524288 + (size_t)r * 1024 + tid * 4, tid, sm);
}

// ---------------------------------------------------------------------------
extern "C" void kernel_launch(void* const* d_in, const int* in_sizes, int n_in,
                              void* d_out, int out_size, void* d_ws, size_t ws_size,
                              hipStream_t stream) {
  (void)in_sizes; (void)n_in; (void)out_size; (void)ws_size;
  const float* q   = (const float*)d_in[0];
  const float* k   = (const float*)d_in[1];
  const float* Wq  = (const float*)d_in[2];
  const float* bq  = (const float*)d_in[3];
  const float* Wk  = (const float*)d_in[4];
  const float* bk  = (const float*)d_in[5];
  const float* Wv  = (const float*)d_in[6];
  const float* bv  = (const float*)d_in[7];
  const float* Wv0 = (const float*)d_in[8];
  const float* bv0 = (const float*)d_in[9];
  const float* Wq0 = (const float*)d_in[10];
  const float* bq0 = (const float*)d_in[11];
  const float* nqa = (const float*)d_in[12];
  const float* nqb = (const float*)d_in[13];
  const float* nxa = (const float*)d_in[14];
  const float* nxb = (const float*)d_in[15];
  const float* W1  = (const float*)d_in[16];
  const float* b1  = (const float*)d_in[17];
  const float* W2  = (const float*)d_in[18];
  const float* b2  = (const float*)d_in[19];
  const float* nsa = (const float*)d_in[20];
  const float* nsb = (const float*)d_in[21];

  float* out = (float*)d_out;
  float* x_out  = out;                       // 8,192
  float* qq_out = out + 8192;                // 4,194,304 f32 (written LAST)
  float* kp_out = out + 4202496;             // 6,291,456
  float* ao_out = out + 10493952;            // 4,194,304
  // qq_out region doubles as scratch until the final LN:
  bfr* kp16 = (bfr*)qq_out;                  // 12,582,912 B
  bfr* vT1  = kp16 + 6291456;                //  4,194,304 B (tail of qq_out)

  char* base = (char*)d_ws;
  // persistent (attention phase)
  bfr* q0p   = (bfr*)(base + 0);            // 8,388,608  [4096,1024]
  bfr* qh    = (bfr*)(base + 8388608);      // 8,388,608  [4096,1024]
  bfr* atl   = (bfr*)(base + 16777216);     // 8,388,608  [4096,1024]
  bfr* WqT   = (bfr*)(base + 25165824);     // 1,572,864  [1024,768]
  bfr* Wq0T  = (bfr*)(base + 26738688);     // 1,572,864
  bfr* WTkv  = (bfr*)(base + 28311552);     // 4,718,592  [WkT 1024; vv-interleaved 2048][768]
  float* xpre = (float*)(base + 33030144);  //    32,768  [8,1024]
  char* S = base + 33062912;                // scratch region (25,165,824 B)
  // attention-loop overlay (batch-paired)
  bfr* sc    = (bfr*)(S + 0);               // 16,777,216 [16,512,1024]
  bfr* kh0   = (bfr*)(S + 16777216);        //  2,097,152 [1024,1024]
  bfr* kh1   = (bfr*)(S + 18874368);        //  2,097,152
  bfr* vT0   = (bfr*)(S + 20971520);        //  4,194,304 [16][128][1024] v1|v0
  // atpb/ub overlay the dead kh of the same batch (kh dead after its score)
  bfr* atp0  = (bfr*)(S + 16777216);        //  1,048,576 [512,1024]
  bfr* ub0   = (bfr*)(S + 17825792);        //  1,048,576
  bfr* atp1  = (bfr*)(S + 18874368);        //  1,048,576
  bfr* ub1   = (bfr*)(S + 19922944);        //  1,048,576
  // pre-loop overlay (dead before attention buffers first written)
  bfr* qp_all = (bfr*)(S + 0);              //  6,291,456 [4096,768]
  bfr* q16    = (bfr*)(S + 6291456);        //  6,291,456 [4096,768] plain q bf16
  // FFN-phase overlay (attention buffers dead; q0p/qh dead)
  bfr* W1Tn  = (bfr*)(S + 0);               //  4,194,304 [2048,1024]
  bfr* W2Tn  = (bfr*)(S + 4194304);         //  4,194,304 [1024,2048]
  bfr* ff1n  = (bfr*)(S + 8388608);         // 16,777,216 [4096,2048]
  float* ff2a = (float*)(base + 0);         // 16,777,216 [4096,1024] f32 (over q0p/qh)

  // --- setup ---
  posenc_k<<<24576, 256, 0, stream>>>(k, kp_out, kp16, 6291456);
  posenc_q_all<<<12288, 256, 0, stream>>>(q, qp_all, q16, 3145728);
  transpose_w<<<dim3(32, 24), 256, 0, stream>>>(Wq, WqT, 768, 1024, 1024, 0);
  transpose_w<<<dim3(32, 24), 256, 0, stream>>>(Wq0, Wq0T, 768, 1024, 1024, 0);
  transpose_w<<<dim3(32, 24), 256, 0, stream>>>(Wk, WTkv, 768, 1024, 1024, 0);
  transpose_w<<<dim3(32, 24), 256, 0, stream>>>(Wv, WTkv + 786432, 768, 1024, 1024, 1);
  transpose_w<<<dim3(32, 24), 256, 0, stream>>>(Wv0, WTkv + 786432, 768, 1024, 1024, 2);

  // full-batch projections (fused, MFMA)
  proj_gemm<<<1024, 256, 0, stream>>>(q16, Wq0T, bq0, q0p, qp_all, WqT, bq, qh);
  hipMemsetAsync(xpre, 0, 32768, stream);

  // --- per-batch-pair attention ---
  for (int p = 0; p < 4; p++) {
    const int b0 = 2 * p;
    kv_gemm2<<<768, 256, 0, stream>>>(kp16 + (size_t)b0 * 786432,
                                      kp16 + (size_t)(b0 + 1) * 786432,
                                      WTkv, bk, kh0, kh1,
                                      WTkv + 786432, vT0, vT1);
    for (int j = 0; j < 2; j++) {
      const int b = b0 + j;
      bfr* kh = j ? kh1 : kh0;
      bfr* vT = j ? vT1 : vT0;
      bfr* atpb = j ? atp1 : atp0;
      bfr* ub = j ? ub1 : ub0;
      score_mfma<<<dim3(8, 4, 16), 256, 0, stream>>>(qh + (size_t)b * 524288, kh, sc);
      smax_ao<<<512, 256, 0, stream>>>(sc, ao_out + (size_t)b * 524288);
      attv3<<<dim3(32, 16), 256, 0, stream>>>(sc, vT, bv, bv0, atpb, ub);
    }
    xpre2<<<dim3(4, 8, 2), 256, 0, stream>>>(q0p + (size_t)b0 * 524288, ub0,
                                             xpre + b0 * 1024);
    ln2_kernel<<<1024, 256, 0, stream>>>(q0p + (size_t)b0 * 524288, atp0,
                                         nqa, nqb, atl + (size_t)b0 * 524288);
  }

  // x = LN(bilinear)
  ln_kernel<float, float, float><<<8, 256, 0, stream>>>(xpre, (const float*)nullptr,
                                                        nxa, nxb, x_out);

  // --- FFN, K-split into 2 chunks of 2048, f32 accumulation in ff2a ---
  for (int nc = 0; nc < 2; nc++) {
    transpose_w<<<dim3(64, 32), 256, 0, stream>>>(W1 + nc * 2048, W1Tn,
                                                  1024, 2048, 4096, 0);
    transpose_w<<<dim3(32, 64), 256, 0, stream>>>(W2 + (size_t)nc * 2048 * 1024, W2Tn,
                                                  2048, 1024, 1024, 0);
    mgemm64<bfr><<<dim3(32, 32), 256, 0, stream>>>(
        atl, W1Tn, b1 + nc * 2048, ff1n, 1024, 2048, 1, 0);
    mgemm64<float><<<dim3(16, 32), 256, 0, stream>>>(
        ff1n, W2Tn, nc == 0 ? b2 : nullptr, ff2a, 2048, 1024, 0, nc);
  }
  ln_kernel<bfr, float, float><<<4096, 256, 0, stream>>>(atl, ff2a, nsa, nsb, qq_out);
}

// Round 10
// 713.363 us; speedup vs baseline: 2.9357x; 1.0086x over previous
//
#include <hip/hip_runtime.h>

// ---------------------------------------------------------------------------
// FocalAtt (CA mode): B=8, Lq=512, Lk=1024, qd=kd=768, hid=1024, mid=4096,
// H=16, dh=64. Inputs f32, outputs f32. bf16 MFMA GEMMs (16x16x32), fp32 acc.
// R9 (resubmit; previous run died on container-acquire infra failure):
// softmax fused into PV (attv4: in-register row softmax -> padded LDS P
// tile -> PV loop; V tile-0 prefetch hidden under softmax). smax_ao replaced
// by ao-only attout8. sc is now written once, read twice (was w1+rw+r).
// Workspace peak 58,241,024 B (< known-good 58,490,880).
// ---------------------------------------------------------------------------

typedef unsigned short bfr;  // raw bf16 bits
using short8 = __attribute__((ext_vector_type(8))) short;
using f32x4  = __attribute__((ext_vector_type(4))) float;

__device__ __forceinline__ float b2f(bfr s) {
  return __uint_as_float(((unsigned int)s) << 16);
}
__device__ __forceinline__ bfr f2b(float f) {
  unsigned int u = __float_as_uint(f);
  u += 0x7fffu + ((u >> 16) & 1u);  // RNE
  return (bfr)(u >> 16);
}

struct __align__(8) us4 { bfr x, y, z, w; };

__device__ __forceinline__ float4 load4f(const float* p) { return *(const float4*)p; }
__device__ __forceinline__ float4 load4f(const bfr* p) {
  us4 u = *(const us4*)p;
  return make_float4(b2f(u.x), b2f(u.y), b2f(u.z), b2f(u.w));
}
__device__ __forceinline__ void store4(float* p, float a, float b, float c, float d) {
  *(float4*)p = make_float4(a, b, c, d);
}
__device__ __forceinline__ void store4(bfr* p, float a, float b, float c, float d) {
  us4 v; v.x = f2b(a); v.y = f2b(b); v.z = f2b(c); v.w = f2b(d);
  *(us4*)p = v;
}

// async global(bf16 x8, 16B) -> LDS at wave-uniform base + lane*16B
__device__ __forceinline__ void gll16(const bfr* g, bfr* l) {
  __builtin_amdgcn_global_load_lds(
      (const __attribute__((address_space(1))) unsigned int*)g,
      (__attribute__((address_space(3))) unsigned int*)l, 16, 0, 0);
}

// element offset into a [rows][64-bf16] tile, chunk = 16B unit 0..7,
// XOR-swizzled: slot(r,c) = r*8 + (c ^ (r&7))  (bank-conflict-free reads)
__device__ __forceinline__ int swz_off(int row, int chunk) {
  return row * 64 + ((chunk ^ (row & 7)) * 8);
}

// ---------------------------------------------------------------------------
// Positional encoding
// ---------------------------------------------------------------------------
__device__ __forceinline__ float pe_val(int l, int d) {
  float ang = (float)l * expf((float)(d & ~1) * (-9.210340371976184f / 768.0f));
  return (d & 1) ? cosf(ang) : sinf(ang);
}

// k + PE -> f32 kp (output) AND bf16 copy (GEMM operand). total = 8*1024*768
__global__ __launch_bounds__(256) void posenc_k(const float* __restrict__ in,
                                                float* __restrict__ outf,
                                                bfr* __restrict__ outb, int total) {
  int idx = blockIdx.x * 256 + threadIdx.x;
  if (idx >= total) return;
  float v = in[idx] + pe_val((idx / 768) % 1024, idx % 768);
  outf[idx] = v;
  outb[idx] = f2b(v);
}

// q + PE -> bf16 qp_all [4096,768]; plain q -> bf16 q_b16
__global__ __launch_bounds__(256) void posenc_q_all(const float* __restrict__ in,
                                                    bfr* __restrict__ out,
                                                    bfr* __restrict__ outraw,
                                                    int total) {
  int idx = blockIdx.x * 256 + threadIdx.x;
  if (idx >= total) return;
  float v = in[idx];
  out[idx] = f2b(v + pe_val((idx / 768) % 512, idx % 768));
  outraw[idx] = f2b(v);
}

// ---------------------------------------------------------------------------
// Weight transpose: src f32 [rows, cols] (row stride ld) -> dst bf16 [cols, rows]
// grid (cols/32, rows/32), 256 threads. mode: dst-row remap for interleaved
// v1|v0 stacking. 0: r=c; 1: r=(c>>6)*128+(c&63); 2: r=(c>>6)*128+64+(c&63).
// ---------------------------------------------------------------------------
__global__ __launch_bounds__(256) void transpose_w(const float* __restrict__ src,
                                                   bfr* __restrict__ dst,
                                                   int rows, int cols, int ld,
                                                   int mode) {
  __shared__ float t[32][33];
  const int bc = blockIdx.x * 32, br = blockIdx.y * 32;
  const int tx = threadIdx.x & 31, ty = threadIdx.x >> 5;  // ty 0..7
#pragma unroll
  for (int i = 0; i < 4; i++)
    t[ty + i * 8][tx] = src[(size_t)(br + ty + i * 8) * ld + bc + tx];
  __syncthreads();
#pragma unroll
  for (int i = 0; i < 4; i++) {
    int c = bc + ty + i * 8;
    int r = (mode == 0) ? c : ((c >> 6) * 128 + (c & 63) + (mode == 2 ? 64 : 0));
    dst[(size_t)r * rows + br + tx] = f2b(t[tx][ty + i * 8]);
  }
}

// ---------------------------------------------------------------------------
// MFMA GEMM body, 128x64 tile: C[M,N] = A[M,K] @ B[K,N] (+bias, relu, accum).
// B passed as BT[N,K]. 4 waves (2m x 2n), each wave 64x32 = 4x2 fragments,
// BK=64. 2-deep: issue(t+1, buf^1) before MFMA(t); vmcnt(0)+barrier per step.
// 48 KB LDS -> 3 blocks/CU; inter-block overlap hides the drain (m114).
// Staging: global_load_lds w16, linear LDS dest, pre-swizzled global source
// chunk ((lane&7)^(lane>>3)); reads apply matching XOR (conflict-free).
// A-frag: lane holds A[m=lane&15][k=(lane>>4)*8+j]; D: row=(lane>>4)*4+r,
// col=lane&15 (measured m89/m91 layouts). K % 64 == 0, NT >= 2.
// ---------------------------------------------------------------------------
template <typename TC>
__device__ __forceinline__ void mgemm_body64(const bfr* __restrict__ A,
                                             const bfr* __restrict__ BT,
                                             const float* __restrict__ bias,
                                             TC* __restrict__ C,
                                             int K, int ldc, int relu, int accum,
                                             int m0, int n0,
                                             bfr* __restrict__ As,   // [2][8192]
                                             bfr* __restrict__ Bs) { // [2][4096]
  const int tid = threadIdx.x;
  const int lane = tid & 63, w = tid >> 6;
  const int wm = (w & 1) * 64, wn = (w >> 1) * 32;
  const int grow = lane >> 3;
  const int gkc = ((lane & 7) ^ (lane >> 3)) * 8;  // pre-swizzled source chunk
  const int fr = lane & 15, fcg = lane >> 4;
  const int NT = K >> 6;
  f32x4 acc[4][2];
#pragma unroll
  for (int i = 0; i < 4; i++)
#pragma unroll
    for (int j = 0; j < 2; j++) acc[i][j] = (f32x4){0.f, 0.f, 0.f, 0.f};

  auto issue = [&](int t, int buf) {  // 6 gll16 per wave
    const int k0 = t << 6;
    const bfr* Ag = A + (size_t)(m0 + w * 32 + grow) * K + k0 + gkc;
#pragma unroll
    for (int i = 0; i < 4; i++)
      gll16(Ag + (size_t)(i * 8) * K, As + buf * 8192 + (w * 32 + i * 8) * 64);
    const bfr* Bg = BT + (size_t)(n0 + w * 16 + grow) * K + k0 + gkc;
#pragma unroll
    for (int i = 0; i < 2; i++)
      gll16(Bg + (size_t)(i * 8) * K, Bs + buf * 4096 + (w * 16 + i * 8) * 64);
  };

  issue(0, 0);
  asm volatile("s_waitcnt vmcnt(0)" ::: "memory");
  __builtin_amdgcn_s_barrier();
  __builtin_amdgcn_sched_barrier(0);
  int cur = 0;
  for (int t = 0; t < NT; ++t) {
    const bool more = (t + 1 < NT);
    if (more) issue(t + 1, cur ^ 1);
    __builtin_amdgcn_s_setprio(1);
#pragma unroll
    for (int ks = 0; ks < 2; ks++) {
      short8 af[4], bf4[2];
#pragma unroll
      for (int i = 0; i < 4; i++)
        af[i] = *(const short8*)(As + cur * 8192 + swz_off(wm + i * 16 + fr, ks * 4 + fcg));
#pragma unroll
      for (int j = 0; j < 2; j++)
        bf4[j] = *(const short8*)(Bs + cur * 4096 + swz_off(wn + j * 16 + fr, ks * 4 + fcg));
#pragma unroll
      for (int i = 0; i < 4; i++)
#pragma unroll
        for (int j = 0; j < 2; j++)
          acc[i][j] = __builtin_amdgcn_mfma_f32_16x16x32_bf16(af[i], bf4[j], acc[i][j], 0, 0, 0);
    }
    __builtin_amdgcn_s_setprio(0);
    if (more) {
      asm volatile("s_waitcnt vmcnt(0)" ::: "memory");
      __builtin_amdgcn_s_barrier();
      __builtin_amdgcn_sched_barrier(0);
      cur ^= 1;
    }
  }
  const int col0 = n0 + wn + fr;
  const int row0 = m0 + wm + (lane >> 4) * 4;
  float bsv[2];
#pragma unroll
  for (int j = 0; j < 2; j++) bsv[j] = bias ? bias[col0 + j * 16] : 0.f;
#pragma unroll
  for (int i = 0; i < 4; i++) {
#pragma unroll
    for (int j = 0; j < 2; j++) {
      const int col = col0 + j * 16;
#pragma unroll
      for (int r = 0; r < 4; r++) {
        const int row = row0 + i * 16 + r;
        float v = acc[i][j][r] + bsv[j];
        if (relu) v = fmaxf(v, 0.f);
        size_t idx = (size_t)row * ldc + col;
        if constexpr (sizeof(TC) == 2) {
          C[idx] = f2b(v);
        } else {
          if (accum) C[idx] += v; else C[idx] = v;
        }
      }
    }
  }
}

// standalone 128x64-tile wrapper: 2-D grid, XCD-bijective swizzle (m204)
template <typename TC>
__global__ __launch_bounds__(256) void mgemm64(const bfr* __restrict__ A,
                                               const bfr* __restrict__ BT,
                                               const float* __restrict__ bias,
                                               TC* __restrict__ C,
                                               int K, int ldc, int relu, int accum) {
  __shared__ bfr As[2][8192];
  __shared__ bfr Bs[2][4096];
  const int nwg = gridDim.x * gridDim.y;
  const int bid = blockIdx.y * gridDim.x + blockIdx.x;
  const int q8 = nwg >> 3, r8 = nwg & 7;
  const int xcd = bid & 7, off = bid >> 3;
  const int swz = (xcd < r8 ? xcd * (q8 + 1) : r8 * (q8 + 1) + (xcd - r8) * q8) + off;
  const int n0 = (swz % gridDim.x) * 64, m0 = (swz / gridDim.x) * 128;
  mgemm_body64<TC>(A, BT, bias, C, K, ldc, relu, accum, m0, n0,
                   &As[0][0], &Bs[0][0]);
}

// batch-paired K/V projection: 768 blocks @128x64 tiles.
// blocks 0..127 kh0, 128..255 kh1, 256..511 vT0, 512..767 vT1.
__global__ __launch_bounds__(256) void kv_gemm2(const bfr* __restrict__ kp0,
                                                const bfr* __restrict__ kp1,
                                                const bfr* __restrict__ WkT,
                                                const float* __restrict__ bk,
                                                bfr* __restrict__ kh0,
                                                bfr* __restrict__ kh1,
                                                const bfr* __restrict__ WTvv,
                                                bfr* __restrict__ vT0,
                                                bfr* __restrict__ vT1) {
  __shared__ bfr As[2][8192];
  __shared__ bfr Bs[2][4096];
  const int swz = (blockIdx.x & 7) * 96 + (blockIdx.x >> 3);  // nwg=768, r8=0
  if (swz < 128) {          // kh0: M=1024 (8x128), N=1024 (16x64)
    mgemm_body64<bfr>(kp0, WkT, bk, kh0, 768, 1024, 0, 0,
                      (swz >> 4) * 128, (swz & 15) * 64, &As[0][0], &Bs[0][0]);
  } else if (swz < 256) {
    const int s = swz - 128;
    mgemm_body64<bfr>(kp1, WkT, bk, kh1, 768, 1024, 0, 0,
                      (s >> 4) * 128, (s & 15) * 64, &As[0][0], &Bs[0][0]);
  } else if (swz < 512) {   // vT0: M=2048 (16x128), N=1024 (16x64)
    const int s = swz - 256;
    mgemm_body64<bfr>(WTvv, kp0, nullptr, vT0, 768, 1024, 0, 0,
                      (s >> 4) * 128, (s & 15) * 64, &As[0][0], &Bs[0][0]);
  } else {
    const int s = swz - 512;
    mgemm_body64<bfr>(WTvv, kp1, nullptr, vT1, 768, 1024, 0, 0,
                      (s >> 4) * 128, (s & 15) * 64, &As[0][0], &Bs[0][0]);
  }
}

// fused q projections: blocks 0..511 -> q0p = q_b16@Wq0T + bq0 (32x16),
// blocks 512..1023 -> qh = qp_all@WqT + bq (32x16). 1-D grid 1024.
__global__ __launch_bounds__(256) void proj_gemm(const bfr* __restrict__ q16,
                                                 const bfr* __restrict__ Wq0T,
                                                 const float* __restrict__ bq0,
                                                 bfr* __restrict__ q0p,
                                                 const bfr* __restrict__ qp_all,
                                                 const bfr* __restrict__ WqT,
                                                 const float* __restrict__ bq,
                                                 bfr* __restrict__ qh) {
  __shared__ bfr As[2][8192];
  __shared__ bfr Bs[2][4096];
  const int swz = (blockIdx.x & 7) * 128 + (blockIdx.x >> 3);  // nwg=1024, r8=0
  if (swz < 512) {
    mgemm_body64<bfr>(q16, Wq0T, bq0, q0p, 768, 1024, 0, 0,
                      (swz >> 4) * 128, (swz & 15) * 64, &As[0][0], &Bs[0][0]);
  } else {
    const int s = swz - 512;
    mgemm_body64<bfr>(qp_all, WqT, bq, qh, 768, 1024, 0, 0,
                      (s >> 4) * 128, (s & 15) * 64, &As[0][0], &Bs[0][0]);
  }
}

// ---------------------------------------------------------------------------
// MFMA scores (one batch): sc[h,q,k] = dot_64(qh[q,h*64+:], kh[k,h*64+:]) / 8
// 128x128 tile, K=64 (two 32-steps, staged once). grid (8 kb, 4 qb, 16 h).
// ---------------------------------------------------------------------------
__global__ __launch_bounds__(256) void score_mfma(const bfr* __restrict__ qh,
                                                  const bfr* __restrict__ kh,
                                                  bfr* __restrict__ sc) {
  __shared__ __align__(16) bfr Qs[128][72];  // stride 144 B: 2-way max, free
  __shared__ __align__(16) bfr Ks[128][72];
  const int h = blockIdx.z, q0 = blockIdx.y * 128, k0 = blockIdx.x * 128;
  const int tid = threadIdx.x, lane = tid & 63;
  const int wm = ((tid >> 6) & 1) * 64, wn = (tid >> 7) * 64;
  const int fr = lane & 15, fc = (lane >> 4) * 8;
  {
    const int r = tid >> 1, c = (tid & 1) * 32;
    const bfr* qsrc = qh + (size_t)(q0 + r) * 1024 + h * 64 + c;
    const bfr* ksrc = kh + (size_t)(k0 + r) * 1024 + h * 64 + c;
#pragma unroll
    for (int i = 0; i < 4; i++) {
      *(short8*)&Qs[r][c + i * 8] = *(const short8*)(qsrc + i * 8);
      *(short8*)&Ks[r][c + i * 8] = *(const short8*)(ksrc + i * 8);
    }
  }
  __syncthreads();
  f32x4 acc[4][4];
#pragma unroll
  for (int i = 0; i < 4; i++)
#pragma unroll
    for (int j = 0; j < 4; j++) acc[i][j] = (f32x4){0.f, 0.f, 0.f, 0.f};
  __builtin_amdgcn_s_setprio(1);
#pragma unroll
  for (int ks = 0; ks < 2; ks++) {
    short8 af[4], bf[4];
#pragma unroll
    for (int t = 0; t < 4; t++) af[t] = *(const short8*)&Qs[wm + t * 16 + fr][ks * 32 + fc];
#pragma unroll
    for (int t = 0; t < 4; t++) bf[t] = *(const short8*)&Ks[wn + t * 16 + fr][ks * 32 + fc];
#pragma unroll
    for (int i = 0; i < 4; i++)
#pragma unroll
      for (int j = 0; j < 4; j++)
        acc[i][j] = __builtin_amdgcn_mfma_f32_16x16x32_bf16(af[i], bf[j], acc[i][j], 0, 0, 0);
  }
  __builtin_amdgcn_s_setprio(0);
  const int col0 = k0 + wn + fr;
  const int row0 = q0 + wm + (lane >> 4) * 4;
#pragma unroll
  for (int i = 0; i < 4; i++)
#pragma unroll
    for (int j = 0; j < 4; j++)
#pragma unroll
      for (int r = 0; r < 4; r++)
        sc[((size_t)h * 512 + row0 + i * 16 + r) * 1024 + col0 + j * 16] =
            f2b(acc[i][j][r] * 0.125f);
}

// ao-only pass: ao[q,k] = sum_h relu(sc[h,q,k])/16 (pre-softmax, f32 out).
// grid 256, 8 elems/thread.
__global__ __launch_bounds__(256) void attout8(const bfr* __restrict__ sc,
                                               float* __restrict__ ao) {
  const int i8 = (blockIdx.x * 256 + threadIdx.x) * 8;  // < 524288
  float s[8] = {};
#pragma unroll
  for (int h = 0; h < 16; h++) {
    short8 r = *(const short8*)(sc + (size_t)h * 524288 + i8);
#pragma unroll
    for (int e = 0; e < 8; e++) s[e] += fmaxf(b2f((bfr)r[e]), 0.f);
  }
  store4(ao + i8, s[0] * 0.0625f, s[1] * 0.0625f, s[2] * 0.0625f, s[3] * 0.0625f);
  store4(ao + i8 + 4, s[4] * 0.0625f, s[5] * 0.0625f, s[6] * 0.0625f, s[7] * 0.0625f);
}

// ---------------------------------------------------------------------------
// Fused softmax + att@V (one batch): block (qb of 16 rows, h), grid (32,16).
// Phase 1: read PRE-softmax sc rows (64 vals/thread, 16 thr/row), f32
// max/exp/sum via 16-lane shfl, write normalized bf16 P into padded LDS
// [16][1032] (pad 8 -> 4-bank row rotation, A-frag reads conflict-free).
// Phase 2 = PV: 4 waves split d' (32 each): w0,w1 -> atp(+bv), w2,w3 ->
// u(+bv0); V dbuf via swizzled gll16, 2-deep. V tile 0 issued BEFORE
// phase 1 (latency hidden under softmax). Bias exact (rows sum to 1).
// LDS total 65,792 B static -- legal on gfx950 (160 KiB/workgroup).
// ---------------------------------------------------------------------------
__global__ __launch_bounds__(256) void attv4(const bfr* __restrict__ sc,
                                             const bfr* __restrict__ vT,
                                             const float* __restrict__ bv,
                                             const float* __restrict__ bv0,
                                             bfr* __restrict__ atp,
                                             bfr* __restrict__ u) {
  __shared__ bfr attL[16][1032];   // 33 KB, row stride 2064 B
  __shared__ bfr Bs[2][128 * 64];  // 32 KB
  const int h = blockIdx.y, q0 = blockIdx.x * 16;
  const int tid = threadIdx.x, lane = tid & 63, w = tid >> 6;
  const int fr = lane & 15, fcg = lane >> 4;
  const int wn = w * 32;  // d' base for this wave
  const bfr* vb = vT + (size_t)h * 128 * 1024;
  const int grow = lane >> 3;
  const int gkc = ((lane & 7) ^ (lane >> 3)) * 8;  // pre-swizzled source chunk

  auto issueV = [&](int t, int buf) {
    const int k0 = t << 6;
#pragma unroll
    for (int i = 0; i < 4; i++)
      gll16(vb + (size_t)(wn + i * 8 + grow) * 1024 + k0 + gkc,
            &Bs[buf][(wn + i * 8) * 64]);
  };

  issueV(0, 0);  // V tile 0 in flight during softmax

  // ---- phase 1: softmax over the 1024-wide row q0+row ----
  const int row = tid >> 4, seg = tid & 15;
  const bfr* srow = sc + ((size_t)h * 512 + q0 + row) * 1024;
  short8 raw[8];
#pragma unroll
  for (int j = 0; j < 8; j++)
    raw[j] = *(const short8*)(srow + j * 128 + seg * 8);
  float v[64];
#pragma unroll
  for (int j = 0; j < 8; j++)
#pragma unroll
    for (int e = 0; e < 8; e++)
      v[j * 8 + e] = b2f((bfr)raw[j][e]);
  float m = v[0];
#pragma unroll
  for (int i = 1; i < 64; i++) m = fmaxf(m, v[i]);
#pragma unroll
  for (int o = 1; o < 16; o <<= 1) m = fmaxf(m, __shfl_xor(m, o, 64));
  float s = 0.f;
#pragma unroll
  for (int i = 0; i < 64; i++) { v[i] = expf(v[i] - m); s += v[i]; }
#pragma unroll
  for (int o = 1; o < 16; o <<= 1) s += __shfl_xor(s, o, 64);
  const float inv = 1.0f / s;
#pragma unroll
  for (int j = 0; j < 8; j++) {
    short8 pw;
#pragma unroll
    for (int e = 0; e < 8; e++) pw[e] = (short)f2b(v[j * 8 + e] * inv);
    *(short8*)&attL[row][j * 128 + seg * 8] = pw;
  }
  asm volatile("s_waitcnt vmcnt(0)" ::: "memory");  // V tile 0 landed
  __syncthreads();                                  // attL visible

  // ---- phase 2: PV ----
  f32x4 acc[2];
#pragma unroll
  for (int j = 0; j < 2; j++) acc[j] = (f32x4){0.f, 0.f, 0.f, 0.f};
  int cur = 0;
  for (int t = 0; t < 16; ++t) {
    const bool more = (t + 1 < 16);
    if (more) issueV(t + 1, cur ^ 1);
    __builtin_amdgcn_s_setprio(1);
#pragma unroll
    for (int ks = 0; ks < 2; ks++) {
      short8 af = *(const short8*)&attL[fr][(t << 6) + ks * 32 + fcg * 8];
#pragma unroll
      for (int j = 0; j < 2; j++) {
        short8 bf = *(const short8*)&Bs[cur][swz_off(wn + j * 16 + fr, ks * 4 + fcg)];
        acc[j] = __builtin_amdgcn_mfma_f32_16x16x32_bf16(af, bf, acc[j], 0, 0, 0);
      }
    }
    __builtin_amdgcn_s_setprio(0);
    if (more) {
      asm volatile("s_waitcnt vmcnt(0)" ::: "memory");
      __builtin_amdgcn_s_barrier();
      __builtin_amdgcn_sched_barrier(0);
      cur ^= 1;
    }
  }
  const int row0 = q0 + (lane >> 4) * 4;
  bfr* o = (w < 2) ? atp : u;
  const float* bias = (w < 2) ? bv : bv0;
  const int dbase = wn & 63;  // 0 or 32 within the selected output half
#pragma unroll
  for (int j = 0; j < 2; j++) {
    const int cm = dbase + j * 16 + fr;  // 0..63
    const float bb = bias[h * 64 + cm];
#pragma unroll
    for (int r = 0; r < 4; r++)
      o[(size_t)(row0 + r) * 1024 + h * 64 + cm] = f2b(acc[j][r] + bb);
  }
}

// pair-merged xpre: grid (4,8,2). xpre[b][c] += sum_64rows q0p_b ⊙ u_b.
// u buffers are at stride 1,048,576 elements (atp0,ub0,atp1,ub1 packed).
__global__ __launch_bounds__(256) void xpre2(const bfr* __restrict__ q0p0,
                                             const bfr* __restrict__ u0,
                                             float* __restrict__ xpre0) {
  const int c = blockIdx.x * 256 + threadIdx.x;
  const int r0 = blockIdx.y * 64;
  const int j = blockIdx.z;
  const bfr* qp = q0p0 + (size_t)j * 524288 + (size_t)r0 * 1024 + c;
  const bfr* up = u0 + (size_t)j * 1048576 + (size_t)r0 * 1024 + c;
  float s = 0.f;
#pragma unroll 8
  for (int r = 0; r < 64; r++)
    s = fmaf(b2f(qp[(size_t)r * 1024]), b2f(up[(size_t)r * 1024]), s);
  atomicAdd(&xpre0[j * 1024 + c], s);
}

// ln body shared by all LN variants
template <typename OT>
__device__ __forceinline__ void ln_body(float4 v, const float* ga, const float* be,
                                        OT* outp, int tid, float* sm) {
  float s = v.x + v.y + v.z + v.w;
  for (int o = 32; o; o >>= 1) s += __shfl_down(s, o, 64);
  if ((tid & 63) == 0) sm[tid >> 6] = s;
  __syncthreads();
  s = sm[0] + sm[1] + sm[2] + sm[3];
  float mean = s * (1.0f / 1024.0f);
  float d0 = v.x - mean, d1 = v.y - mean, d2 = v.z - mean, d3 = v.w - mean;
  float q = d0 * d0 + d1 * d1 + d2 * d2 + d3 * d3;
  __syncthreads();
  for (int o = 32; o; o >>= 1) q += __shfl_down(q, o, 64);
  if ((tid & 63) == 0) sm[tid >> 6] = q;
  __syncthreads();
  q = sm[0] + sm[1] + sm[2] + sm[3];
  float rs = 1.0f / (sqrtf(q * (1.0f / 1023.0f)) + 1e-6f);
  float4 g = *(const float4*)(ga + tid * 4);
  float4 bb = *(const float4*)(be + tid * 4);
  store4(outp, g.x * d0 * rs + bb.x, g.y * d1 * rs + bb.y,
         g.z * d2 * rs + bb.z, g.w * d3 * rs + bb.w);
}

// torch_ln over rows of 1024: a*(x-mean)/(sqrt(var_unbiased)+1e-6)+b, X (+Y)
template <typename TX, typename TY, typename OT>
__global__ __launch_bounds__(256) void ln_kernel(const TX* __restrict__ X,
                                                 const TY* __restrict__ Y,
                                                 const float* __restrict__ ga,
                                                 const float* __restrict__ be,
                                                 OT* __restrict__ out) {
  __shared__ float sm[4];
  const size_t row = blockIdx.x;
  const int tid = threadIdx.x;
  float4 v = load4f(X + row * 1024 + tid * 4);
  if (Y) {
    float4 w = load4f(Y + row * 1024 + tid * 4);
    v.x += w.x; v.y += w.y; v.z += w.z; v.w += w.w;
  }
  ln_body(v, ga, be, out + row * 1024 + tid * 4, tid, sm);
}

// pair-merged attention LN: grid 1024. atl_b = LN(q0p_b + atp_b).
// atp buffers at stride 1,048,576 elements.
__global__ __launch_bounds__(256) void ln2_kernel(const bfr* __restrict__ q0p0,
                                                  const bfr* __restrict__ atp0,
                                                  const float* __restrict__ ga,
                                                  const float* __restrict__ be,
                                                  bfr* __restrict__ atl0) {
  __shared__ float sm[4];
  const int row = blockIdx.x;
  const int b = row >> 9, r = row & 511;
  const int tid = threadIdx.x;
  float4 v = load4f(q0p0 + (size_t)b * 524288 + (size_t)r * 1024 + tid * 4);
  float4 w = load4f(atp0 + (size_t)b * 1048576 + (size_t)r * 1024 + tid * 4);
  v.x += w.x; v.y += w.y; v.z += w.z; v.w += w.w;
  ln_body(v, ga, be, atl0 + (size_t)b * 524288 + (size_t)r * 1024 + tid * 4, tid, sm);
}

// ---------------------------------------------------------------------------
extern "C" void kernel_launch(void* const* d_in, const int* in_sizes, int n_in,
                              void* d_out, int out_size, void* d_ws, size_t ws_size,
                              hipStream_t stream) {
  (void)in_sizes; (void)n_in; (void)out_size; (void)ws_size;
  const float* q   = (const float*)d_in[0];
  const float* k   = (const float*)d_in[1];
  const float* Wq  = (const float*)d_in[2];
  const float* bq  = (const float*)d_in[3];
  const float* Wk  = (const float*)d_in[4];
  const float* bk  = (const float*)d_in[5];
  const float* Wv  = (const float*)d_in[6];
  const float* bv  = (const float*)d_in[7];
  const float* Wv0 = (const float*)d_in[8];
  const float* bv0 = (const float*)d_in[9];
  const float* Wq0 = (const float*)d_in[10];
  const float* bq0 = (const float*)d_in[11];
  const float* nqa = (const float*)d_in[12];
  const float* nqb = (const float*)d_in[13];
  const float* nxa = (const float*)d_in[14];
  const float* nxb = (const float*)d_in[15];
  const float* W1  = (const float*)d_in[16];
  const float* b1  = (const float*)d_in[17];
  const float* W2  = (const float*)d_in[18];
  const float* b2  = (const float*)d_in[19];
  const float* nsa = (const float*)d_in[20];
  const float* nsb = (const float*)d_in[21];

  float* out = (float*)d_out;
  float* x_out  = out;                       // 8,192
  float* qq_out = out + 8192;                // 4,194,304 f32 (written LAST)
  float* kp_out = out + 4202496;             // 6,291,456
  float* ao_out = out + 10493952;            // 4,194,304
  // qq_out region doubles as scratch until the final LN:
  bfr* kp16 = (bfr*)qq_out;                  // 12,582,912 B
  bfr* vT1  = kp16 + 6291456;                //  4,194,304 B (tail of qq_out)

  char* base = (char*)d_ws;
  // persistent (attention phase)
  bfr* q0p   = (bfr*)(base + 0);            // 8,388,608  [4096,1024]
  bfr* qh    = (bfr*)(base + 8388608);      // 8,388,608  [4096,1024]
  bfr* atl   = (bfr*)(base + 16777216);     // 8,388,608  [4096,1024]
  bfr* WqT   = (bfr*)(base + 25165824);     // 1,572,864  [1024,768]
  bfr* Wq0T  = (bfr*)(base + 26738688);     // 1,572,864
  bfr* WTkv  = (bfr*)(base + 28311552);     // 4,718,592  [WkT 1024; vv-interleaved 2048][768]
  float* xpre = (float*)(base + 33030144);  //    32,768  [8,1024]
  char* S = base + 33062912;                // scratch region (25,165,824 B)
  // attention-loop overlay (batch-paired)
  bfr* sc    = (bfr*)(S + 0);               // 16,777,216 [16,512,1024]
  bfr* kh0   = (bfr*)(S + 16777216);        //  2,097,152 [1024,1024]
  bfr* kh1   = (bfr*)(S + 18874368);        //  2,097,152
  bfr* vT0   = (bfr*)(S + 20971520);        //  4,194,304 [16][128][1024] v1|v0
  // atpb/ub overlay the dead kh of the same batch (kh dead after its score)
  bfr* atp0  = (bfr*)(S + 16777216);        //  1,048,576 [512,1024]
  bfr* ub0   = (bfr*)(S + 17825792);        //  1,048,576
  bfr* atp1  = (bfr*)(S + 18874368);        //  1,048,576
  bfr* ub1   = (bfr*)(S + 19922944);        //  1,048,576
  // pre-loop overlay (dead before attention buffers first written)
  bfr* qp_all = (bfr*)(S + 0);              //  6,291,456 [4096,768]
  bfr* q16    = (bfr*)(S + 6291456);        //  6,291,456 [4096,768] plain q bf16
  // FFN-phase overlay (attention buffers dead; q0p/qh dead)
  bfr* W1Tn  = (bfr*)(S + 0);               //  4,194,304 [2048,1024]
  bfr* W2Tn  = (bfr*)(S + 4194304);         //  4,194,304 [1024,2048]
  bfr* ff1n  = (bfr*)(S + 8388608);         // 16,777,216 [4096,2048]
  float* ff2a = (float*)(base + 0);         // 16,777,216 [4096,1024] f32 (over q0p/qh)

  // --- setup ---
  posenc_k<<<24576, 256, 0, stream>>>(k, kp_out, kp16, 6291456);
  posenc_q_all<<<12288, 256, 0, stream>>>(q, qp_all, q16, 3145728);
  transpose_w<<<dim3(32, 24), 256, 0, stream>>>(Wq, WqT, 768, 1024, 1024, 0);
  transpose_w<<<dim3(32, 24), 256, 0, stream>>>(Wq0, Wq0T, 768, 1024, 1024, 0);
  transpose_w<<<dim3(32, 24), 256, 0, stream>>>(Wk, WTkv, 768, 1024, 1024, 0);
  transpose_w<<<dim3(32, 24), 256, 0, stream>>>(Wv, WTkv + 786432, 768, 1024, 1024, 1);
  transpose_w<<<dim3(32, 24), 256, 0, stream>>>(Wv0, WTkv + 786432, 768, 1024, 1024, 2);

  // full-batch projections (fused, MFMA)
  proj_gemm<<<1024, 256, 0, stream>>>(q16, Wq0T, bq0, q0p, qp_all, WqT, bq, qh);
  hipMemsetAsync(xpre, 0, 32768, stream);

  // --- per-batch-pair attention ---
  for (int p = 0; p < 4; p++) {
    const int b0 = 2 * p;
    kv_gemm2<<<768, 256, 0, stream>>>(kp16 + (size_t)b0 * 786432,
                                      kp16 + (size_t)(b0 + 1) * 786432,
                                      WTkv, bk, kh0, kh1,
                                      WTkv + 786432, vT0, vT1);
    for (int j = 0; j < 2; j++) {
      const int b = b0 + j;
      bfr* kh = j ? kh1 : kh0;
      bfr* vT = j ? vT1 : vT0;
      bfr* atpb = j ? atp1 : atp0;
      bfr* ub = j ? ub1 : ub0;
      score_mfma<<<dim3(8, 4, 16), 256, 0, stream>>>(qh + (size_t)b * 524288, kh, sc);
      attout8<<<256, 256, 0, stream>>>(sc, ao_out + (size_t)b * 524288);
      attv4<<<dim3(32, 16), 256, 0, stream>>>(sc, vT, bv, bv0, atpb, ub);
    }
    xpre2<<<dim3(4, 8, 2), 256, 0, stream>>>(q0p + (size_t)b0 * 524288, ub0,
                                             xpre + b0 * 1024);
    ln2_kernel<<<1024, 256, 0, stream>>>(q0p + (size_t)b0 * 524288, atp0,
                                         nqa, nqb, atl + (size_t)b0 * 524288);
  }

  // x = LN(bilinear)
  ln_kernel<float, float, float><<<8, 256, 0, stream>>>(xpre, (const float*)nullptr,
                                                        nxa, nxb, x_out);

  // --- FFN, K-split into 2 chunks of 2048, f32 accumulation in ff2a ---
  for (int nc = 0; nc < 2; nc++) {
    transpose_w<<<dim3(64, 32), 256, 0, stream>>>(W1 + nc * 2048, W1Tn,
                                                  1024, 2048, 4096, 0);
    transpose_w<<<dim3(32, 64), 256, 0, stream>>>(W2 + (size_t)nc * 2048 * 1024, W2Tn,
                                                  2048, 1024, 1024, 0);
    mgemm64<bfr><<<dim3(32, 32), 256, 0, stream>>>(
        atl, W1Tn, b1 + nc * 2048, ff1n, 1024, 2048, 1, 0);
    mgemm64<float><<<dim3(16, 32), 256, 0, stream>>>(
        ff1n, W2Tn, nc == 0 ? b2 : nullptr, ff2a, 2048, 1024, 0, nc);
  }
  ln_kernel<bfr, float, float><<<4096, 256, 0, stream>>>(atl, ff2a, nsa, nsb, qq_out);
}